// Round 18
// baseline (331.897 us; speedup 1.0000x reference)
//
#include <hip/hip_runtime.h>
#include <math.h>

#define NN 50000
#define NE 800000
#define EP (NE + NN)        // edges including self loops
#define INC 128
#define HID 64
#define HEADS 4
#define C1 (HEADS * HID)    // 256
#define NEG 0.2f
#define EPSS 1e-16f

#define SCHUNK 512
#define NSB ((NN + SCHUNK - 1) / SCHUNK)   // 98

#define KP1 136             // gemm1 W1^T LDS stride
#define KP2 264             // gemm2 W2^T LDS stride
typedef __attribute__((ext_vector_type(8))) short bf16x8;
typedef __attribute__((ext_vector_type(4))) float f32x4;

// ---------- bf16 helpers ----------
__device__ __forceinline__ unsigned short f2bf(float f) {
    unsigned u = __float_as_uint(f);
    unsigned r = (u + 0x7FFFu + ((u >> 16) & 1u)) >> 16;
    return (unsigned short)r;
}
__device__ __forceinline__ float bf2f(unsigned short b) {
    return __uint_as_float(((unsigned)b) << 16);
}

// ================= CSR scans =================
__global__ __launch_bounds__(SCHUNK) void scan_partial(const int* __restrict__ counts,
                                                       int* __restrict__ bsum) {
    __shared__ int lds[SCHUNK];
    int i = blockIdx.x * SCHUNK + threadIdx.x;
    lds[threadIdx.x] = (i < NN) ? counts[i] : 0;
    __syncthreads();
    for (int off = SCHUNK / 2; off > 0; off >>= 1) {
        if (threadIdx.x < off) lds[threadIdx.x] += lds[threadIdx.x + off];
        __syncthreads();
    }
    if (threadIdx.x == 0) bsum[blockIdx.x] = lds[0];
}

__global__ void scan_top(int* __restrict__ bsum, int* __restrict__ rowptr) {
    __shared__ int lds[NSB];
    int t = threadIdx.x;
    if (t < NSB) lds[t] = bsum[t];
    __syncthreads();
    if (t == 0) {
        int acc = 0;
        for (int i = 0; i < NSB; ++i) { int v = lds[i]; lds[i] = acc; acc += v; }
        rowptr[NN] = acc;   // == EP
    }
    __syncthreads();
    if (t < NSB) bsum[t] = lds[t];
}

__global__ __launch_bounds__(SCHUNK) void scan_final(const int* __restrict__ counts,
                                                     const int* __restrict__ bsum,
                                                     int* __restrict__ rowptr,
                                                     int* __restrict__ cursor) {
    __shared__ int lds[SCHUNK];
    int i = blockIdx.x * SCHUNK + threadIdx.x;
    int v = (i < NN) ? counts[i] : 0;
    lds[threadIdx.x] = v;
    __syncthreads();
    for (int off = 1; off < SCHUNK; off <<= 1) {
        int t = (threadIdx.x >= off) ? lds[threadIdx.x - off] : 0;
        __syncthreads();
        lds[threadIdx.x] += t;
        __syncthreads();
    }
    if (i < NN) {
        int excl = lds[threadIdx.x] - v + bsum[blockIdx.x];
        rowptr[i] = excl;
        cursor[i] = excl;
    }
}

// packed (src,dst) written via device-scope atomicExch: scattered 8B writes
// merge at the coherent point instead of forcing per-XCD full-line writebacks.
__global__ void csr_fill(const int* __restrict__ ei, int* __restrict__ cursor,
                         unsigned long long* __restrict__ csr2) {
    int e = blockIdx.x * 256 + threadIdx.x;
    if (e >= EP) return;
    int s, d;
    if (e < NE) { s = ei[e]; d = ei[NE + e]; } else { s = d = e - NE; }
    int pos = atomicAdd(&cursor[d], 1);
    unsigned long long packed = ((unsigned long long)(unsigned)d << 32) | (unsigned)s;
    atomicExch(&csr2[pos], packed);
}

// ================= merged weight prep + projections + edge count =============
#define PREP_N0 (C1 * INC)
#define PREP_N1 (HID * C1)
#define PREP_N2 (5 * 4 * 64 * 8)   // 10240
#define PREP_N3 1024
#define PREP_N4 (NN * INC)
#define PREP_TOT (PREP_N0 + PREP_N1 + PREP_N2 + PREP_N3 + PREP_N4)
__global__ void prep_all(const float* __restrict__ mW1, const float* __restrict__ W1,
                         const float* __restrict__ W2, const int* __restrict__ ei,
                         const float* __restrict__ x,
                         const float* __restrict__ att_s1, const float* __restrict__ att_d1,
                         unsigned short* __restrict__ w1h, unsigned short* __restrict__ w1l,
                         unsigned short* __restrict__ w2h, unsigned short* __restrict__ w2l,
                         unsigned short* __restrict__ wFh, unsigned short* __restrict__ wFl,
                         float* __restrict__ vsd, unsigned short* __restrict__ xb,
                         int* __restrict__ counts) {
    int i = blockIdx.x * 256 + threadIdx.x;
    if (i < PREP_N0) {
        int c = i >> 7, k = i & 127;
        float f = W1[k * C1 + c];
        unsigned short h = f2bf(f);
        w1h[i] = h; w1l[i] = f2bf(f - bf2f(h));
        return;
    }
    i -= PREP_N0;
    if (i < PREP_N1) {
        int c = i >> 8, k = i & 255;
        float f = W2[k * HID + c];
        unsigned short h = f2bf(f);
        w2h[i] = h; w2l[i] = f2bf(f - bf2f(h));
        return;
    }
    i -= PREP_N1;
    if (i < PREP_N2) {
        int kk = i >> 11;
        int ct = (i >> 9) & 3;
        int l  = (i >> 3) & 63;
        int j  = i & 7;
        int cl = l & 15, g = l >> 4;
        int k   = kk * 32 + g * 8 + j;
        int col = ct * 16 + cl;
        unsigned short h = 0, lo = 0;
        if (k < 131) {
            float f = mW1[k * 64 + col];
            h  = f2bf(f);
            lo = f2bf(f - bf2f(h));
        }
        wFh[i] = h;
        wFl[i] = lo;
        return;
    }
    i -= PREP_N2;
    if (i < PREP_N3) {
        int type = i >> 9;
        int rem  = i & 511;
        int h = rem >> 7, k = rem & 127;
        const float* att = type ? att_d1 : att_s1;
        float acc = 0.f;
        for (int c = 0; c < 64; ++c)
            acc += W1[k * C1 + h * 64 + c] * att[h * 64 + c];
        vsd[i] = acc;
        return;
    }
    i -= PREP_N3;
    if (i < PREP_N4) {
        xb[i] = f2bf(x[i]);
        return;
    }
    i -= PREP_N4;
    if (i < EP) {
        int d = (i < NE) ? ei[NE + i] : (i - NE);
        atomicAdd(&counts[d], 1);
    }
}

// ================= att1: as1/ad1 = x . (W1 @ att) — 16 lanes/node ============
__global__ __launch_bounds__(256) void att1_kernel(const float* __restrict__ x,
                                                   const float* __restrict__ vsd,
                                                   float* __restrict__ as1,
                                                   float* __restrict__ ad1) {
    __shared__ float vsS[1024];
    const int tid = threadIdx.x;
    for (int idx = tid; idx < 1024; idx += 256) vsS[idx] = vsd[idx];
    __syncthreads();

    const int n = blockIdx.x * 16 + (tid >> 4);
    const int l16 = tid & 15;
    const float* xp = x + (size_t)n * INC + l16 * 8;
    float4 xa = *(const float4*)xp;
    float4 xc = *(const float4*)(xp + 4);

    float o[8];
#pragma unroll
    for (int h = 0; h < 4; ++h) {
        const float* vp = vsS + h * 128 + l16 * 8;
        const float* dp = vsS + 512 + h * 128 + l16 * 8;
        o[h]     = xa.x * vp[0] + xa.y * vp[1] + xa.z * vp[2] + xa.w * vp[3]
                 + xc.x * vp[4] + xc.y * vp[5] + xc.z * vp[6] + xc.w * vp[7];
        o[4 + h] = xa.x * dp[0] + xa.y * dp[1] + xa.z * dp[2] + xa.w * dp[3]
                 + xc.x * dp[4] + xc.y * dp[5] + xc.z * dp[6] + xc.w * dp[7];
    }
#pragma unroll
    for (int off = 1; off < 16; off <<= 1)
#pragma unroll
        for (int v = 0; v < 8; ++v) o[v] += __shfl_xor(o[v], off);
    if (l16 == 0) {
        *(float4*)(as1 + n * 4) = make_float4(o[0], o[1], o[2], o[3]);
        *(float4*)(ad1 + n * 4) = make_float4(o[4], o[5], o[6], o[7]);
    }
}

// ================= edge softmax weights (packed CSR) =================
__global__ void edge_w1k(const int2* __restrict__ csr2,
                         const float* __restrict__ as1, const float* __restrict__ ad1,
                         float* __restrict__ w1e) {
    int i = blockIdx.x * 256 + threadIdx.x;
    if (i >= EP) return;
    int2 sd = csr2[i];
    float4 a = *(const float4*)(as1 + sd.x * 4);
    float4 b = *(const float4*)(ad1 + sd.y * 4);
    float4 o;
    float t;
    t = a.x + b.x; t = t > 0.f ? t : NEG * t; o.x = __expf(t);
    t = a.y + b.y; t = t > 0.f ? t : NEG * t; o.y = __expf(t);
    t = a.z + b.z; t = t > 0.f ? t : NEG * t; o.z = __expf(t);
    t = a.w + b.w; t = t > 0.f ? t : NEG * t; o.w = __expf(t);
    *(float4*)(w1e + (size_t)i * 4) = o;
}

__global__ void edge_w2k(const int2* __restrict__ csr2,
                         const float* __restrict__ as2, const float* __restrict__ ad2,
                         float* __restrict__ w2e) {
    int i = blockIdx.x * 256 + threadIdx.x;
    if (i >= EP) return;
    int2 sd = csr2[i];
    float t = as2[sd.x] + ad2[sd.y];
    t = t > 0.f ? t : NEG * t;
    w2e[i] = __expf(t);
}

// ================= conv1 aggregate of x (bf16): 16 lanes/node ================
__global__ __launch_bounds__(256) void conv1_agg(const int* __restrict__ rowptr,
                                                 const int2* __restrict__ csr2,
                                                 const float* __restrict__ w1e,
                                                 const unsigned short* __restrict__ xb,
                                                 unsigned short* __restrict__ xaggb) {
    const int tid = threadIdx.x;
    const int node = blockIdx.x * 16 + (tid >> 4);   // NN % 16 == 0
    const int l16 = tid & 15;
    const int beg = rowptr[node], end = rowptr[node + 1];

    float acc[4][8];
#pragma unroll
    for (int h = 0; h < 4; ++h)
#pragma unroll
        for (int j = 0; j < 8; ++j) acc[h][j] = 0.f;
    float sm[4] = {0.f, 0.f, 0.f, 0.f};

#pragma unroll 2
    for (int i = beg; i < end; ++i) {
        int s = csr2[i].x;
        float4 w = *(const float4*)(w1e + (size_t)i * 4);
        bf16x8 xv = *(const bf16x8*)(xb + (size_t)s * INC + l16 * 8);
        float xf[8];
#pragma unroll
        for (int j = 0; j < 8; ++j) xf[j] = bf2f((unsigned short)xv[j]);
#pragma unroll
        for (int j = 0; j < 8; ++j) {
            acc[0][j] += w.x * xf[j];
            acc[1][j] += w.y * xf[j];
            acc[2][j] += w.z * xf[j];
            acc[3][j] += w.w * xf[j];
        }
        sm[0] += w.x; sm[1] += w.y; sm[2] += w.z; sm[3] += w.w;
    }

#pragma unroll
    for (int h = 0; h < 4; ++h) {
        const float rden = 1.f / (sm[h] + EPSS);
        bf16x8 ob;
#pragma unroll
        for (int j = 0; j < 8; ++j) ob[j] = (short)f2bf(acc[h][j] * rden);
        *(bf16x8*)(xaggb + ((size_t)node * 4 + h) * INC + l16 * 8) = ob;
    }
}

// ================= GEMM1 (post-agg): h1c = ELU(xagg @ W1 + b1), bf16 A =======
__global__ __launch_bounds__(256) void gemm1b(const unsigned short* __restrict__ xaggb,
                                              const unsigned short* __restrict__ w1h,
                                              const unsigned short* __restrict__ w1l,
                                              const float* __restrict__ b1,
                                              unsigned short* __restrict__ h1c) {
    __shared__ unsigned short wH[64 * KP1];
    __shared__ unsigned short wL[64 * KP1];
    const int tid = threadIdx.x;
    const int n0 = blockIdx.x * 64;
    const int q  = blockIdx.y;

    for (int idx = tid; idx < 64 * 16; idx += 256) {
        int col = idx >> 4, ch = idx & 15;
        *(bf16x8*)(wH + col * KP1 + ch * 8) =
            *(const bf16x8*)(w1h + ((q * 64 + col) << 7) + ch * 8);
        *(bf16x8*)(wL + col * KP1 + ch * 8) =
            *(const bf16x8*)(w1l + ((q * 64 + col) << 7) + ch * 8);
    }

    const int w = tid >> 6, l = tid & 63;
    const int cl = l & 15, g = l >> 4, g8 = g * 8;
    const int na = min(n0 + w * 16 + cl, NN - 1);

    bf16x8 aH[4];
#pragma unroll
    for (int kk = 0; kk < 4; ++kk)
        aH[kk] = *(const bf16x8*)(xaggb + ((size_t)na * 4 + q) * INC + kk * 32 + g8);

    f32x4 acc[4];
#pragma unroll
    for (int ct = 0; ct < 4; ++ct) acc[ct] = (f32x4){0.f, 0.f, 0.f, 0.f};

    __syncthreads();

#pragma unroll
    for (int kk = 0; kk < 4; ++kk) {
        const int ko = kk * 32 + g8;
#pragma unroll
        for (int ct = 0; ct < 4; ++ct) {
            const bf16x8 bH = *(const bf16x8*)(wH + (ct * 16 + cl) * KP1 + ko);
            const bf16x8 bL = *(const bf16x8*)(wL + (ct * 16 + cl) * KP1 + ko);
            acc[ct] = __builtin_amdgcn_mfma_f32_16x16x32_bf16(aH[kk], bH, acc[ct], 0, 0, 0);
            acc[ct] = __builtin_amdgcn_mfma_f32_16x16x32_bf16(aH[kk], bL, acc[ct], 0, 0, 0);
        }
    }

#pragma unroll
    for (int reg = 0; reg < 4; ++reg) {
        const int nd = n0 + w * 16 + g * 4 + reg;
        if (nd < NN) {
#pragma unroll
            for (int ct = 0; ct < 4; ++ct) {
                const int col = q * 64 + ct * 16 + cl;
                float o = acc[ct][reg] + b1[col];
                o = o > 0.f ? o : (__expf(o) - 1.f);
                h1c[(size_t)nd * C1 + col] = f2bf(o);
            }
        }
    }
}

// ================= GEMM2: bf16-A x split-bf16-W MFMA + att2 epilogue =========
__global__ __launch_bounds__(256) void gemm2_mfma(const unsigned short* __restrict__ h1c,
                                                  const unsigned short* __restrict__ w2h,
                                                  const unsigned short* __restrict__ w2l,
                                                  const float* __restrict__ att_s,
                                                  const float* __restrict__ att_d,
                                                  unsigned short* __restrict__ h2b,
                                                  float* __restrict__ as2,
                                                  float* __restrict__ ad2) {
    __shared__ unsigned short wH[64 * KP2];
    __shared__ unsigned short wL[64 * KP2];
    const int tid = threadIdx.x;
    const int n0 = blockIdx.x * 64;

    for (int idx = tid; idx < 64 * 32; idx += 256) {
        int col = idx >> 5, ch = idx & 31;
        *(bf16x8*)(wH + col * KP2 + ch * 8) =
            *(const bf16x8*)(w2h + ((col) << 8) + ch * 8);
        *(bf16x8*)(wL + col * KP2 + ch * 8) =
            *(const bf16x8*)(w2l + ((col) << 8) + ch * 8);
    }

    const int w = tid >> 6, l = tid & 63;
    const int cl = l & 15, g = l >> 4, g8 = g * 8;
    const int na = min(n0 + w * 16 + cl, NN - 1);

    f32x4 acc[4];
#pragma unroll
    for (int ct = 0; ct < 4; ++ct) acc[ct] = (f32x4){0.f, 0.f, 0.f, 0.f};

    __syncthreads();

#pragma unroll
    for (int kk = 0; kk < 8; ++kk) {
        const bf16x8 aH = *(const bf16x8*)(h1c + (size_t)na * C1 + kk * 32 + g8);
        const int ko = kk * 32 + g8;
#pragma unroll
        for (int ct = 0; ct < 4; ++ct) {
            const bf16x8 bH = *(const bf16x8*)(wH + (ct * 16 + cl) * KP2 + ko);
            const bf16x8 bL = *(const bf16x8*)(wL + (ct * 16 + cl) * KP2 + ko);
            acc[ct] = __builtin_amdgcn_mfma_f32_16x16x32_bf16(aH, bH, acc[ct], 0, 0, 0);
            acc[ct] = __builtin_amdgcn_mfma_f32_16x16x32_bf16(aH, bL, acc[ct], 0, 0, 0);
        }
    }

    float asc[4], adc[4];
#pragma unroll
    for (int ct = 0; ct < 4; ++ct) {
        asc[ct] = att_s[ct * 16 + cl];
        adc[ct] = att_d[ct * 16 + cl];
    }

#pragma unroll
    for (int reg = 0; reg < 4; ++reg) {
        const int nd = n0 + w * 16 + g * 4 + reg;
        float sa = 0.f, sd = 0.f;
#pragma unroll
        for (int ct = 0; ct < 4; ++ct) {
            sa += acc[ct][reg] * asc[ct];
            sd += acc[ct][reg] * adc[ct];
        }
#pragma unroll
        for (int off = 8; off > 0; off >>= 1) {
            sa += __shfl_xor(sa, off);
            sd += __shfl_xor(sd, off);
        }
        if (nd < NN) {
#pragma unroll
            for (int ct = 0; ct < 4; ++ct)
                h2b[(size_t)nd * HID + ct * 16 + cl] = f2bf(acc[ct][reg]);
            if (cl == 0) { as2[nd] = sa; ad2[nd] = sd; }
        }
    }
}

// ================= conv2 aggregate: 2 nodes/wave, precomputed weights =========
__global__ __launch_bounds__(256) void conv2_agg(const int* __restrict__ rowptr,
                                                 const int2* __restrict__ csr2,
                                                 const float* __restrict__ w2e,
                                                 const unsigned short* __restrict__ h2b,
                                                 const float* __restrict__ b2,
                                                 unsigned short* __restrict__ embb) {
    const int tid  = threadIdx.x;
    const int wid  = tid >> 6;
    const int l    = tid & 63;
    const int half = l >> 5;
    const int l32  = l & 31;
    const int node = blockIdx.x * 8 + wid * 2 + half;
    const int beg = rowptr[node], end = rowptr[node + 1];

    float a0 = 0.f, a1 = 0.f, sm = 0.f;
#pragma unroll 2
    for (int i = beg; i < end; ++i) {
        int s = csr2[i].x;
        float w = w2e[i];
        unsigned hv = *(const unsigned*)(h2b + (size_t)s * HID + l32 * 2);
        a0 += w * bf2f((unsigned short)(hv & 0xFFFF));
        a1 += w * bf2f((unsigned short)(hv >> 16));
        sm += w;
    }
    const float rden = 1.f / (sm + EPSS);
    float o0 = a0 * rden + b2[l32 * 2];
    float o1 = a1 * rden + b2[l32 * 2 + 1];
    unsigned outw = (unsigned)f2bf(o0) | ((unsigned)f2bf(o1) << 16);
    *(unsigned*)(embb + (size_t)node * HID + l32 * 2) = outw;
}

// ================= edge MLP: swapped operands, 512 thr, 1 tile/wave ===========
#define NT_MLP (NE / 32)    // 25000
__global__ __launch_bounds__(512) void edge_mlp_mfma(const int* __restrict__ ei,
                                                     const unsigned short* __restrict__ embb,
                                                     const float* __restrict__ stats,
                                                     const unsigned short* __restrict__ wFh,
                                                     const unsigned short* __restrict__ wFl,
                                                     const float* __restrict__ mb1,
                                                     const float* __restrict__ mW2,
                                                     const float* __restrict__ mb2,
                                                     float* __restrict__ out) {
    __shared__ unsigned short sH[PREP_N2];   // 20 KB
    __shared__ unsigned short sL[PREP_N2];   // 20 KB
    __shared__ float biaS[64], w2aS[64], w2bS[64];
    const int tid = threadIdx.x;
    for (int idx = tid; idx < PREP_N2 / 8; idx += 512) {
        ((float4*)sH)[idx] = ((const float4*)wFh)[idx];
        ((float4*)sL)[idx] = ((const float4*)wFl)[idx];
    }
    if (tid < 64) {
        biaS[tid] = mb1[tid];
        w2aS[tid] = mW2[tid * 2];
        w2bS[tid] = mW2[tid * 2 + 1];
    }

    const int l  = tid & 63;
    const int cl = l & 15;
    const int g  = l >> 4;
    const int g8 = g * 8;
    const float ob0 = mb2[0], ob1 = mb2[1];

    const int t = blockIdx.x * 8 + (tid >> 6);   // 32-edge tile id

    bf16x8 a[2][5];
#pragma unroll
    for (int s = 0; s < 2; ++s) {
        const int ge_a = t * 32 + s * 16 + cl;
        const int rn = ei[ge_a];
        const int cn = ei[NE + ge_a];
        const unsigned short* rp = embb + (size_t)rn * HID;
        const unsigned short* cp = embb + (size_t)cn * HID;
        a[s][0] = *(const bf16x8*)(rp + g8);
        a[s][1] = *(const bf16x8*)(rp + 32 + g8);
        a[s][2] = *(const bf16x8*)(cp + g8);
        a[s][3] = *(const bf16x8*)(cp + 32 + g8);
        bf16x8 z = {0, 0, 0, 0, 0, 0, 0, 0};
        if (g == 0) {
            const float* sp = stats + (size_t)ge_a * 3;
            z[0] = (short)f2bf(sp[0]);
            z[1] = (short)f2bf(sp[1]);
            z[2] = (short)f2bf(sp[2]);
        }
        a[s][4] = z;
    }

    f32x4 acc[2][4];
#pragma unroll
    for (int s = 0; s < 2; ++s)
#pragma unroll
        for (int ct = 0; ct < 4; ++ct)
            acc[s][ct] = (f32x4){0.f, 0.f, 0.f, 0.f};

    __syncthreads();

#pragma unroll
    for (int kk = 0; kk < 5; ++kk) {
#pragma unroll
        for (int ct = 0; ct < 4; ++ct) {
            const int fo = ((kk * 4 + ct) * 64 + l) * 8;
            const bf16x8 wHf = *(const bf16x8*)(sH + fo);
            const bf16x8 wLf = *(const bf16x8*)(sL + fo);
#pragma unroll
            for (int s = 0; s < 2; ++s) {
                acc[s][ct] = __builtin_amdgcn_mfma_f32_16x16x32_bf16(wHf, a[s][kk], acc[s][ct], 0, 0, 0);
                acc[s][ct] = __builtin_amdgcn_mfma_f32_16x16x32_bf16(wLf, a[s][kk], acc[s][ct], 0, 0, 0);
            }
        }
    }

#pragma unroll
    for (int s = 0; s < 2; ++s) {
        float p0 = 0.f, p1 = 0.f;
#pragma unroll
        for (int ct = 0; ct < 4; ++ct) {
            const int hb = ct * 16 + g * 4;
            float4 bi = *(const float4*)(biaS + hb);
            float4 wa = *(const float4*)(w2aS + hb);
            float4 wb = *(const float4*)(w2bS + hb);
#pragma unroll
            for (int reg = 0; reg < 4; ++reg) {
                float bv = (reg == 0) ? bi.x : (reg == 1) ? bi.y : (reg == 2) ? bi.z : bi.w;
                float av = (reg == 0) ? wa.x : (reg == 1) ? wa.y : (reg == 2) ? wa.z : wa.w;
                float wv = (reg == 0) ? wb.x : (reg == 1) ? wb.y : (reg == 2) ? wb.z : wb.w;
                float h = fmaxf(acc[s][ct][reg] + bv, 0.f);
                p0 += h * av;
                p1 += h * wv;
            }
        }
        p0 += __shfl_xor(p0, 16); p0 += __shfl_xor(p0, 32);
        p1 += __shfl_xor(p1, 16); p1 += __shfl_xor(p1, 32);
        if (g == 0) {
            const int ge = t * 32 + s * 16 + cl;
            *(float2*)(out + (size_t)ge * 2) = make_float2(p0 + ob0, p1 + ob1);
        }
    }
}

// ================= launcher =================
extern "C" void kernel_launch(void* const* d_in, const int* in_sizes, int n_in,
                              void* d_out, int out_size, void* d_ws, size_t ws_size,
                              hipStream_t stream) {
    const float* x      = (const float*)d_in[0];
    const int*   ei     = (const int*)d_in[1];
    const float* stats  = (const float*)d_in[2];
    const float* W1     = (const float*)d_in[3];
    const float* att_s1 = (const float*)d_in[4];
    const float* att_d1 = (const float*)d_in[5];
    const float* b1     = (const float*)d_in[6];
    const float* W2     = (const float*)d_in[7];
    const float* att_s2 = (const float*)d_in[8];
    const float* att_d2 = (const float*)d_in[9];
    const float* b2     = (const float*)d_in[10];
    const float* mW1    = (const float*)d_in[11];
    const float* mb1    = (const float*)d_in[12];
    const float* mW2    = (const float*)d_in[13];
    const float* mb2    = (const float*)d_in[14];
    float* out = (float*)d_out;
    float* ws  = (float*)d_ws;

    // f32-word-offset layout (no aliasing; all chunks 16B-aligned)
    int*   rowptr  = (int*)ws;                                 // NN+16
    unsigned long long* csr2u = (unsigned long long*)(rowptr + NN + 16);  // EP u64
    int2*  csr2    = (int2*)csr2u;                             // same storage
    float* as1     = (float*)(csr2u + EP);                     // 4NN
    float* ad1     = as1 + (size_t)4 * NN;                     // 4NN
    unsigned short* xb    = (unsigned short*)(ad1 + (size_t)4 * NN);  // NN*128 bf16
    unsigned short* xaggb = xb + (size_t)128 * NN;             // NN*512 bf16
    unsigned short* h1c   = xaggb + (size_t)512 * NN;          // NN*256 bf16
    unsigned short* h2b   = h1c + (size_t)256 * NN;            // NN*64 bf16
    unsigned short* embb  = h2b + (size_t)64 * NN;             // NN*64 bf16
    float* as2     = (float*)(embb + (size_t)64 * NN);         // NN
    float* ad2     = as2 + NN;                                 // NN
    unsigned short* w1h = (unsigned short*)(ad2 + NN);         // 256*128
    unsigned short* w1l = w1h + C1 * INC;
    unsigned short* w2h = w1l + C1 * INC;                      // 64*256
    unsigned short* w2l = w2h + HID * C1;
    unsigned short* wFh = w2l + HID * C1;                      // 10240
    unsigned short* wFl = wFh + PREP_N2;                       // 10240
    float* vsd     = (float*)(wFl + PREP_N2);                  // 1024
    float* w1e     = vsd + 1024;                               // 4*EP
    float* w2e     = w1e + (size_t)4 * EP;                     // EP
    int*   counts  = (int*)(w2e + EP + 64);                    // NN
    int*   bsum    = counts + NN + 64;                         // NSB
    int*   cursor  = bsum + NSB + 64;                          // NN

    // ---- CSR build + weight prep + projections ----
    hipMemsetAsync(counts, 0, NN * sizeof(int), stream);
    prep_all<<<(PREP_TOT + EP + 255) / 256, 256, 0, stream>>>(
        mW1, W1, W2, ei, x, att_s1, att_d1,
        w1h, w1l, w2h, w2l, wFh, wFl, vsd, xb, counts);
    scan_partial<<<NSB, SCHUNK, 0, stream>>>(counts, bsum);
    scan_top<<<1, 128, 0, stream>>>(bsum, rowptr);
    scan_final<<<NSB, SCHUNK, 0, stream>>>(counts, bsum, rowptr, cursor);
    csr_fill<<<(EP + 255) / 256, 256, 0, stream>>>(ei, cursor, csr2u);

    // ---- conv1: logits -> edge weights -> aggregate x -> GEMM ----
    att1_kernel<<<NN / 16, 256, 0, stream>>>(x, vsd, as1, ad1);
    edge_w1k<<<(EP + 255) / 256, 256, 0, stream>>>(csr2, as1, ad1, w1e);
    conv1_agg<<<NN / 16, 256, 0, stream>>>(rowptr, csr2, w1e, xb, xaggb);
    gemm1b<<<dim3((NN + 63) / 64, 4), 256, 0, stream>>>(xaggb, w1h, w1l, b1, h1c);

    // ---- conv2 ----
    gemm2_mfma<<<(NN + 63) / 64, 256, 0, stream>>>(h1c, w2h, w2l, att_s2, att_d2,
                                                   h2b, as2, ad2);
    edge_w2k<<<(EP + 255) / 256, 256, 0, stream>>>(csr2, as2, ad2, w2e);
    conv2_agg<<<NN / 8, 256, 0, stream>>>(rowptr, csr2, w2e, h2b, b2, embb);

    // ---- edge MLP: swapped-operand MFMA, 512 thr, 1 tile/wave ----
    edge_mlp_mfma<<<NT_MLP / 8, 512, 0, stream>>>(ei, embb, stats, wFh, wFl,
                                                  mb1, mW2, mb2, out);
}

// Round 19
// 316.804 us; speedup vs baseline: 1.0476x; 1.0476x over previous
//
#include <hip/hip_runtime.h>
#include <math.h>

#define NN 50000
#define NE 800000
#define EP (NE + NN)        // edges including self loops
#define INC 128
#define HID 64
#define HEADS 4
#define C1 (HEADS * HID)    // 256
#define NEG 0.2f
#define EPSS 1e-16f

#define SCHUNK 512
#define NSB ((NN + SCHUNK - 1) / SCHUNK)   // 98

#define KP1 136             // gemm1 W1^T LDS stride
#define KP2 264             // gemm2 W2^T LDS stride
typedef __attribute__((ext_vector_type(8))) short bf16x8;
typedef __attribute__((ext_vector_type(4))) float f32x4;

// ---------- bf16 helpers ----------
__device__ __forceinline__ unsigned short f2bf(float f) {
    unsigned u = __float_as_uint(f);
    unsigned r = (u + 0x7FFFu + ((u >> 16) & 1u)) >> 16;
    return (unsigned short)r;
}
__device__ __forceinline__ float bf2f(unsigned short b) {
    return __uint_as_float(((unsigned)b) << 16);
}

// ================= CSR scans =================
__global__ __launch_bounds__(SCHUNK) void scan_partial(const int* __restrict__ counts,
                                                       int* __restrict__ bsum) {
    __shared__ int lds[SCHUNK];
    int i = blockIdx.x * SCHUNK + threadIdx.x;
    lds[threadIdx.x] = (i < NN) ? counts[i] : 0;
    __syncthreads();
    for (int off = SCHUNK / 2; off > 0; off >>= 1) {
        if (threadIdx.x < off) lds[threadIdx.x] += lds[threadIdx.x + off];
        __syncthreads();
    }
    if (threadIdx.x == 0) bsum[blockIdx.x] = lds[0];
}

__global__ void scan_top(int* __restrict__ bsum, int* __restrict__ rowptr) {
    __shared__ int lds[NSB];
    int t = threadIdx.x;
    if (t < NSB) lds[t] = bsum[t];
    __syncthreads();
    if (t == 0) {
        int acc = 0;
        for (int i = 0; i < NSB; ++i) { int v = lds[i]; lds[i] = acc; acc += v; }
        rowptr[NN] = acc;   // == EP
    }
    __syncthreads();
    if (t < NSB) bsum[t] = lds[t];
}

__global__ __launch_bounds__(SCHUNK) void scan_final(const int* __restrict__ counts,
                                                     const int* __restrict__ bsum,
                                                     int* __restrict__ rowptr,
                                                     int* __restrict__ cursor) {
    __shared__ int lds[SCHUNK];
    int i = blockIdx.x * SCHUNK + threadIdx.x;
    int v = (i < NN) ? counts[i] : 0;
    lds[threadIdx.x] = v;
    __syncthreads();
    for (int off = 1; off < SCHUNK; off <<= 1) {
        int t = (threadIdx.x >= off) ? lds[threadIdx.x - off] : 0;
        __syncthreads();
        lds[threadIdx.x] += t;
        __syncthreads();
    }
    if (i < NN) {
        int excl = lds[threadIdx.x] - v + bsum[blockIdx.x];
        rowptr[i] = excl;
        cursor[i] = excl;
    }
}

// scattered write of src ONLY (4B/edge -> half the scattered line traffic)
__global__ void csr_fill(const int* __restrict__ ei, int* __restrict__ cursor,
                         int* __restrict__ csr_src) {
    int e = blockIdx.x * 256 + threadIdx.x;
    if (e >= EP) return;
    int s, d;
    if (e < NE) { s = ei[e]; d = ei[NE + e]; } else { s = d = e - NE; }
    int pos = atomicAdd(&cursor[d], 1);
    csr_src[pos] = s;
}

// sequential coalesced fill of dst-per-position (node n owns rowptr[n]..rowptr[n+1])
__global__ void fill_dst(const int* __restrict__ rowptr, int* __restrict__ csr_dst) {
    int n = blockIdx.x * 256 + threadIdx.x;
    if (n >= NN) return;
    int beg = rowptr[n], end = rowptr[n + 1];
    for (int i = beg; i < end; ++i) csr_dst[i] = n;
}

// ================= merged weight prep + projections + edge count =============
#define PREP_N0 (C1 * INC)
#define PREP_N1 (HID * C1)
#define PREP_N2 (5 * 4 * 64 * 8)   // 10240
#define PREP_N3 1024
#define PREP_N4 (NN * INC)
#define PREP_TOT (PREP_N0 + PREP_N1 + PREP_N2 + PREP_N3 + PREP_N4)
__global__ void prep_all(const float* __restrict__ mW1, const float* __restrict__ W1,
                         const float* __restrict__ W2, const int* __restrict__ ei,
                         const float* __restrict__ x,
                         const float* __restrict__ att_s1, const float* __restrict__ att_d1,
                         unsigned short* __restrict__ w1h, unsigned short* __restrict__ w1l,
                         unsigned short* __restrict__ w2h, unsigned short* __restrict__ w2l,
                         unsigned short* __restrict__ wFh, unsigned short* __restrict__ wFl,
                         float* __restrict__ vsd, unsigned short* __restrict__ xb,
                         int* __restrict__ counts) {
    int i = blockIdx.x * 256 + threadIdx.x;
    if (i < PREP_N0) {
        int c = i >> 7, k = i & 127;
        float f = W1[k * C1 + c];
        unsigned short h = f2bf(f);
        w1h[i] = h; w1l[i] = f2bf(f - bf2f(h));
        return;
    }
    i -= PREP_N0;
    if (i < PREP_N1) {
        int c = i >> 8, k = i & 255;
        float f = W2[k * HID + c];
        unsigned short h = f2bf(f);
        w2h[i] = h; w2l[i] = f2bf(f - bf2f(h));
        return;
    }
    i -= PREP_N1;
    if (i < PREP_N2) {
        int kk = i >> 11;
        int ct = (i >> 9) & 3;
        int l  = (i >> 3) & 63;
        int j  = i & 7;
        int cl = l & 15, g = l >> 4;
        int k   = kk * 32 + g * 8 + j;
        int col = ct * 16 + cl;
        unsigned short h = 0, lo = 0;
        if (k < 131) {
            float f = mW1[k * 64 + col];
            h  = f2bf(f);
            lo = f2bf(f - bf2f(h));
        }
        wFh[i] = h;
        wFl[i] = lo;
        return;
    }
    i -= PREP_N2;
    if (i < PREP_N3) {
        int type = i >> 9;
        int rem  = i & 511;
        int h = rem >> 7, k = rem & 127;
        const float* att = type ? att_d1 : att_s1;
        float acc = 0.f;
        for (int c = 0; c < 64; ++c)
            acc += W1[k * C1 + h * 64 + c] * att[h * 64 + c];
        vsd[i] = acc;
        return;
    }
    i -= PREP_N3;
    if (i < PREP_N4) {
        xb[i] = f2bf(x[i]);
        return;
    }
    i -= PREP_N4;
    if (i < EP) {
        int d = (i < NE) ? ei[NE + i] : (i - NE);
        atomicAdd(&counts[d], 1);
    }
}

// ================= att1: as1/ad1 = x . (W1 @ att) — 16 lanes/node ============
__global__ __launch_bounds__(256) void att1_kernel(const float* __restrict__ x,
                                                   const float* __restrict__ vsd,
                                                   float* __restrict__ as1,
                                                   float* __restrict__ ad1) {
    __shared__ float vsS[1024];
    const int tid = threadIdx.x;
    for (int idx = tid; idx < 1024; idx += 256) vsS[idx] = vsd[idx];
    __syncthreads();

    const int n = blockIdx.x * 16 + (tid >> 4);
    const int l16 = tid & 15;
    const float* xp = x + (size_t)n * INC + l16 * 8;
    float4 xa = *(const float4*)xp;
    float4 xc = *(const float4*)(xp + 4);

    float o[8];
#pragma unroll
    for (int h = 0; h < 4; ++h) {
        const float* vp = vsS + h * 128 + l16 * 8;
        const float* dp = vsS + 512 + h * 128 + l16 * 8;
        o[h]     = xa.x * vp[0] + xa.y * vp[1] + xa.z * vp[2] + xa.w * vp[3]
                 + xc.x * vp[4] + xc.y * vp[5] + xc.z * vp[6] + xc.w * vp[7];
        o[4 + h] = xa.x * dp[0] + xa.y * dp[1] + xa.z * dp[2] + xa.w * dp[3]
                 + xc.x * dp[4] + xc.y * dp[5] + xc.z * dp[6] + xc.w * dp[7];
    }
#pragma unroll
    for (int off = 1; off < 16; off <<= 1)
#pragma unroll
        for (int v = 0; v < 8; ++v) o[v] += __shfl_xor(o[v], off);
    if (l16 == 0) {
        *(float4*)(as1 + n * 4) = make_float4(o[0], o[1], o[2], o[3]);
        *(float4*)(ad1 + n * 4) = make_float4(o[4], o[5], o[6], o[7]);
    }
}

// ================= edge softmax weights =================
__global__ void edge_w1k(const int* __restrict__ csr_src, const int* __restrict__ csr_dst,
                         const float* __restrict__ as1, const float* __restrict__ ad1,
                         float* __restrict__ w1e) {
    int i = blockIdx.x * 256 + threadIdx.x;
    if (i >= EP) return;
    int s = csr_src[i], d = csr_dst[i];
    float4 a = *(const float4*)(as1 + s * 4);
    float4 b = *(const float4*)(ad1 + d * 4);
    float4 o;
    float t;
    t = a.x + b.x; t = t > 0.f ? t : NEG * t; o.x = __expf(t);
    t = a.y + b.y; t = t > 0.f ? t : NEG * t; o.y = __expf(t);
    t = a.z + b.z; t = t > 0.f ? t : NEG * t; o.z = __expf(t);
    t = a.w + b.w; t = t > 0.f ? t : NEG * t; o.w = __expf(t);
    *(float4*)(w1e + (size_t)i * 4) = o;
}

__global__ void edge_w2k(const int* __restrict__ csr_src, const int* __restrict__ csr_dst,
                         const float* __restrict__ as2, const float* __restrict__ ad2,
                         float* __restrict__ w2e) {
    int i = blockIdx.x * 256 + threadIdx.x;
    if (i >= EP) return;
    float t = as2[csr_src[i]] + ad2[csr_dst[i]];
    t = t > 0.f ? t : NEG * t;
    w2e[i] = __expf(t);
}

// ================= conv1 aggregate of x (bf16): 16 lanes/node ================
__global__ __launch_bounds__(256) void conv1_agg(const int* __restrict__ rowptr,
                                                 const int* __restrict__ csr_src,
                                                 const float* __restrict__ w1e,
                                                 const unsigned short* __restrict__ xb,
                                                 unsigned short* __restrict__ xaggb) {
    const int tid = threadIdx.x;
    const int node = blockIdx.x * 16 + (tid >> 4);   // NN % 16 == 0
    const int l16 = tid & 15;
    const int beg = rowptr[node], end = rowptr[node + 1];

    float acc[4][8];
#pragma unroll
    for (int h = 0; h < 4; ++h)
#pragma unroll
        for (int j = 0; j < 8; ++j) acc[h][j] = 0.f;
    float sm[4] = {0.f, 0.f, 0.f, 0.f};

#pragma unroll 2
    for (int i = beg; i < end; ++i) {
        int s = csr_src[i];
        float4 w = *(const float4*)(w1e + (size_t)i * 4);
        bf16x8 xv = *(const bf16x8*)(xb + (size_t)s * INC + l16 * 8);
        float xf[8];
#pragma unroll
        for (int j = 0; j < 8; ++j) xf[j] = bf2f((unsigned short)xv[j]);
#pragma unroll
        for (int j = 0; j < 8; ++j) {
            acc[0][j] += w.x * xf[j];
            acc[1][j] += w.y * xf[j];
            acc[2][j] += w.z * xf[j];
            acc[3][j] += w.w * xf[j];
        }
        sm[0] += w.x; sm[1] += w.y; sm[2] += w.z; sm[3] += w.w;
    }

#pragma unroll
    for (int h = 0; h < 4; ++h) {
        const float rden = 1.f / (sm[h] + EPSS);
        bf16x8 ob;
#pragma unroll
        for (int j = 0; j < 8; ++j) ob[j] = (short)f2bf(acc[h][j] * rden);
        *(bf16x8*)(xaggb + ((size_t)node * 4 + h) * INC + l16 * 8) = ob;
    }
}

// ================= GEMM1 (post-agg): h1c = ELU(xagg @ W1 + b1), bf16 A =======
__global__ __launch_bounds__(256) void gemm1b(const unsigned short* __restrict__ xaggb,
                                              const unsigned short* __restrict__ w1h,
                                              const unsigned short* __restrict__ w1l,
                                              const float* __restrict__ b1,
                                              unsigned short* __restrict__ h1c) {
    __shared__ unsigned short wH[64 * KP1];
    __shared__ unsigned short wL[64 * KP1];
    const int tid = threadIdx.x;
    const int n0 = blockIdx.x * 64;
    const int q  = blockIdx.y;

    for (int idx = tid; idx < 64 * 16; idx += 256) {
        int col = idx >> 4, ch = idx & 15;
        *(bf16x8*)(wH + col * KP1 + ch * 8) =
            *(const bf16x8*)(w1h + ((q * 64 + col) << 7) + ch * 8);
        *(bf16x8*)(wL + col * KP1 + ch * 8) =
            *(const bf16x8*)(w1l + ((q * 64 + col) << 7) + ch * 8);
    }

    const int w = tid >> 6, l = tid & 63;
    const int cl = l & 15, g = l >> 4, g8 = g * 8;
    const int na = min(n0 + w * 16 + cl, NN - 1);

    bf16x8 aH[4];
#pragma unroll
    for (int kk = 0; kk < 4; ++kk)
        aH[kk] = *(const bf16x8*)(xaggb + ((size_t)na * 4 + q) * INC + kk * 32 + g8);

    f32x4 acc[4];
#pragma unroll
    for (int ct = 0; ct < 4; ++ct) acc[ct] = (f32x4){0.f, 0.f, 0.f, 0.f};

    __syncthreads();

#pragma unroll
    for (int kk = 0; kk < 4; ++kk) {
        const int ko = kk * 32 + g8;
#pragma unroll
        for (int ct = 0; ct < 4; ++ct) {
            const bf16x8 bH = *(const bf16x8*)(wH + (ct * 16 + cl) * KP1 + ko);
            const bf16x8 bL = *(const bf16x8*)(wL + (ct * 16 + cl) * KP1 + ko);
            acc[ct] = __builtin_amdgcn_mfma_f32_16x16x32_bf16(aH[kk], bH, acc[ct], 0, 0, 0);
            acc[ct] = __builtin_amdgcn_mfma_f32_16x16x32_bf16(aH[kk], bL, acc[ct], 0, 0, 0);
        }
    }

#pragma unroll
    for (int reg = 0; reg < 4; ++reg) {
        const int nd = n0 + w * 16 + g * 4 + reg;
        if (nd < NN) {
#pragma unroll
            for (int ct = 0; ct < 4; ++ct) {
                const int col = q * 64 + ct * 16 + cl;
                float o = acc[ct][reg] + b1[col];
                o = o > 0.f ? o : (__expf(o) - 1.f);
                h1c[(size_t)nd * C1 + col] = f2bf(o);
            }
        }
    }
}

// ================= GEMM2: bf16-A x split-bf16-W MFMA + att2 epilogue =========
__global__ __launch_bounds__(256) void gemm2_mfma(const unsigned short* __restrict__ h1c,
                                                  const unsigned short* __restrict__ w2h,
                                                  const unsigned short* __restrict__ w2l,
                                                  const float* __restrict__ att_s,
                                                  const float* __restrict__ att_d,
                                                  unsigned short* __restrict__ h2b,
                                                  float* __restrict__ as2,
                                                  float* __restrict__ ad2) {
    __shared__ unsigned short wH[64 * KP2];
    __shared__ unsigned short wL[64 * KP2];
    const int tid = threadIdx.x;
    const int n0 = blockIdx.x * 64;

    for (int idx = tid; idx < 64 * 32; idx += 256) {
        int col = idx >> 5, ch = idx & 31;
        *(bf16x8*)(wH + col * KP2 + ch * 8) =
            *(const bf16x8*)(w2h + ((col) << 8) + ch * 8);
        *(bf16x8*)(wL + col * KP2 + ch * 8) =
            *(const bf16x8*)(w2l + ((col) << 8) + ch * 8);
    }

    const int w = tid >> 6, l = tid & 63;
    const int cl = l & 15, g = l >> 4, g8 = g * 8;
    const int na = min(n0 + w * 16 + cl, NN - 1);

    f32x4 acc[4];
#pragma unroll
    for (int ct = 0; ct < 4; ++ct) acc[ct] = (f32x4){0.f, 0.f, 0.f, 0.f};

    __syncthreads();

#pragma unroll
    for (int kk = 0; kk < 8; ++kk) {
        const bf16x8 aH = *(const bf16x8*)(h1c + (size_t)na * C1 + kk * 32 + g8);
        const int ko = kk * 32 + g8;
#pragma unroll
        for (int ct = 0; ct < 4; ++ct) {
            const bf16x8 bH = *(const bf16x8*)(wH + (ct * 16 + cl) * KP2 + ko);
            const bf16x8 bL = *(const bf16x8*)(wL + (ct * 16 + cl) * KP2 + ko);
            acc[ct] = __builtin_amdgcn_mfma_f32_16x16x32_bf16(aH, bH, acc[ct], 0, 0, 0);
            acc[ct] = __builtin_amdgcn_mfma_f32_16x16x32_bf16(aH, bL, acc[ct], 0, 0, 0);
        }
    }

    float asc[4], adc[4];
#pragma unroll
    for (int ct = 0; ct < 4; ++ct) {
        asc[ct] = att_s[ct * 16 + cl];
        adc[ct] = att_d[ct * 16 + cl];
    }

#pragma unroll
    for (int reg = 0; reg < 4; ++reg) {
        const int nd = n0 + w * 16 + g * 4 + reg;
        float sa = 0.f, sd = 0.f;
#pragma unroll
        for (int ct = 0; ct < 4; ++ct) {
            sa += acc[ct][reg] * asc[ct];
            sd += acc[ct][reg] * adc[ct];
        }
#pragma unroll
        for (int off = 8; off > 0; off >>= 1) {
            sa += __shfl_xor(sa, off);
            sd += __shfl_xor(sd, off);
        }
        if (nd < NN) {
#pragma unroll
            for (int ct = 0; ct < 4; ++ct)
                h2b[(size_t)nd * HID + ct * 16 + cl] = f2bf(acc[ct][reg]);
            if (cl == 0) { as2[nd] = sa; ad2[nd] = sd; }
        }
    }
}

// ================= conv2 aggregate: 2 nodes/wave, precomputed weights =========
__global__ __launch_bounds__(256) void conv2_agg(const int* __restrict__ rowptr,
                                                 const int* __restrict__ csr_src,
                                                 const float* __restrict__ w2e,
                                                 const unsigned short* __restrict__ h2b,
                                                 const float* __restrict__ b2,
                                                 unsigned short* __restrict__ embb) {
    const int tid  = threadIdx.x;
    const int wid  = tid >> 6;
    const int l    = tid & 63;
    const int half = l >> 5;
    const int l32  = l & 31;
    const int node = blockIdx.x * 8 + wid * 2 + half;
    const int beg = rowptr[node], end = rowptr[node + 1];

    float a0 = 0.f, a1 = 0.f, sm = 0.f;
#pragma unroll 2
    for (int i = beg; i < end; ++i) {
        int s = csr_src[i];
        float w = w2e[i];
        unsigned hv = *(const unsigned*)(h2b + (size_t)s * HID + l32 * 2);
        a0 += w * bf2f((unsigned short)(hv & 0xFFFF));
        a1 += w * bf2f((unsigned short)(hv >> 16));
        sm += w;
    }
    const float rden = 1.f / (sm + EPSS);
    float o0 = a0 * rden + b2[l32 * 2];
    float o1 = a1 * rden + b2[l32 * 2 + 1];
    unsigned outw = (unsigned)f2bf(o0) | ((unsigned)f2bf(o1) << 16);
    *(unsigned*)(embb + (size_t)node * HID + l32 * 2) = outw;
}

// ================= edge MLP: swapped operands, 512 thr, 1 tile/wave ===========
#define NT_MLP (NE / 32)    // 25000
__global__ __launch_bounds__(512) void edge_mlp_mfma(const int* __restrict__ ei,
                                                     const unsigned short* __restrict__ embb,
                                                     const float* __restrict__ stats,
                                                     const unsigned short* __restrict__ wFh,
                                                     const unsigned short* __restrict__ wFl,
                                                     const float* __restrict__ mb1,
                                                     const float* __restrict__ mW2,
                                                     const float* __restrict__ mb2,
                                                     float* __restrict__ out) {
    __shared__ unsigned short sH[PREP_N2];   // 20 KB
    __shared__ unsigned short sL[PREP_N2];   // 20 KB
    __shared__ float biaS[64], w2aS[64], w2bS[64];
    const int tid = threadIdx.x;
    for (int idx = tid; idx < PREP_N2 / 8; idx += 512) {
        ((float4*)sH)[idx] = ((const float4*)wFh)[idx];
        ((float4*)sL)[idx] = ((const float4*)wFl)[idx];
    }
    if (tid < 64) {
        biaS[tid] = mb1[tid];
        w2aS[tid] = mW2[tid * 2];
        w2bS[tid] = mW2[tid * 2 + 1];
    }

    const int l  = tid & 63;
    const int cl = l & 15;
    const int g  = l >> 4;
    const int g8 = g * 8;
    const float ob0 = mb2[0], ob1 = mb2[1];

    const int t = blockIdx.x * 8 + (tid >> 6);   // 32-edge tile id

    bf16x8 a[2][5];
#pragma unroll
    for (int s = 0; s < 2; ++s) {
        const int ge_a = t * 32 + s * 16 + cl;
        const int rn = ei[ge_a];
        const int cn = ei[NE + ge_a];
        const unsigned short* rp = embb + (size_t)rn * HID;
        const unsigned short* cp = embb + (size_t)cn * HID;
        a[s][0] = *(const bf16x8*)(rp + g8);
        a[s][1] = *(const bf16x8*)(rp + 32 + g8);
        a[s][2] = *(const bf16x8*)(cp + g8);
        a[s][3] = *(const bf16x8*)(cp + 32 + g8);
        bf16x8 z = {0, 0, 0, 0, 0, 0, 0, 0};
        if (g == 0) {
            const float* sp = stats + (size_t)ge_a * 3;
            z[0] = (short)f2bf(sp[0]);
            z[1] = (short)f2bf(sp[1]);
            z[2] = (short)f2bf(sp[2]);
        }
        a[s][4] = z;
    }

    f32x4 acc[2][4];
#pragma unroll
    for (int s = 0; s < 2; ++s)
#pragma unroll
        for (int ct = 0; ct < 4; ++ct)
            acc[s][ct] = (f32x4){0.f, 0.f, 0.f, 0.f};

    __syncthreads();

#pragma unroll
    for (int kk = 0; kk < 5; ++kk) {
#pragma unroll
        for (int ct = 0; ct < 4; ++ct) {
            const int fo = ((kk * 4 + ct) * 64 + l) * 8;
            const bf16x8 wHf = *(const bf16x8*)(sH + fo);
            const bf16x8 wLf = *(const bf16x8*)(sL + fo);
#pragma unroll
            for (int s = 0; s < 2; ++s) {
                acc[s][ct] = __builtin_amdgcn_mfma_f32_16x16x32_bf16(wHf, a[s][kk], acc[s][ct], 0, 0, 0);
                acc[s][ct] = __builtin_amdgcn_mfma_f32_16x16x32_bf16(wLf, a[s][kk], acc[s][ct], 0, 0, 0);
            }
        }
    }

#pragma unroll
    for (int s = 0; s < 2; ++s) {
        float p0 = 0.f, p1 = 0.f;
#pragma unroll
        for (int ct = 0; ct < 4; ++ct) {
            const int hb = ct * 16 + g * 4;
            float4 bi = *(const float4*)(biaS + hb);
            float4 wa = *(const float4*)(w2aS + hb);
            float4 wb = *(const float4*)(w2bS + hb);
#pragma unroll
            for (int reg = 0; reg < 4; ++reg) {
                float bv = (reg == 0) ? bi.x : (reg == 1) ? bi.y : (reg == 2) ? bi.z : bi.w;
                float av = (reg == 0) ? wa.x : (reg == 1) ? wa.y : (reg == 2) ? wa.z : wa.w;
                float wv = (reg == 0) ? wb.x : (reg == 1) ? wb.y : (reg == 2) ? wb.z : wb.w;
                float h = fmaxf(acc[s][ct][reg] + bv, 0.f);
                p0 += h * av;
                p1 += h * wv;
            }
        }
        p0 += __shfl_xor(p0, 16); p0 += __shfl_xor(p0, 32);
        p1 += __shfl_xor(p1, 16); p1 += __shfl_xor(p1, 32);
        if (g == 0) {
            const int ge = t * 32 + s * 16 + cl;
            *(float2*)(out + (size_t)ge * 2) = make_float2(p0 + ob0, p1 + ob1);
        }
    }
}

// ================= launcher =================
extern "C" void kernel_launch(void* const* d_in, const int* in_sizes, int n_in,
                              void* d_out, int out_size, void* d_ws, size_t ws_size,
                              hipStream_t stream) {
    const float* x      = (const float*)d_in[0];
    const int*   ei     = (const int*)d_in[1];
    const float* stats  = (const float*)d_in[2];
    const float* W1     = (const float*)d_in[3];
    const float* att_s1 = (const float*)d_in[4];
    const float* att_d1 = (const float*)d_in[5];
    const float* b1     = (const float*)d_in[6];
    const float* W2     = (const float*)d_in[7];
    const float* att_s2 = (const float*)d_in[8];
    const float* att_d2 = (const float*)d_in[9];
    const float* b2     = (const float*)d_in[10];
    const float* mW1    = (const float*)d_in[11];
    const float* mb1    = (const float*)d_in[12];
    const float* mW2    = (const float*)d_in[13];
    const float* mb2    = (const float*)d_in[14];
    float* out = (float*)d_out;
    float* ws  = (float*)d_ws;

    // f32-word-offset layout (no aliasing; all chunks 16B-aligned)
    int*   rowptr  = (int*)ws;                                 // NN+16
    int*   csr_src = rowptr + NN + 16;                         // EP
    int*   csr_dst = csr_src + EP;                             // EP
    float* as1     = (float*)(csr_dst + EP);                   // 4NN
    float* ad1     = as1 + (size_t)4 * NN;                     // 4NN
    unsigned short* xb    = (unsigned short*)(ad1 + (size_t)4 * NN);  // NN*128 bf16
    unsigned short* xaggb = xb + (size_t)128 * NN;             // NN*512 bf16
    unsigned short* h1c   = xaggb + (size_t)512 * NN;          // NN*256 bf16
    unsigned short* h2b   = h1c + (size_t)256 * NN;            // NN*64 bf16
    unsigned short* embb  = h2b + (size_t)64 * NN;             // NN*64 bf16
    float* as2     = (float*)(embb + (size_t)64 * NN);         // NN
    float* ad2     = as2 + NN;                                 // NN
    unsigned short* w1h = (unsigned short*)(ad2 + NN);         // 256*128
    unsigned short* w1l = w1h + C1 * INC;
    unsigned short* w2h = w1l + C1 * INC;                      // 64*256
    unsigned short* w2l = w2h + HID * C1;
    unsigned short* wFh = w2l + HID * C1;                      // 10240
    unsigned short* wFl = wFh + PREP_N2;                       // 10240
    float* vsd     = (float*)(wFl + PREP_N2);                  // 1024
    float* w1e     = vsd + 1024;                               // 4*EP
    float* w2e     = w1e + (size_t)4 * EP;                     // EP
    int*   counts  = (int*)(w2e + EP + 64);                    // NN
    int*   bsum    = counts + NN + 64;                         // NSB
    int*   cursor  = bsum + NSB + 64;                          // NN

    // ---- CSR build + weight prep + projections ----
    hipMemsetAsync(counts, 0, NN * sizeof(int), stream);
    prep_all<<<(PREP_TOT + EP + 255) / 256, 256, 0, stream>>>(
        mW1, W1, W2, ei, x, att_s1, att_d1,
        w1h, w1l, w2h, w2l, wFh, wFl, vsd, xb, counts);
    scan_partial<<<NSB, SCHUNK, 0, stream>>>(counts, bsum);
    scan_top<<<1, 128, 0, stream>>>(bsum, rowptr);
    scan_final<<<NSB, SCHUNK, 0, stream>>>(counts, bsum, rowptr, cursor);
    csr_fill<<<(EP + 255) / 256, 256, 0, stream>>>(ei, cursor, csr_src);
    fill_dst<<<(NN + 255) / 256, 256, 0, stream>>>(rowptr, csr_dst);

    // ---- conv1: logits -> edge weights -> aggregate x -> GEMM ----
    att1_kernel<<<NN / 16, 256, 0, stream>>>(x, vsd, as1, ad1);
    edge_w1k<<<(EP + 255) / 256, 256, 0, stream>>>(csr_src, csr_dst, as1, ad1, w1e);
    conv1_agg<<<NN / 16, 256, 0, stream>>>(rowptr, csr_src, w1e, xb, xaggb);
    gemm1b<<<dim3((NN + 63) / 64, 4), 256, 0, stream>>>(xaggb, w1h, w1l, b1, h1c);

    // ---- conv2 ----
    gemm2_mfma<<<(NN + 63) / 64, 256, 0, stream>>>(h1c, w2h, w2l, att_s2, att_d2,
                                                   h2b, as2, ad2);
    edge_w2k<<<(EP + 255) / 256, 256, 0, stream>>>(csr_src, csr_dst, as2, ad2, w2e);
    conv2_agg<<<NN / 8, 256, 0, stream>>>(rowptr, csr_src, w2e, h2b, b2, embb);

    // ---- edge MLP: swapped-operand MFMA, 512 thr, 1 tile/wave ----
    edge_mlp_mfma<<<NT_MLP / 8, 512, 0, stream>>>(ei, embb, stats, wFh, wFl,
                                                  mb1, mW2, mb2, out);
}

// Round 22
// 296.968 us; speedup vs baseline: 1.1176x; 1.0668x over previous
//
#include <hip/hip_runtime.h>
#include <math.h>

#define NN 50000
#define NE 800000
#define EP (NE + NN)        // edges including self loops
#define INC 128
#define HID 64
#define HEADS 4
#define C1 (HEADS * HID)    // 256
#define NEG 0.2f
#define EPSS 1e-16f

#define SCHUNK 512
#define NSB ((NN + SCHUNK - 1) / SCHUNK)   // 98

#define KP1 136             // gemm1 W1^T LDS stride
#define KP2 264             // gemm2 W2^T LDS stride
typedef __attribute__((ext_vector_type(8))) short bf16x8;
typedef __attribute__((ext_vector_type(4))) float f32x4;

// ---------- bf16 helpers ----------
__device__ __forceinline__ unsigned short f2bf(float f) {
    unsigned u = __float_as_uint(f);
    unsigned r = (u + 0x7FFFu + ((u >> 16) & 1u)) >> 16;
    return (unsigned short)r;
}
__device__ __forceinline__ float bf2f(unsigned short b) {
    return __uint_as_float(((unsigned)b) << 16);
}

// ================= CSR scans =================
__global__ __launch_bounds__(SCHUNK) void scan_partial(const int* __restrict__ counts,
                                                       int* __restrict__ bsum) {
    __shared__ int lds[SCHUNK];
    int i = blockIdx.x * SCHUNK + threadIdx.x;
    lds[threadIdx.x] = (i < NN) ? counts[i] : 0;
    __syncthreads();
    for (int off = SCHUNK / 2; off > 0; off >>= 1) {
        if (threadIdx.x < off) lds[threadIdx.x] += lds[threadIdx.x + off];
        __syncthreads();
    }
    if (threadIdx.x == 0) bsum[blockIdx.x] = lds[0];
}

__global__ void scan_top(int* __restrict__ bsum, int* __restrict__ rowptr) {
    __shared__ int lds[NSB];
    int t = threadIdx.x;
    if (t < NSB) lds[t] = bsum[t];
    __syncthreads();
    if (t == 0) {
        int acc = 0;
        for (int i = 0; i < NSB; ++i) { int v = lds[i]; lds[i] = acc; acc += v; }
        rowptr[NN] = acc;   // == EP
    }
    __syncthreads();
    if (t < NSB) bsum[t] = lds[t];
}

__global__ __launch_bounds__(SCHUNK) void scan_final(const int* __restrict__ counts,
                                                     const int* __restrict__ bsum,
                                                     int* __restrict__ rowptr,
                                                     int* __restrict__ cursor) {
    __shared__ int lds[SCHUNK];
    int i = blockIdx.x * SCHUNK + threadIdx.x;
    int v = (i < NN) ? counts[i] : 0;
    lds[threadIdx.x] = v;
    __syncthreads();
    for (int off = 1; off < SCHUNK; off <<= 1) {
        int t = (threadIdx.x >= off) ? lds[threadIdx.x - off] : 0;
        __syncthreads();
        lds[threadIdx.x] += t;
        __syncthreads();
    }
    if (i < NN) {
        int excl = lds[threadIdx.x] - v + bsum[blockIdx.x];
        rowptr[i] = excl;
        cursor[i] = excl;
    }
}

// ================= XCD-partitioned CSR scatter =================
// Block's presumed XCD = blockIdx & 7 (round-robin dispatch). Each block
// commits only edges whose dst falls in its XCD's contiguous dst-range, so
// the scattered 4B writes for one csr_src region stay in ONE XCD's L2 and
// merge before writeback (vs 850k full-line write-throughs when all XCDs
// touch every line). Wrong mapping degrades speed only, never correctness.
#define NXCD 8
#define NSUB 104
#define DRANGE ((NN + NXCD - 1) / NXCD)   // 6250
__global__ __launch_bounds__(256) void csr_fill_x(const int* __restrict__ ei,
                                                  int* __restrict__ cursor,
                                                  int* __restrict__ csr_src) {
    const int x   = blockIdx.x & (NXCD - 1);
    const int sub = blockIdx.x >> 3;
    const int CH  = (EP + NSUB - 1) / NSUB;
    const int beg = sub * CH;
    const int end = min(beg + CH, EP);
    const int dlo = x * DRANGE;
    const int dhi = dlo + DRANGE;
    for (int e = beg + (int)threadIdx.x; e < end; e += 256) {
        int s, d;
        if (e < NE) { s = ei[e]; d = ei[NE + e]; } else { s = d = e - NE; }
        if (d >= dlo && d < dhi) {
            int pos = atomicAdd(&cursor[d], 1);
            csr_src[pos] = s;
        }
    }
}

// sequential coalesced fill of dst-per-position (node n owns rowptr[n]..rowptr[n+1])
__global__ void fill_dst(const int* __restrict__ rowptr, int* __restrict__ csr_dst) {
    int n = blockIdx.x * 256 + threadIdx.x;
    if (n >= NN) return;
    int beg = rowptr[n], end = rowptr[n + 1];
    for (int i = beg; i < end; ++i) csr_dst[i] = n;
}

// ================= merged weight prep + projections + edge count =============
#define PREP_N0 (C1 * INC)
#define PREP_N1 (HID * C1)
#define PREP_N2 (5 * 4 * 64 * 8)   // 10240
#define PREP_N3 1024
#define PREP_N4 (NN * INC)
#define PREP_TOT (PREP_N0 + PREP_N1 + PREP_N2 + PREP_N3 + PREP_N4)
__global__ void prep_all(const float* __restrict__ mW1, const float* __restrict__ W1,
                         const float* __restrict__ W2, const int* __restrict__ ei,
                         const float* __restrict__ x,
                         const float* __restrict__ att_s1, const float* __restrict__ att_d1,
                         unsigned short* __restrict__ w1h, unsigned short* __restrict__ w1l,
                         unsigned short* __restrict__ w2h, unsigned short* __restrict__ w2l,
                         unsigned short* __restrict__ wFh, unsigned short* __restrict__ wFl,
                         float* __restrict__ vsd, unsigned short* __restrict__ xb,
                         int* __restrict__ counts) {
    int i = blockIdx.x * 256 + threadIdx.x;
    if (i < PREP_N0) {
        int c = i >> 7, k = i & 127;
        float f = W1[k * C1 + c];
        unsigned short h = f2bf(f);
        w1h[i] = h; w1l[i] = f2bf(f - bf2f(h));
        return;
    }
    i -= PREP_N0;
    if (i < PREP_N1) {
        int c = i >> 8, k = i & 255;
        float f = W2[k * HID + c];
        unsigned short h = f2bf(f);
        w2h[i] = h; w2l[i] = f2bf(f - bf2f(h));
        return;
    }
    i -= PREP_N1;
    if (i < PREP_N2) {
        int kk = i >> 11;
        int ct = (i >> 9) & 3;
        int l  = (i >> 3) & 63;
        int j  = i & 7;
        int cl = l & 15, g = l >> 4;
        int k   = kk * 32 + g * 8 + j;
        int col = ct * 16 + cl;
        unsigned short h = 0, lo = 0;
        if (k < 131) {
            float f = mW1[k * 64 + col];
            h  = f2bf(f);
            lo = f2bf(f - bf2f(h));
        }
        wFh[i] = h;
        wFl[i] = lo;
        return;
    }
    i -= PREP_N2;
    if (i < PREP_N3) {
        int type = i >> 9;
        int rem  = i & 511;
        int h = rem >> 7, k = rem & 127;
        const float* att = type ? att_d1 : att_s1;
        float acc = 0.f;
        for (int c = 0; c < 64; ++c)
            acc += W1[k * C1 + h * 64 + c] * att[h * 64 + c];
        vsd[i] = acc;
        return;
    }
    i -= PREP_N3;
    if (i < PREP_N4) {
        xb[i] = f2bf(x[i]);
        return;
    }
    i -= PREP_N4;
    if (i < EP) {
        int d = (i < NE) ? ei[NE + i] : (i - NE);
        atomicAdd(&counts[d], 1);
    }
}

// ================= att1: as1/ad1 = x . (W1 @ att) — 16 lanes/node ============
__global__ __launch_bounds__(256) void att1_kernel(const float* __restrict__ x,
                                                   const float* __restrict__ vsd,
                                                   float* __restrict__ as1,
                                                   float* __restrict__ ad1) {
    __shared__ float vsS[1024];
    const int tid = threadIdx.x;
    for (int idx = tid; idx < 1024; idx += 256) vsS[idx] = vsd[idx];
    __syncthreads();

    const int n = blockIdx.x * 16 + (tid >> 4);
    const int l16 = tid & 15;
    const float* xp = x + (size_t)n * INC + l16 * 8;
    float4 xa = *(const float4*)xp;
    float4 xc = *(const float4*)(xp + 4);

    float o[8];
#pragma unroll
    for (int h = 0; h < 4; ++h) {
        const float* vp = vsS + h * 128 + l16 * 8;
        const float* dp = vsS + 512 + h * 128 + l16 * 8;
        o[h]     = xa.x * vp[0] + xa.y * vp[1] + xa.z * vp[2] + xa.w * vp[3]
                 + xc.x * vp[4] + xc.y * vp[5] + xc.z * vp[6] + xc.w * vp[7];
        o[4 + h] = xa.x * dp[0] + xa.y * dp[1] + xa.z * dp[2] + xa.w * dp[3]
                 + xc.x * dp[4] + xc.y * dp[5] + xc.z * dp[6] + xc.w * dp[7];
    }
#pragma unroll
    for (int off = 1; off < 16; off <<= 1)
#pragma unroll
        for (int v = 0; v < 8; ++v) o[v] += __shfl_xor(o[v], off);
    if (l16 == 0) {
        *(float4*)(as1 + n * 4) = make_float4(o[0], o[1], o[2], o[3]);
        *(float4*)(ad1 + n * 4) = make_float4(o[4], o[5], o[6], o[7]);
    }
}

// ================= edge softmax weights =================
__global__ void edge_w1k(const int* __restrict__ csr_src, const int* __restrict__ csr_dst,
                         const float* __restrict__ as1, const float* __restrict__ ad1,
                         float* __restrict__ w1e) {
    int i = blockIdx.x * 256 + threadIdx.x;
    if (i >= EP) return;
    int s = csr_src[i], d = csr_dst[i];
    float4 a = *(const float4*)(as1 + s * 4);
    float4 b = *(const float4*)(ad1 + d * 4);
    float4 o;
    float t;
    t = a.x + b.x; t = t > 0.f ? t : NEG * t; o.x = __expf(t);
    t = a.y + b.y; t = t > 0.f ? t : NEG * t; o.y = __expf(t);
    t = a.z + b.z; t = t > 0.f ? t : NEG * t; o.z = __expf(t);
    t = a.w + b.w; t = t > 0.f ? t : NEG * t; o.w = __expf(t);
    *(float4*)(w1e + (size_t)i * 4) = o;
}

__global__ void edge_w2k(const int* __restrict__ csr_src, const int* __restrict__ csr_dst,
                         const float* __restrict__ as2, const float* __restrict__ ad2,
                         float* __restrict__ w2e) {
    int i = blockIdx.x * 256 + threadIdx.x;
    if (i >= EP) return;
    float t = as2[csr_src[i]] + ad2[csr_dst[i]];
    t = t > 0.f ? t : NEG * t;
    w2e[i] = __expf(t);
}

// ================= conv1 aggregate of x (bf16): 16 lanes/node ================
__global__ __launch_bounds__(256) void conv1_agg(const int* __restrict__ rowptr,
                                                 const int* __restrict__ csr_src,
                                                 const float* __restrict__ w1e,
                                                 const unsigned short* __restrict__ xb,
                                                 unsigned short* __restrict__ xaggb) {
    const int tid = threadIdx.x;
    const int node = blockIdx.x * 16 + (tid >> 4);   // NN % 16 == 0
    const int l16 = tid & 15;
    const int beg = rowptr[node], end = rowptr[node + 1];

    float acc[4][8];
#pragma unroll
    for (int h = 0; h < 4; ++h)
#pragma unroll
        for (int j = 0; j < 8; ++j) acc[h][j] = 0.f;
    float sm[4] = {0.f, 0.f, 0.f, 0.f};

#pragma unroll 2
    for (int i = beg; i < end; ++i) {
        int s = csr_src[i];
        float4 w = *(const float4*)(w1e + (size_t)i * 4);
        bf16x8 xv = *(const bf16x8*)(xb + (size_t)s * INC + l16 * 8);
        float xf[8];
#pragma unroll
        for (int j = 0; j < 8; ++j) xf[j] = bf2f((unsigned short)xv[j]);
#pragma unroll
        for (int j = 0; j < 8; ++j) {
            acc[0][j] += w.x * xf[j];
            acc[1][j] += w.y * xf[j];
            acc[2][j] += w.z * xf[j];
            acc[3][j] += w.w * xf[j];
        }
        sm[0] += w.x; sm[1] += w.y; sm[2] += w.z; sm[3] += w.w;
    }

#pragma unroll
    for (int h = 0; h < 4; ++h) {
        const float rden = 1.f / (sm[h] + EPSS);
        bf16x8 ob;
#pragma unroll
        for (int j = 0; j < 8; ++j) ob[j] = (short)f2bf(acc[h][j] * rden);
        *(bf16x8*)(xaggb + ((size_t)node * 4 + h) * INC + l16 * 8) = ob;
    }
}

// ================= GEMM1 (post-agg): h1c = ELU(xagg @ W1 + b1), bf16 A =======
__global__ __launch_bounds__(256) void gemm1b(const unsigned short* __restrict__ xaggb,
                                              const unsigned short* __restrict__ w1h,
                                              const unsigned short* __restrict__ w1l,
                                              const float* __restrict__ b1,
                                              unsigned short* __restrict__ h1c) {
    __shared__ unsigned short wH[64 * KP1];
    __shared__ unsigned short wL[64 * KP1];
    const int tid = threadIdx.x;
    const int n0 = blockIdx.x * 64;
    const int q  = blockIdx.y;

    for (int idx = tid; idx < 64 * 16; idx += 256) {
        int col = idx >> 4, ch = idx & 15;
        *(bf16x8*)(wH + col * KP1 + ch * 8) =
            *(const bf16x8*)(w1h + ((q * 64 + col) << 7) + ch * 8);
        *(bf16x8*)(wL + col * KP1 + ch * 8) =
            *(const bf16x8*)(w1l + ((q * 64 + col) << 7) + ch * 8);
    }

    const int w = tid >> 6, l = tid & 63;
    const int cl = l & 15, g = l >> 4, g8 = g * 8;
    const int na = min(n0 + w * 16 + cl, NN - 1);

    bf16x8 aH[4];
#pragma unroll
    for (int kk = 0; kk < 4; ++kk)
        aH[kk] = *(const bf16x8*)(xaggb + ((size_t)na * 4 + q) * INC + kk * 32 + g8);

    f32x4 acc[4];
#pragma unroll
    for (int ct = 0; ct < 4; ++ct) acc[ct] = (f32x4){0.f, 0.f, 0.f, 0.f};

    __syncthreads();

#pragma unroll
    for (int kk = 0; kk < 4; ++kk) {
        const int ko = kk * 32 + g8;
#pragma unroll
        for (int ct = 0; ct < 4; ++ct) {
            const bf16x8 bH = *(const bf16x8*)(wH + (ct * 16 + cl) * KP1 + ko);
            const bf16x8 bL = *(const bf16x8*)(wL + (ct * 16 + cl) * KP1 + ko);
            acc[ct] = __builtin_amdgcn_mfma_f32_16x16x32_bf16(aH[kk], bH, acc[ct], 0, 0, 0);
            acc[ct] = __builtin_amdgcn_mfma_f32_16x16x32_bf16(aH[kk], bL, acc[ct], 0, 0, 0);
        }
    }

#pragma unroll
    for (int reg = 0; reg < 4; ++reg) {
        const int nd = n0 + w * 16 + g * 4 + reg;
        if (nd < NN) {
#pragma unroll
            for (int ct = 0; ct < 4; ++ct) {
                const int col = q * 64 + ct * 16 + cl;
                float o = acc[ct][reg] + b1[col];
                o = o > 0.f ? o : (__expf(o) - 1.f);
                h1c[(size_t)nd * C1 + col] = f2bf(o);
            }
        }
    }
}

// ================= GEMM2: bf16-A x split-bf16-W MFMA + att2 epilogue =========
__global__ __launch_bounds__(256) void gemm2_mfma(const unsigned short* __restrict__ h1c,
                                                  const unsigned short* __restrict__ w2h,
                                                  const unsigned short* __restrict__ w2l,
                                                  const float* __restrict__ att_s,
                                                  const float* __restrict__ att_d,
                                                  unsigned short* __restrict__ h2b,
                                                  float* __restrict__ as2,
                                                  float* __restrict__ ad2) {
    __shared__ unsigned short wH[64 * KP2];
    __shared__ unsigned short wL[64 * KP2];
    const int tid = threadIdx.x;
    const int n0 = blockIdx.x * 64;

    for (int idx = tid; idx < 64 * 32; idx += 256) {
        int col = idx >> 5, ch = idx & 31;
        *(bf16x8*)(wH + col * KP2 + ch * 8) =
            *(const bf16x8*)(w2h + ((col) << 8) + ch * 8);
        *(bf16x8*)(wL + col * KP2 + ch * 8) =
            *(const bf16x8*)(w2l + ((col) << 8) + ch * 8);
    }

    const int w = tid >> 6, l = tid & 63;
    const int cl = l & 15, g = l >> 4, g8 = g * 8;
    const int na = min(n0 + w * 16 + cl, NN - 1);

    f32x4 acc[4];
#pragma unroll
    for (int ct = 0; ct < 4; ++ct) acc[ct] = (f32x4){0.f, 0.f, 0.f, 0.f};

    __syncthreads();

#pragma unroll
    for (int kk = 0; kk < 8; ++kk) {
        const bf16x8 aH = *(const bf16x8*)(h1c + (size_t)na * C1 + kk * 32 + g8);
        const int ko = kk * 32 + g8;
#pragma unroll
        for (int ct = 0; ct < 4; ++ct) {
            const bf16x8 bH = *(const bf16x8*)(wH + (ct * 16 + cl) * KP2 + ko);
            const bf16x8 bL = *(const bf16x8*)(wL + (ct * 16 + cl) * KP2 + ko);
            acc[ct] = __builtin_amdgcn_mfma_f32_16x16x32_bf16(aH, bH, acc[ct], 0, 0, 0);
            acc[ct] = __builtin_amdgcn_mfma_f32_16x16x32_bf16(aH, bL, acc[ct], 0, 0, 0);
        }
    }

    float asc[4], adc[4];
#pragma unroll
    for (int ct = 0; ct < 4; ++ct) {
        asc[ct] = att_s[ct * 16 + cl];
        adc[ct] = att_d[ct * 16 + cl];
    }

#pragma unroll
    for (int reg = 0; reg < 4; ++reg) {
        const int nd = n0 + w * 16 + g * 4 + reg;
        float sa = 0.f, sd = 0.f;
#pragma unroll
        for (int ct = 0; ct < 4; ++ct) {
            sa += acc[ct][reg] * asc[ct];
            sd += acc[ct][reg] * adc[ct];
        }
#pragma unroll
        for (int off = 8; off > 0; off >>= 1) {
            sa += __shfl_xor(sa, off);
            sd += __shfl_xor(sd, off);
        }
        if (nd < NN) {
#pragma unroll
            for (int ct = 0; ct < 4; ++ct)
                h2b[(size_t)nd * HID + ct * 16 + cl] = f2bf(acc[ct][reg]);
            if (cl == 0) { as2[nd] = sa; ad2[nd] = sd; }
        }
    }
}

// ================= conv2 aggregate: 2 nodes/wave, precomputed weights =========
__global__ __launch_bounds__(256) void conv2_agg(const int* __restrict__ rowptr,
                                                 const int* __restrict__ csr_src,
                                                 const float* __restrict__ w2e,
                                                 const unsigned short* __restrict__ h2b,
                                                 const float* __restrict__ b2,
                                                 unsigned short* __restrict__ embb) {
    const int tid  = threadIdx.x;
    const int wid  = tid >> 6;
    const int l    = tid & 63;
    const int half = l >> 5;
    const int l32  = l & 31;
    const int node = blockIdx.x * 8 + wid * 2 + half;
    const int beg = rowptr[node], end = rowptr[node + 1];

    float a0 = 0.f, a1 = 0.f, sm = 0.f;
#pragma unroll 2
    for (int i = beg; i < end; ++i) {
        int s = csr_src[i];
        float w = w2e[i];
        unsigned hv = *(const unsigned*)(h2b + (size_t)s * HID + l32 * 2);
        a0 += w * bf2f((unsigned short)(hv & 0xFFFF));
        a1 += w * bf2f((unsigned short)(hv >> 16));
        sm += w;
    }
    const float rden = 1.f / (sm + EPSS);
    float o0 = a0 * rden + b2[l32 * 2];
    float o1 = a1 * rden + b2[l32 * 2 + 1];
    unsigned outw = (unsigned)f2bf(o0) | ((unsigned)f2bf(o1) << 16);
    *(unsigned*)(embb + (size_t)node * HID + l32 * 2) = outw;
}

// ================= edge MLP: swapped operands, 512 thr, 1 tile/wave ===========
#define NT_MLP (NE / 32)    // 25000
__global__ __launch_bounds__(512) void edge_mlp_mfma(const int* __restrict__ ei,
                                                     const unsigned short* __restrict__ embb,
                                                     const float* __restrict__ stats,
                                                     const unsigned short* __restrict__ wFh,
                                                     const unsigned short* __restrict__ wFl,
                                                     const float* __restrict__ mb1,
                                                     const float* __restrict__ mW2,
                                                     const float* __restrict__ mb2,
                                                     float* __restrict__ out) {
    __shared__ unsigned short sH[PREP_N2];   // 20 KB
    __shared__ unsigned short sL[PREP_N2];   // 20 KB
    __shared__ float biaS[64], w2aS[64], w2bS[64];
    const int tid = threadIdx.x;
    for (int idx = tid; idx < PREP_N2 / 8; idx += 512) {
        ((float4*)sH)[idx] = ((const float4*)wFh)[idx];
        ((float4*)sL)[idx] = ((const float4*)wFl)[idx];
    }
    if (tid < 64) {
        biaS[tid] = mb1[tid];
        w2aS[tid] = mW2[tid * 2];
        w2bS[tid] = mW2[tid * 2 + 1];
    }

    const int l  = tid & 63;
    const int cl = l & 15;
    const int g  = l >> 4;
    const int g8 = g * 8;
    const float ob0 = mb2[0], ob1 = mb2[1];

    const int t = blockIdx.x * 8 + (tid >> 6);   // 32-edge tile id

    bf16x8 a[2][5];
#pragma unroll
    for (int s = 0; s < 2; ++s) {
        const int ge_a = t * 32 + s * 16 + cl;
        const int rn = ei[ge_a];
        const int cn = ei[NE + ge_a];
        const unsigned short* rp = embb + (size_t)rn * HID;
        const unsigned short* cp = embb + (size_t)cn * HID;
        a[s][0] = *(const bf16x8*)(rp + g8);
        a[s][1] = *(const bf16x8*)(rp + 32 + g8);
        a[s][2] = *(const bf16x8*)(cp + g8);
        a[s][3] = *(const bf16x8*)(cp + 32 + g8);
        bf16x8 z = {0, 0, 0, 0, 0, 0, 0, 0};
        if (g == 0) {
            const float* sp = stats + (size_t)ge_a * 3;
            z[0] = (short)f2bf(sp[0]);
            z[1] = (short)f2bf(sp[1]);
            z[2] = (short)f2bf(sp[2]);
        }
        a[s][4] = z;
    }

    f32x4 acc[2][4];
#pragma unroll
    for (int s = 0; s < 2; ++s)
#pragma unroll
        for (int ct = 0; ct < 4; ++ct)
            acc[s][ct] = (f32x4){0.f, 0.f, 0.f, 0.f};

    __syncthreads();

#pragma unroll
    for (int kk = 0; kk < 5; ++kk) {
#pragma unroll
        for (int ct = 0; ct < 4; ++ct) {
            const int fo = ((kk * 4 + ct) * 64 + l) * 8;
            const bf16x8 wHf = *(const bf16x8*)(sH + fo);
            const bf16x8 wLf = *(const bf16x8*)(sL + fo);
#pragma unroll
            for (int s = 0; s < 2; ++s) {
                acc[s][ct] = __builtin_amdgcn_mfma_f32_16x16x32_bf16(wHf, a[s][kk], acc[s][ct], 0, 0, 0);
                acc[s][ct] = __builtin_amdgcn_mfma_f32_16x16x32_bf16(wLf, a[s][kk], acc[s][ct], 0, 0, 0);
            }
        }
    }

#pragma unroll
    for (int s = 0; s < 2; ++s) {
        float p0 = 0.f, p1 = 0.f;
#pragma unroll
        for (int ct = 0; ct < 4; ++ct) {
            const int hb = ct * 16 + g * 4;
            float4 bi = *(const float4*)(biaS + hb);
            float4 wa = *(const float4*)(w2aS + hb);
            float4 wb = *(const float4*)(w2bS + hb);
#pragma unroll
            for (int reg = 0; reg < 4; ++reg) {
                float bv = (reg == 0) ? bi.x : (reg == 1) ? bi.y : (reg == 2) ? bi.z : bi.w;
                float av = (reg == 0) ? wa.x : (reg == 1) ? wa.y : (reg == 2) ? wa.z : wa.w;
                float wv = (reg == 0) ? wb.x : (reg == 1) ? wb.y : (reg == 2) ? wb.z : wb.w;
                float h = fmaxf(acc[s][ct][reg] + bv, 0.f);
                p0 += h * av;
                p1 += h * wv;
            }
        }
        p0 += __shfl_xor(p0, 16); p0 += __shfl_xor(p0, 32);
        p1 += __shfl_xor(p1, 16); p1 += __shfl_xor(p1, 32);
        if (g == 0) {
            const int ge = t * 32 + s * 16 + cl;
            *(float2*)(out + (size_t)ge * 2) = make_float2(p0 + ob0, p1 + ob1);
        }
    }
}

// ================= launcher =================
extern "C" void kernel_launch(void* const* d_in, const int* in_sizes, int n_in,
                              void* d_out, int out_size, void* d_ws, size_t ws_size,
                              hipStream_t stream) {
    const float* x      = (const float*)d_in[0];
    const int*   ei     = (const int*)d_in[1];
    const float* stats  = (const float*)d_in[2];
    const float* W1     = (const float*)d_in[3];
    const float* att_s1 = (const float*)d_in[4];
    const float* att_d1 = (const float*)d_in[5];
    const float* b1     = (const float*)d_in[6];
    const float* W2     = (const float*)d_in[7];
    const float* att_s2 = (const float*)d_in[8];
    const float* att_d2 = (const float*)d_in[9];
    const float* b2     = (const float*)d_in[10];
    const float* mW1    = (const float*)d_in[11];
    const float* mb1    = (const float*)d_in[12];
    const float* mW2    = (const float*)d_in[13];
    const float* mb2    = (const float*)d_in[14];
    float* out = (float*)d_out;
    float* ws  = (float*)d_ws;

    // f32-word-offset layout (no aliasing; all chunks 16B-aligned)
    int*   rowptr  = (int*)ws;                                 // NN+16
    int*   csr_src = rowptr + NN + 16;                         // EP
    int*   csr_dst = csr_src + EP;                             // EP
    float* as1     = (float*)(csr_dst + EP);                   // 4NN
    float* ad1     = as1 + (size_t)4 * NN;                     // 4NN
    unsigned short* xb    = (unsigned short*)(ad1 + (size_t)4 * NN);  // NN*128 bf16
    unsigned short* xaggb = xb + (size_t)128 * NN;             // NN*512 bf16
    unsigned short* h1c   = xaggb + (size_t)512 * NN;          // NN*256 bf16
    unsigned short* h2b   = h1c + (size_t)256 * NN;            // NN*64 bf16
    unsigned short* embb  = h2b + (size_t)64 * NN;             // NN*64 bf16
    float* as2     = (float*)(embb + (size_t)64 * NN);         // NN
    float* ad2     = as2 + NN;                                 // NN
    unsigned short* w1h = (unsigned short*)(ad2 + NN);         // 256*128
    unsigned short* w1l = w1h + C1 * INC;
    unsigned short* w2h = w1l + C1 * INC;                      // 64*256
    unsigned short* w2l = w2h + HID * C1;
    unsigned short* wFh = w2l + HID * C1;                      // 10240
    unsigned short* wFl = wFh + PREP_N2;                       // 10240
    float* vsd     = (float*)(wFl + PREP_N2);                  // 1024
    float* w1e     = vsd + 1024;                               // 4*EP
    float* w2e     = w1e + (size_t)4 * EP;                     // EP
    int*   counts  = (int*)(w2e + EP + 64);                    // NN
    int*   bsum    = counts + NN + 64;                         // NSB
    int*   cursor  = bsum + NSB + 64;                          // NN

    // ---- CSR build + weight prep + projections ----
    hipMemsetAsync(counts, 0, NN * sizeof(int), stream);
    prep_all<<<(PREP_TOT + EP + 255) / 256, 256, 0, stream>>>(
        mW1, W1, W2, ei, x, att_s1, att_d1,
        w1h, w1l, w2h, w2l, wFh, wFl, vsd, xb, counts);
    scan_partial<<<NSB, SCHUNK, 0, stream>>>(counts, bsum);
    scan_top<<<1, 128, 0, stream>>>(bsum, rowptr);
    scan_final<<<NSB, SCHUNK, 0, stream>>>(counts, bsum, rowptr, cursor);
    csr_fill_x<<<NXCD * NSUB, 256, 0, stream>>>(ei, cursor, csr_src);
    fill_dst<<<(NN + 255) / 256, 256, 0, stream>>>(rowptr, csr_dst);

    // ---- conv1: logits -> edge weights -> aggregate x -> GEMM ----
    att1_kernel<<<NN / 16, 256, 0, stream>>>(x, vsd, as1, ad1);
    edge_w1k<<<(EP + 255) / 256, 256, 0, stream>>>(csr_src, csr_dst, as1, ad1, w1e);
    conv1_agg<<<NN / 16, 256, 0, stream>>>(rowptr, csr_src, w1e, xb, xaggb);
    gemm1b<<<dim3((NN + 63) / 64, 4), 256, 0, stream>>>(xaggb, w1h, w1l, b1, h1c);

    // ---- conv2 ----
    gemm2_mfma<<<(NN + 63) / 64, 256, 0, stream>>>(h1c, w2h, w2l, att_s2, att_d2,
                                                   h2b, as2, ad2);
    edge_w2k<<<(EP + 255) / 256, 256, 0, stream>>>(csr_src, csr_dst, as2, ad2, w2e);
    conv2_agg<<<NN / 8, 256, 0, stream>>>(rowptr, csr_src, w2e, h2b, b2, embb);

    // ---- edge MLP: swapped-operand MFMA, 512 thr, 1 tile/wave ----
    edge_mlp_mfma<<<NT_MLP / 8, 512, 0, stream>>>(ei, embb, stats, wFh, wFl,
                                                  mb1, mW2, mb2, out);
}

// Round 23
// 290.260 us; speedup vs baseline: 1.1434x; 1.0231x over previous
//
#include <hip/hip_runtime.h>
#include <math.h>

#define NN 50000
#define NE 800000
#define EP (NE + NN)        // edges including self loops
#define INC 128
#define HID 64
#define HEADS 4
#define C1 (HEADS * HID)    // 256
#define NEG 0.2f
#define EPSS 1e-16f

#define SCHUNK 512
#define NSB ((NN + SCHUNK - 1) / SCHUNK)   // 98

#define KP1 136             // gemm1 W1^T LDS stride
#define KP2 264             // gemm2 W2^T LDS stride
typedef __attribute__((ext_vector_type(8))) short bf16x8;
typedef __attribute__((ext_vector_type(4))) float f32x4;

// ---------- bf16 helpers ----------
__device__ __forceinline__ unsigned short f2bf(float f) {
    unsigned u = __float_as_uint(f);
    unsigned r = (u + 0x7FFFu + ((u >> 16) & 1u)) >> 16;
    return (unsigned short)r;
}
__device__ __forceinline__ float bf2f(unsigned short b) {
    return __uint_as_float(((unsigned)b) << 16);
}

// ================= CSR scans =================
__global__ __launch_bounds__(SCHUNK) void scan_partial(const int* __restrict__ counts,
                                                       int* __restrict__ bsum) {
    __shared__ int lds[SCHUNK];
    int i = blockIdx.x * SCHUNK + threadIdx.x;
    lds[threadIdx.x] = (i < NN) ? counts[i] : 0;
    __syncthreads();
    for (int off = SCHUNK / 2; off > 0; off >>= 1) {
        if (threadIdx.x < off) lds[threadIdx.x] += lds[threadIdx.x + off];
        __syncthreads();
    }
    if (threadIdx.x == 0) bsum[blockIdx.x] = lds[0];
}

__global__ void scan_top(int* __restrict__ bsum, int* __restrict__ rowptr) {
    __shared__ int lds[NSB];
    int t = threadIdx.x;
    if (t < NSB) lds[t] = bsum[t];
    __syncthreads();
    if (t == 0) {
        int acc = 0;
        for (int i = 0; i < NSB; ++i) { int v = lds[i]; lds[i] = acc; acc += v; }
        rowptr[NN] = acc;   // == EP
    }
    __syncthreads();
    if (t < NSB) bsum[t] = lds[t];
}

__global__ __launch_bounds__(SCHUNK) void scan_final(const int* __restrict__ counts,
                                                     const int* __restrict__ bsum,
                                                     int* __restrict__ rowptr,
                                                     int* __restrict__ cursor) {
    __shared__ int lds[SCHUNK];
    int i = blockIdx.x * SCHUNK + threadIdx.x;
    int v = (i < NN) ? counts[i] : 0;
    lds[threadIdx.x] = v;
    __syncthreads();
    for (int off = 1; off < SCHUNK; off <<= 1) {
        int t = (threadIdx.x >= off) ? lds[threadIdx.x - off] : 0;
        __syncthreads();
        lds[threadIdx.x] += t;
        __syncthreads();
    }
    if (i < NN) {
        int excl = lds[threadIdx.x] - v + bsum[blockIdx.x];
        rowptr[i] = excl;
        cursor[i] = excl;
    }
}

// ================= XCD-partitioned CSR scatter =================
#define NXCD 8
#define NSUB 104
#define DRANGE ((NN + NXCD - 1) / NXCD)   // 6250
__global__ __launch_bounds__(256) void csr_fill_x(const int* __restrict__ ei,
                                                  int* __restrict__ cursor,
                                                  int* __restrict__ csr_src) {
    const int x   = blockIdx.x & (NXCD - 1);
    const int sub = blockIdx.x >> 3;
    const int CH  = (EP + NSUB - 1) / NSUB;
    const int beg = sub * CH;
    const int end = min(beg + CH, EP);
    const int dlo = x * DRANGE;
    const int dhi = dlo + DRANGE;
    for (int e = beg + (int)threadIdx.x; e < end; e += 256) {
        int s, d;
        if (e < NE) { s = ei[e]; d = ei[NE + e]; } else { s = d = e - NE; }
        if (d >= dlo && d < dhi) {
            int pos = atomicAdd(&cursor[d], 1);
            csr_src[pos] = s;
        }
    }
}

// sequential coalesced fill of dst-per-position
__global__ void fill_dst(const int* __restrict__ rowptr, int* __restrict__ csr_dst) {
    int n = blockIdx.x * 256 + threadIdx.x;
    if (n >= NN) return;
    int beg = rowptr[n], end = rowptr[n + 1];
    for (int i = beg; i < end; ++i) csr_dst[i] = n;
}

// ================= merged weight prep + projections + edge count =============
#define PREP_N0 (C1 * INC)
#define PREP_N1 (HID * C1)
#define PREP_N2 (5 * 4 * 64 * 8)   // 10240
#define PREP_N3 1024
#define PREP_N4 (NN * INC)
#define PREP_TOT (PREP_N0 + PREP_N1 + PREP_N2 + PREP_N3 + PREP_N4)
__global__ void prep_all(const float* __restrict__ mW1, const float* __restrict__ W1,
                         const float* __restrict__ W2, const int* __restrict__ ei,
                         const float* __restrict__ x,
                         const float* __restrict__ att_s1, const float* __restrict__ att_d1,
                         unsigned short* __restrict__ w1h, unsigned short* __restrict__ w1l,
                         unsigned short* __restrict__ w2h, unsigned short* __restrict__ w2l,
                         unsigned short* __restrict__ wFh,
                         float* __restrict__ vsd, unsigned short* __restrict__ xb,
                         int* __restrict__ counts) {
    int i = blockIdx.x * 256 + threadIdx.x;
    if (i < PREP_N0) {
        int c = i >> 7, k = i & 127;
        float f = W1[k * C1 + c];
        unsigned short h = f2bf(f);
        w1h[i] = h; w1l[i] = f2bf(f - bf2f(h));
        return;
    }
    i -= PREP_N0;
    if (i < PREP_N1) {
        int c = i >> 8, k = i & 255;
        float f = W2[k * HID + c];
        unsigned short h = f2bf(f);
        w2h[i] = h; w2l[i] = f2bf(f - bf2f(h));
        return;
    }
    i -= PREP_N1;
    if (i < PREP_N2) {
        int kk = i >> 11;
        int ct = (i >> 9) & 3;
        int l  = (i >> 3) & 63;
        int j  = i & 7;
        int cl = l & 15, g = l >> 4;
        int k   = kk * 32 + g * 8 + j;
        int col = ct * 16 + cl;
        unsigned short h = 0;
        if (k < 131) h = f2bf(mW1[k * 64 + col]);
        wFh[i] = h;
        return;
    }
    i -= PREP_N2;
    if (i < PREP_N3) {
        int type = i >> 9;
        int rem  = i & 511;
        int h = rem >> 7, k = rem & 127;
        const float* att = type ? att_d1 : att_s1;
        float acc = 0.f;
        for (int c = 0; c < 64; ++c)
            acc += W1[k * C1 + h * 64 + c] * att[h * 64 + c];
        vsd[i] = acc;
        return;
    }
    i -= PREP_N3;
    if (i < PREP_N4) {
        xb[i] = f2bf(x[i]);
        return;
    }
    i -= PREP_N4;
    if (i < EP) {
        int d = (i < NE) ? ei[NE + i] : (i - NE);
        atomicAdd(&counts[d], 1);
    }
}

// ================= att1: as1/ad1 = x . (W1 @ att) — 16 lanes/node ============
__global__ __launch_bounds__(256) void att1_kernel(const float* __restrict__ x,
                                                   const float* __restrict__ vsd,
                                                   float* __restrict__ as1,
                                                   float* __restrict__ ad1) {
    __shared__ float vsS[1024];
    const int tid = threadIdx.x;
    for (int idx = tid; idx < 1024; idx += 256) vsS[idx] = vsd[idx];
    __syncthreads();

    const int n = blockIdx.x * 16 + (tid >> 4);
    const int l16 = tid & 15;
    const float* xp = x + (size_t)n * INC + l16 * 8;
    float4 xa = *(const float4*)xp;
    float4 xc = *(const float4*)(xp + 4);

    float o[8];
#pragma unroll
    for (int h = 0; h < 4; ++h) {
        const float* vp = vsS + h * 128 + l16 * 8;
        const float* dp = vsS + 512 + h * 128 + l16 * 8;
        o[h]     = xa.x * vp[0] + xa.y * vp[1] + xa.z * vp[2] + xa.w * vp[3]
                 + xc.x * vp[4] + xc.y * vp[5] + xc.z * vp[6] + xc.w * vp[7];
        o[4 + h] = xa.x * dp[0] + xa.y * dp[1] + xa.z * dp[2] + xa.w * dp[3]
                 + xc.x * dp[4] + xc.y * dp[5] + xc.z * dp[6] + xc.w * dp[7];
    }
#pragma unroll
    for (int off = 1; off < 16; off <<= 1)
#pragma unroll
        for (int v = 0; v < 8; ++v) o[v] += __shfl_xor(o[v], off);
    if (l16 == 0) {
        *(float4*)(as1 + n * 4) = make_float4(o[0], o[1], o[2], o[3]);
        *(float4*)(ad1 + n * 4) = make_float4(o[4], o[5], o[6], o[7]);
    }
}

// ================= edge softmax weights =================
__global__ void edge_w1k(const int* __restrict__ csr_src, const int* __restrict__ csr_dst,
                         const float* __restrict__ as1, const float* __restrict__ ad1,
                         float* __restrict__ w1e) {
    int i = blockIdx.x * 256 + threadIdx.x;
    if (i >= EP) return;
    int s = csr_src[i], d = csr_dst[i];
    float4 a = *(const float4*)(as1 + s * 4);
    float4 b = *(const float4*)(ad1 + d * 4);
    float4 o;
    float t;
    t = a.x + b.x; t = t > 0.f ? t : NEG * t; o.x = __expf(t);
    t = a.y + b.y; t = t > 0.f ? t : NEG * t; o.y = __expf(t);
    t = a.z + b.z; t = t > 0.f ? t : NEG * t; o.z = __expf(t);
    t = a.w + b.w; t = t > 0.f ? t : NEG * t; o.w = __expf(t);
    *(float4*)(w1e + (size_t)i * 4) = o;
}

__global__ void edge_w2k(const int* __restrict__ csr_src, const int* __restrict__ csr_dst,
                         const float* __restrict__ as2, const float* __restrict__ ad2,
                         float* __restrict__ w2e) {
    int i = blockIdx.x * 256 + threadIdx.x;
    if (i >= EP) return;
    float t = as2[csr_src[i]] + ad2[csr_dst[i]];
    t = t > 0.f ? t : NEG * t;
    w2e[i] = __expf(t);
}

// ================= conv1 aggregate of x (bf16): 16 lanes/node ================
__global__ __launch_bounds__(256) void conv1_agg(const int* __restrict__ rowptr,
                                                 const int* __restrict__ csr_src,
                                                 const float* __restrict__ w1e,
                                                 const unsigned short* __restrict__ xb,
                                                 unsigned short* __restrict__ xaggb) {
    const int tid = threadIdx.x;
    const int node = blockIdx.x * 16 + (tid >> 4);   // NN % 16 == 0
    const int l16 = tid & 15;
    const int beg = rowptr[node], end = rowptr[node + 1];

    float acc[4][8];
#pragma unroll
    for (int h = 0; h < 4; ++h)
#pragma unroll
        for (int j = 0; j < 8; ++j) acc[h][j] = 0.f;
    float sm[4] = {0.f, 0.f, 0.f, 0.f};

#pragma unroll 2
    for (int i = beg; i < end; ++i) {
        int s = csr_src[i];
        float4 w = *(const float4*)(w1e + (size_t)i * 4);
        bf16x8 xv = *(const bf16x8*)(xb + (size_t)s * INC + l16 * 8);
        float xf[8];
#pragma unroll
        for (int j = 0; j < 8; ++j) xf[j] = bf2f((unsigned short)xv[j]);
#pragma unroll
        for (int j = 0; j < 8; ++j) {
            acc[0][j] += w.x * xf[j];
            acc[1][j] += w.y * xf[j];
            acc[2][j] += w.z * xf[j];
            acc[3][j] += w.w * xf[j];
        }
        sm[0] += w.x; sm[1] += w.y; sm[2] += w.z; sm[3] += w.w;
    }

#pragma unroll
    for (int h = 0; h < 4; ++h) {
        const float rden = 1.f / (sm[h] + EPSS);
        bf16x8 ob;
#pragma unroll
        for (int j = 0; j < 8; ++j) ob[j] = (short)f2bf(acc[h][j] * rden);
        *(bf16x8*)(xaggb + ((size_t)node * 4 + h) * INC + l16 * 8) = ob;
    }
}

// ================= GEMM1 (post-agg): h1c = ELU(xagg @ W1 + b1), bf16 A =======
__global__ __launch_bounds__(256) void gemm1b(const unsigned short* __restrict__ xaggb,
                                              const unsigned short* __restrict__ w1h,
                                              const unsigned short* __restrict__ w1l,
                                              const float* __restrict__ b1,
                                              unsigned short* __restrict__ h1c) {
    __shared__ unsigned short wH[64 * KP1];
    __shared__ unsigned short wL[64 * KP1];
    const int tid = threadIdx.x;
    const int n0 = blockIdx.x * 64;
    const int q  = blockIdx.y;

    for (int idx = tid; idx < 64 * 16; idx += 256) {
        int col = idx >> 4, ch = idx & 15;
        *(bf16x8*)(wH + col * KP1 + ch * 8) =
            *(const bf16x8*)(w1h + ((q * 64 + col) << 7) + ch * 8);
        *(bf16x8*)(wL + col * KP1 + ch * 8) =
            *(const bf16x8*)(w1l + ((q * 64 + col) << 7) + ch * 8);
    }

    const int w = tid >> 6, l = tid & 63;
    const int cl = l & 15, g = l >> 4, g8 = g * 8;
    const int na = min(n0 + w * 16 + cl, NN - 1);

    bf16x8 aH[4];
#pragma unroll
    for (int kk = 0; kk < 4; ++kk)
        aH[kk] = *(const bf16x8*)(xaggb + ((size_t)na * 4 + q) * INC + kk * 32 + g8);

    f32x4 acc[4];
#pragma unroll
    for (int ct = 0; ct < 4; ++ct) acc[ct] = (f32x4){0.f, 0.f, 0.f, 0.f};

    __syncthreads();

#pragma unroll
    for (int kk = 0; kk < 4; ++kk) {
        const int ko = kk * 32 + g8;
#pragma unroll
        for (int ct = 0; ct < 4; ++ct) {
            const bf16x8 bH = *(const bf16x8*)(wH + (ct * 16 + cl) * KP1 + ko);
            const bf16x8 bL = *(const bf16x8*)(wL + (ct * 16 + cl) * KP1 + ko);
            acc[ct] = __builtin_amdgcn_mfma_f32_16x16x32_bf16(aH[kk], bH, acc[ct], 0, 0, 0);
            acc[ct] = __builtin_amdgcn_mfma_f32_16x16x32_bf16(aH[kk], bL, acc[ct], 0, 0, 0);
        }
    }

#pragma unroll
    for (int reg = 0; reg < 4; ++reg) {
        const int nd = n0 + w * 16 + g * 4 + reg;
        if (nd < NN) {
#pragma unroll
            for (int ct = 0; ct < 4; ++ct) {
                const int col = q * 64 + ct * 16 + cl;
                float o = acc[ct][reg] + b1[col];
                o = o > 0.f ? o : (__expf(o) - 1.f);
                h1c[(size_t)nd * C1 + col] = f2bf(o);
            }
        }
    }
}

// ================= GEMM2: bf16-A x split-bf16-W MFMA + att2 epilogue =========
__global__ __launch_bounds__(256) void gemm2_mfma(const unsigned short* __restrict__ h1c,
                                                  const unsigned short* __restrict__ w2h,
                                                  const unsigned short* __restrict__ w2l,
                                                  const float* __restrict__ att_s,
                                                  const float* __restrict__ att_d,
                                                  unsigned short* __restrict__ h2b,
                                                  float* __restrict__ as2,
                                                  float* __restrict__ ad2) {
    __shared__ unsigned short wH[64 * KP2];
    __shared__ unsigned short wL[64 * KP2];
    const int tid = threadIdx.x;
    const int n0 = blockIdx.x * 64;

    for (int idx = tid; idx < 64 * 32; idx += 256) {
        int col = idx >> 5, ch = idx & 31;
        *(bf16x8*)(wH + col * KP2 + ch * 8) =
            *(const bf16x8*)(w2h + ((col) << 8) + ch * 8);
        *(bf16x8*)(wL + col * KP2 + ch * 8) =
            *(const bf16x8*)(w2l + ((col) << 8) + ch * 8);
    }

    const int w = tid >> 6, l = tid & 63;
    const int cl = l & 15, g = l >> 4, g8 = g * 8;
    const int na = min(n0 + w * 16 + cl, NN - 1);

    f32x4 acc[4];
#pragma unroll
    for (int ct = 0; ct < 4; ++ct) acc[ct] = (f32x4){0.f, 0.f, 0.f, 0.f};

    __syncthreads();

#pragma unroll
    for (int kk = 0; kk < 8; ++kk) {
        const bf16x8 aH = *(const bf16x8*)(h1c + (size_t)na * C1 + kk * 32 + g8);
        const int ko = kk * 32 + g8;
#pragma unroll
        for (int ct = 0; ct < 4; ++ct) {
            const bf16x8 bH = *(const bf16x8*)(wH + (ct * 16 + cl) * KP2 + ko);
            const bf16x8 bL = *(const bf16x8*)(wL + (ct * 16 + cl) * KP2 + ko);
            acc[ct] = __builtin_amdgcn_mfma_f32_16x16x32_bf16(aH, bH, acc[ct], 0, 0, 0);
            acc[ct] = __builtin_amdgcn_mfma_f32_16x16x32_bf16(aH, bL, acc[ct], 0, 0, 0);
        }
    }

    float asc[4], adc[4];
#pragma unroll
    for (int ct = 0; ct < 4; ++ct) {
        asc[ct] = att_s[ct * 16 + cl];
        adc[ct] = att_d[ct * 16 + cl];
    }

#pragma unroll
    for (int reg = 0; reg < 4; ++reg) {
        const int nd = n0 + w * 16 + g * 4 + reg;
        float sa = 0.f, sd = 0.f;
#pragma unroll
        for (int ct = 0; ct < 4; ++ct) {
            sa += acc[ct][reg] * asc[ct];
            sd += acc[ct][reg] * adc[ct];
        }
#pragma unroll
        for (int off = 8; off > 0; off >>= 1) {
            sa += __shfl_xor(sa, off);
            sd += __shfl_xor(sd, off);
        }
        if (nd < NN) {
#pragma unroll
            for (int ct = 0; ct < 4; ++ct)
                h2b[(size_t)nd * HID + ct * 16 + cl] = f2bf(acc[ct][reg]);
            if (cl == 0) { as2[nd] = sa; ad2[nd] = sd; }
        }
    }
}

// ================= conv2 aggregate: 2 nodes/wave, precomputed weights =========
__global__ __launch_bounds__(256) void conv2_agg(const int* __restrict__ rowptr,
                                                 const int* __restrict__ csr_src,
                                                 const float* __restrict__ w2e,
                                                 const unsigned short* __restrict__ h2b,
                                                 const float* __restrict__ b2,
                                                 unsigned short* __restrict__ embb) {
    const int tid  = threadIdx.x;
    const int wid  = tid >> 6;
    const int l    = tid & 63;
    const int half = l >> 5;
    const int l32  = l & 31;
    const int node = blockIdx.x * 8 + wid * 2 + half;
    const int beg = rowptr[node], end = rowptr[node + 1];

    float a0 = 0.f, a1 = 0.f, sm = 0.f;
#pragma unroll 2
    for (int i = beg; i < end; ++i) {
        int s = csr_src[i];
        float w = w2e[i];
        unsigned hv = *(const unsigned*)(h2b + (size_t)s * HID + l32 * 2);
        a0 += w * bf2f((unsigned short)(hv & 0xFFFF));
        a1 += w * bf2f((unsigned short)(hv >> 16));
        sm += w;
    }
    const float rden = 1.f / (sm + EPSS);
    float o0 = a0 * rden + b2[l32 * 2];
    float o1 = a1 * rden + b2[l32 * 2 + 1];
    unsigned outw = (unsigned)f2bf(o0) | ((unsigned)f2bf(o1) << 16);
    *(unsigned*)(embb + (size_t)node * HID + l32 * 2) = outw;
}

// ================= edge MLP: swapped operands, bf16-only W (no low split) =====
// A (emb) is exact bf16; W1 rounded to bf16 adds ~1e-3 output error (under
// threshold). Halves MFMAs (40/tile) and LDS (21 KB) -> 4 blocks x 8 waves =
// full wave occupancy for gather-latency hiding.
#define NT_MLP (NE / 32)    // 25000
__global__ __launch_bounds__(512) void edge_mlp_mfma(const int* __restrict__ ei,
                                                     const unsigned short* __restrict__ embb,
                                                     const float* __restrict__ stats,
                                                     const unsigned short* __restrict__ wFh,
                                                     const float* __restrict__ mb1,
                                                     const float* __restrict__ mW2,
                                                     const float* __restrict__ mb2,
                                                     float* __restrict__ out) {
    __shared__ unsigned short sH[PREP_N2];   // 20 KB
    __shared__ float biaS[64], w2aS[64], w2bS[64];
    const int tid = threadIdx.x;
    for (int idx = tid; idx < PREP_N2 / 8; idx += 512)
        ((float4*)sH)[idx] = ((const float4*)wFh)[idx];
    if (tid < 64) {
        biaS[tid] = mb1[tid];
        w2aS[tid] = mW2[tid * 2];
        w2bS[tid] = mW2[tid * 2 + 1];
    }

    const int l  = tid & 63;
    const int cl = l & 15;
    const int g  = l >> 4;
    const int g8 = g * 8;
    const float ob0 = mb2[0], ob1 = mb2[1];

    const int t = blockIdx.x * 8 + (tid >> 6);   // 32-edge tile id

    bf16x8 a[2][5];
#pragma unroll
    for (int s = 0; s < 2; ++s) {
        const int ge_a = t * 32 + s * 16 + cl;
        const int rn = ei[ge_a];
        const int cn = ei[NE + ge_a];
        const unsigned short* rp = embb + (size_t)rn * HID;
        const unsigned short* cp = embb + (size_t)cn * HID;
        a[s][0] = *(const bf16x8*)(rp + g8);
        a[s][1] = *(const bf16x8*)(rp + 32 + g8);
        a[s][2] = *(const bf16x8*)(cp + g8);
        a[s][3] = *(const bf16x8*)(cp + 32 + g8);
        bf16x8 z = {0, 0, 0, 0, 0, 0, 0, 0};
        if (g == 0) {
            const float* sp = stats + (size_t)ge_a * 3;
            z[0] = (short)f2bf(sp[0]);
            z[1] = (short)f2bf(sp[1]);
            z[2] = (short)f2bf(sp[2]);
        }
        a[s][4] = z;
    }

    f32x4 acc[2][4];
#pragma unroll
    for (int s = 0; s < 2; ++s)
#pragma unroll
        for (int ct = 0; ct < 4; ++ct)
            acc[s][ct] = (f32x4){0.f, 0.f, 0.f, 0.f};

    __syncthreads();

#pragma unroll
    for (int kk = 0; kk < 5; ++kk) {
#pragma unroll
        for (int ct = 0; ct < 4; ++ct) {
            const int fo = ((kk * 4 + ct) * 64 + l) * 8;
            const bf16x8 wHf = *(const bf16x8*)(sH + fo);
#pragma unroll
            for (int s = 0; s < 2; ++s) {
                acc[s][ct] = __builtin_amdgcn_mfma_f32_16x16x32_bf16(wHf, a[s][kk], acc[s][ct], 0, 0, 0);
            }
        }
    }

#pragma unroll
    for (int s = 0; s < 2; ++s) {
        float p0 = 0.f, p1 = 0.f;
#pragma unroll
        for (int ct = 0; ct < 4; ++ct) {
            const int hb = ct * 16 + g * 4;
            float4 bi = *(const float4*)(biaS + hb);
            float4 wa = *(const float4*)(w2aS + hb);
            float4 wb = *(const float4*)(w2bS + hb);
#pragma unroll
            for (int reg = 0; reg < 4; ++reg) {
                float bv = (reg == 0) ? bi.x : (reg == 1) ? bi.y : (reg == 2) ? bi.z : bi.w;
                float av = (reg == 0) ? wa.x : (reg == 1) ? wa.y : (reg == 2) ? wa.z : wa.w;
                float wv = (reg == 0) ? wb.x : (reg == 1) ? wb.y : (reg == 2) ? wb.z : wb.w;
                float h = fmaxf(acc[s][ct][reg] + bv, 0.f);
                p0 += h * av;
                p1 += h * wv;
            }
        }
        p0 += __shfl_xor(p0, 16); p0 += __shfl_xor(p0, 32);
        p1 += __shfl_xor(p1, 16); p1 += __shfl_xor(p1, 32);
        if (g == 0) {
            const int ge = t * 32 + s * 16 + cl;
            *(float2*)(out + (size_t)ge * 2) = make_float2(p0 + ob0, p1 + ob1);
        }
    }
}

// ================= launcher =================
extern "C" void kernel_launch(void* const* d_in, const int* in_sizes, int n_in,
                              void* d_out, int out_size, void* d_ws, size_t ws_size,
                              hipStream_t stream) {
    const float* x      = (const float*)d_in[0];
    const int*   ei     = (const int*)d_in[1];
    const float* stats  = (const float*)d_in[2];
    const float* W1     = (const float*)d_in[3];
    const float* att_s1 = (const float*)d_in[4];
    const float* att_d1 = (const float*)d_in[5];
    const float* b1     = (const float*)d_in[6];
    const float* W2     = (const float*)d_in[7];
    const float* att_s2 = (const float*)d_in[8];
    const float* att_d2 = (const float*)d_in[9];
    const float* b2     = (const float*)d_in[10];
    const float* mW1    = (const float*)d_in[11];
    const float* mb1    = (const float*)d_in[12];
    const float* mW2    = (const float*)d_in[13];
    const float* mb2    = (const float*)d_in[14];
    float* out = (float*)d_out;
    float* ws  = (float*)d_ws;

    // f32-word-offset layout (no aliasing; all chunks 16B-aligned)
    int*   rowptr  = (int*)ws;                                 // NN+16
    int*   csr_src = rowptr + NN + 16;                         // EP
    int*   csr_dst = csr_src + EP;                             // EP
    float* as1     = (float*)(csr_dst + EP);                   // 4NN
    float* ad1     = as1 + (size_t)4 * NN;                     // 4NN
    unsigned short* xb    = (unsigned short*)(ad1 + (size_t)4 * NN);  // NN*128 bf16
    unsigned short* xaggb = xb + (size_t)128 * NN;             // NN*512 bf16
    unsigned short* h1c   = xaggb + (size_t)512 * NN;          // NN*256 bf16
    unsigned short* h2b   = h1c + (size_t)256 * NN;            // NN*64 bf16
    unsigned short* embb  = h2b + (size_t)64 * NN;             // NN*64 bf16
    float* as2     = (float*)(embb + (size_t)64 * NN);         // NN
    float* ad2     = as2 + NN;                                 // NN
    unsigned short* w1h = (unsigned short*)(ad2 + NN);         // 256*128
    unsigned short* w1l = w1h + C1 * INC;
    unsigned short* w2h = w1l + C1 * INC;                      // 64*256
    unsigned short* w2l = w2h + HID * C1;
    unsigned short* wFh = w2l + HID * C1;                      // 10240
    float* vsd     = (float*)(wFh + PREP_N2);                  // 1024
    float* w1e     = vsd + 1024;                               // 4*EP
    float* w2e     = w1e + (size_t)4 * EP;                     // EP
    int*   counts  = (int*)(w2e + EP + 64);                    // NN
    int*   bsum    = counts + NN + 64;                         // NSB
    int*   cursor  = bsum + NSB + 64;                          // NN

    // ---- CSR build + weight prep + projections ----
    hipMemsetAsync(counts, 0, NN * sizeof(int), stream);
    prep_all<<<(PREP_TOT + EP + 255) / 256, 256, 0, stream>>>(
        mW1, W1, W2, ei, x, att_s1, att_d1,
        w1h, w1l, w2h, w2l, wFh, vsd, xb, counts);
    scan_partial<<<NSB, SCHUNK, 0, stream>>>(counts, bsum);
    scan_top<<<1, 128, 0, stream>>>(bsum, rowptr);
    scan_final<<<NSB, SCHUNK, 0, stream>>>(counts, bsum, rowptr, cursor);
    csr_fill_x<<<NXCD * NSUB, 256, 0, stream>>>(ei, cursor, csr_src);
    fill_dst<<<(NN + 255) / 256, 256, 0, stream>>>(rowptr, csr_dst);

    // ---- conv1: logits -> edge weights -> aggregate x -> GEMM ----
    att1_kernel<<<NN / 16, 256, 0, stream>>>(x, vsd, as1, ad1);
    edge_w1k<<<(EP + 255) / 256, 256, 0, stream>>>(csr_src, csr_dst, as1, ad1, w1e);
    conv1_agg<<<NN / 16, 256, 0, stream>>>(rowptr, csr_src, w1e, xb, xaggb);
    gemm1b<<<dim3((NN + 63) / 64, 4), 256, 0, stream>>>(xaggb, w1h, w1l, b1, h1c);

    // ---- conv2 ----
    gemm2_mfma<<<(NN + 63) / 64, 256, 0, stream>>>(h1c, w2h, w2l, att_s2, att_d2,
                                                   h2b, as2, ad2);
    edge_w2k<<<(EP + 255) / 256, 256, 0, stream>>>(csr_src, csr_dst, as2, ad2, w2e);
    conv2_agg<<<NN / 8, 256, 0, stream>>>(rowptr, csr_src, w2e, h2b, b2, embb);

    // ---- edge MLP: swapped-operand MFMA, bf16-only W, 512 thr ----
    edge_mlp_mfma<<<NT_MLP / 8, 512, 0, stream>>>(ei, embb, stats, wFh,
                                                  mb1, mW2, mb2, out);
}

// Round 24
// 288.971 us; speedup vs baseline: 1.1485x; 1.0045x over previous
//
#include <hip/hip_runtime.h>
#include <math.h>

#define NN 50000
#define NE 800000
#define EP (NE + NN)        // edges including self loops
#define INC 128
#define HID 64
#define HEADS 4
#define C1 (HEADS * HID)    // 256
#define NEG 0.2f
#define EPSS 1e-16f

#define SCHUNK 512
#define NSB ((NN + SCHUNK - 1) / SCHUNK)   // 98

#define KP1 136             // gemm1 W1^T LDS stride
#define KP2 264             // gemm2 W2^T LDS stride
typedef __attribute__((ext_vector_type(8))) short bf16x8;
typedef __attribute__((ext_vector_type(4))) float f32x4;

// ---------- bf16 helpers ----------
__device__ __forceinline__ unsigned short f2bf(float f) {
    unsigned u = __float_as_uint(f);
    unsigned r = (u + 0x7FFFu + ((u >> 16) & 1u)) >> 16;
    return (unsigned short)r;
}
__device__ __forceinline__ float bf2f(unsigned short b) {
    return __uint_as_float(((unsigned)b) << 16);
}

// ================= CSR scans =================
__global__ __launch_bounds__(SCHUNK) void scan_partial(const int* __restrict__ counts,
                                                       int* __restrict__ bsum) {
    __shared__ int lds[SCHUNK];
    int i = blockIdx.x * SCHUNK + threadIdx.x;
    lds[threadIdx.x] = (i < NN) ? counts[i] : 0;
    __syncthreads();
    for (int off = SCHUNK / 2; off > 0; off >>= 1) {
        if (threadIdx.x < off) lds[threadIdx.x] += lds[threadIdx.x + off];
        __syncthreads();
    }
    if (threadIdx.x == 0) bsum[blockIdx.x] = lds[0];
}

__global__ void scan_top(int* __restrict__ bsum, int* __restrict__ rowptr) {
    __shared__ int lds[NSB];
    int t = threadIdx.x;
    if (t < NSB) lds[t] = bsum[t];
    __syncthreads();
    if (t == 0) {
        int acc = 0;
        for (int i = 0; i < NSB; ++i) { int v = lds[i]; lds[i] = acc; acc += v; }
        rowptr[NN] = acc;   // == EP
    }
    __syncthreads();
    if (t < NSB) bsum[t] = lds[t];
}

__global__ __launch_bounds__(SCHUNK) void scan_final(const int* __restrict__ counts,
                                                     const int* __restrict__ bsum,
                                                     int* __restrict__ rowptr,
                                                     int* __restrict__ cursor) {
    __shared__ int lds[SCHUNK];
    int i = blockIdx.x * SCHUNK + threadIdx.x;
    int v = (i < NN) ? counts[i] : 0;
    lds[threadIdx.x] = v;
    __syncthreads();
    for (int off = 1; off < SCHUNK; off <<= 1) {
        int t = (threadIdx.x >= off) ? lds[threadIdx.x - off] : 0;
        __syncthreads();
        lds[threadIdx.x] += t;
        __syncthreads();
    }
    if (i < NN) {
        int excl = lds[threadIdx.x] - v + bsum[blockIdx.x];
        rowptr[i] = excl;
        cursor[i] = excl;
    }
}

// ================= XCD-partitioned histogram + CSR scatter =================
#define NXCD 8
#define NSUB 104
#define DRANGE ((NN + NXCD - 1) / NXCD)   // 6250
__global__ __launch_bounds__(256) void count_x(const int* __restrict__ ei,
                                               int* __restrict__ counts) {
    const int x   = blockIdx.x & (NXCD - 1);
    const int sub = blockIdx.x >> 3;
    const int CH  = (EP + NSUB - 1) / NSUB;
    const int beg = sub * CH;
    const int end = min(beg + CH, EP);
    const int dlo = x * DRANGE;
    const int dhi = dlo + DRANGE;
    for (int e = beg + (int)threadIdx.x; e < end; e += 256) {
        int d = (e < NE) ? ei[NE + e] : (e - NE);
        if (d >= dlo && d < dhi) atomicAdd(&counts[d], 1);
    }
}

__global__ __launch_bounds__(256) void csr_fill_x(const int* __restrict__ ei,
                                                  int* __restrict__ cursor,
                                                  int* __restrict__ csr_src) {
    const int x   = blockIdx.x & (NXCD - 1);
    const int sub = blockIdx.x >> 3;
    const int CH  = (EP + NSUB - 1) / NSUB;
    const int beg = sub * CH;
    const int end = min(beg + CH, EP);
    const int dlo = x * DRANGE;
    const int dhi = dlo + DRANGE;
    for (int e = beg + (int)threadIdx.x; e < end; e += 256) {
        int s, d;
        if (e < NE) { s = ei[e]; d = ei[NE + e]; } else { s = d = e - NE; }
        if (d >= dlo && d < dhi) {
            int pos = atomicAdd(&cursor[d], 1);
            csr_src[pos] = s;
        }
    }
}

// sequential coalesced fill of dst-per-position
__global__ void fill_dst(const int* __restrict__ rowptr, int* __restrict__ csr_dst) {
    int n = blockIdx.x * 256 + threadIdx.x;
    if (n >= NN) return;
    int beg = rowptr[n], end = rowptr[n + 1];
    for (int i = beg; i < end; ++i) csr_dst[i] = n;
}

// ================= merged weight prep + projections (no counts) =============
// R0: W1^T hi/lo; R1: W2^T hi/lo; R2: mW1 fragment-linear (bf16 only)
// R3: vsd projections; R4: xb = bf16(x), 8 elems/thread (vectorized)
#define PREP_N0 (C1 * INC)
#define PREP_N1 (HID * C1)
#define PREP_N2 (5 * 4 * 64 * 8)   // 10240
#define PREP_N3 1024
#define PREP_N4 (NN * INC / 8)     // 800000 threads, 8 elems each
#define PREP_TOT (PREP_N0 + PREP_N1 + PREP_N2 + PREP_N3 + PREP_N4)
__global__ void prep_all(const float* __restrict__ mW1, const float* __restrict__ W1,
                         const float* __restrict__ W2,
                         const float* __restrict__ x,
                         const float* __restrict__ att_s1, const float* __restrict__ att_d1,
                         unsigned short* __restrict__ w1h, unsigned short* __restrict__ w1l,
                         unsigned short* __restrict__ w2h, unsigned short* __restrict__ w2l,
                         unsigned short* __restrict__ wFh,
                         float* __restrict__ vsd, unsigned short* __restrict__ xb) {
    int i = blockIdx.x * 256 + threadIdx.x;
    if (i < PREP_N0) {
        int c = i >> 7, k = i & 127;
        float f = W1[k * C1 + c];
        unsigned short h = f2bf(f);
        w1h[i] = h; w1l[i] = f2bf(f - bf2f(h));
        return;
    }
    i -= PREP_N0;
    if (i < PREP_N1) {
        int c = i >> 8, k = i & 255;
        float f = W2[k * HID + c];
        unsigned short h = f2bf(f);
        w2h[i] = h; w2l[i] = f2bf(f - bf2f(h));
        return;
    }
    i -= PREP_N1;
    if (i < PREP_N2) {
        int kk = i >> 11;
        int ct = (i >> 9) & 3;
        int l  = (i >> 3) & 63;
        int j  = i & 7;
        int cl = l & 15, g = l >> 4;
        int k   = kk * 32 + g * 8 + j;
        int col = ct * 16 + cl;
        unsigned short h = 0;
        if (k < 131) h = f2bf(mW1[k * 64 + col]);
        wFh[i] = h;
        return;
    }
    i -= PREP_N2;
    if (i < PREP_N3) {
        int type = i >> 9;
        int rem  = i & 511;
        int h = rem >> 7, k = rem & 127;
        const float* att = type ? att_d1 : att_s1;
        float acc = 0.f;
        for (int c = 0; c < 64; ++c)
            acc += W1[k * C1 + h * 64 + c] * att[h * 64 + c];
        vsd[i] = acc;
        return;
    }
    i -= PREP_N3;
    if (i < PREP_N4) {
        const float* xp = x + (size_t)i * 8;
        float4 v0 = *(const float4*)xp;
        float4 v1 = *(const float4*)(xp + 4);
        bf16x8 ob;
        ob[0] = (short)f2bf(v0.x); ob[1] = (short)f2bf(v0.y);
        ob[2] = (short)f2bf(v0.z); ob[3] = (short)f2bf(v0.w);
        ob[4] = (short)f2bf(v1.x); ob[5] = (short)f2bf(v1.y);
        ob[6] = (short)f2bf(v1.z); ob[7] = (short)f2bf(v1.w);
        *(bf16x8*)(xb + (size_t)i * 8) = ob;
        return;
    }
}

// ================= att1: as1/ad1 = x . (W1 @ att) — 16 lanes/node ============
__global__ __launch_bounds__(256) void att1_kernel(const float* __restrict__ x,
                                                   const float* __restrict__ vsd,
                                                   float* __restrict__ as1,
                                                   float* __restrict__ ad1) {
    __shared__ float vsS[1024];
    const int tid = threadIdx.x;
    for (int idx = tid; idx < 1024; idx += 256) vsS[idx] = vsd[idx];
    __syncthreads();

    const int n = blockIdx.x * 16 + (tid >> 4);
    const int l16 = tid & 15;
    const float* xp = x + (size_t)n * INC + l16 * 8;
    float4 xa = *(const float4*)xp;
    float4 xc = *(const float4*)(xp + 4);

    float o[8];
#pragma unroll
    for (int h = 0; h < 4; ++h) {
        const float* vp = vsS + h * 128 + l16 * 8;
        const float* dp = vsS + 512 + h * 128 + l16 * 8;
        o[h]     = xa.x * vp[0] + xa.y * vp[1] + xa.z * vp[2] + xa.w * vp[3]
                 + xc.x * vp[4] + xc.y * vp[5] + xc.z * vp[6] + xc.w * vp[7];
        o[4 + h] = xa.x * dp[0] + xa.y * dp[1] + xa.z * dp[2] + xa.w * dp[3]
                 + xc.x * dp[4] + xc.y * dp[5] + xc.z * dp[6] + xc.w * dp[7];
    }
#pragma unroll
    for (int off = 1; off < 16; off <<= 1)
#pragma unroll
        for (int v = 0; v < 8; ++v) o[v] += __shfl_xor(o[v], off);
    if (l16 == 0) {
        *(float4*)(as1 + n * 4) = make_float4(o[0], o[1], o[2], o[3]);
        *(float4*)(ad1 + n * 4) = make_float4(o[4], o[5], o[6], o[7]);
    }
}

// ================= edge softmax weights =================
__global__ void edge_w1k(const int* __restrict__ csr_src, const int* __restrict__ csr_dst,
                         const float* __restrict__ as1, const float* __restrict__ ad1,
                         float* __restrict__ w1e) {
    int i = blockIdx.x * 256 + threadIdx.x;
    if (i >= EP) return;
    int s = csr_src[i], d = csr_dst[i];
    float4 a = *(const float4*)(as1 + s * 4);
    float4 b = *(const float4*)(ad1 + d * 4);
    float4 o;
    float t;
    t = a.x + b.x; t = t > 0.f ? t : NEG * t; o.x = __expf(t);
    t = a.y + b.y; t = t > 0.f ? t : NEG * t; o.y = __expf(t);
    t = a.z + b.z; t = t > 0.f ? t : NEG * t; o.z = __expf(t);
    t = a.w + b.w; t = t > 0.f ? t : NEG * t; o.w = __expf(t);
    *(float4*)(w1e + (size_t)i * 4) = o;
}

__global__ void edge_w2k(const int* __restrict__ csr_src, const int* __restrict__ csr_dst,
                         const float* __restrict__ as2, const float* __restrict__ ad2,
                         float* __restrict__ w2e) {
    int i = blockIdx.x * 256 + threadIdx.x;
    if (i >= EP) return;
    float t = as2[csr_src[i]] + ad2[csr_dst[i]];
    t = t > 0.f ? t : NEG * t;
    w2e[i] = __expf(t);
}

// ================= conv1 aggregate of x (bf16): 16 lanes/node ================
__global__ __launch_bounds__(256) void conv1_agg(const int* __restrict__ rowptr,
                                                 const int* __restrict__ csr_src,
                                                 const float* __restrict__ w1e,
                                                 const unsigned short* __restrict__ xb,
                                                 unsigned short* __restrict__ xaggb) {
    const int tid = threadIdx.x;
    const int node = blockIdx.x * 16 + (tid >> 4);   // NN % 16 == 0
    const int l16 = tid & 15;
    const int beg = rowptr[node], end = rowptr[node + 1];

    float acc[4][8];
#pragma unroll
    for (int h = 0; h < 4; ++h)
#pragma unroll
        for (int j = 0; j < 8; ++j) acc[h][j] = 0.f;
    float sm[4] = {0.f, 0.f, 0.f, 0.f};

#pragma unroll 2
    for (int i = beg; i < end; ++i) {
        int s = csr_src[i];
        float4 w = *(const float4*)(w1e + (size_t)i * 4);
        bf16x8 xv = *(const bf16x8*)(xb + (size_t)s * INC + l16 * 8);
        float xf[8];
#pragma unroll
        for (int j = 0; j < 8; ++j) xf[j] = bf2f((unsigned short)xv[j]);
#pragma unroll
        for (int j = 0; j < 8; ++j) {
            acc[0][j] += w.x * xf[j];
            acc[1][j] += w.y * xf[j];
            acc[2][j] += w.z * xf[j];
            acc[3][j] += w.w * xf[j];
        }
        sm[0] += w.x; sm[1] += w.y; sm[2] += w.z; sm[3] += w.w;
    }

#pragma unroll
    for (int h = 0; h < 4; ++h) {
        const float rden = 1.f / (sm[h] + EPSS);
        bf16x8 ob;
#pragma unroll
        for (int j = 0; j < 8; ++j) ob[j] = (short)f2bf(acc[h][j] * rden);
        *(bf16x8*)(xaggb + ((size_t)node * 4 + h) * INC + l16 * 8) = ob;
    }
}

// ================= GEMM1 (post-agg): h1c = ELU(xagg @ W1 + b1), bf16 A =======
__global__ __launch_bounds__(256) void gemm1b(const unsigned short* __restrict__ xaggb,
                                              const unsigned short* __restrict__ w1h,
                                              const unsigned short* __restrict__ w1l,
                                              const float* __restrict__ b1,
                                              unsigned short* __restrict__ h1c) {
    __shared__ unsigned short wH[64 * KP1];
    __shared__ unsigned short wL[64 * KP1];
    const int tid = threadIdx.x;
    const int n0 = blockIdx.x * 64;
    const int q  = blockIdx.y;

    for (int idx = tid; idx < 64 * 16; idx += 256) {
        int col = idx >> 4, ch = idx & 15;
        *(bf16x8*)(wH + col * KP1 + ch * 8) =
            *(const bf16x8*)(w1h + ((q * 64 + col) << 7) + ch * 8);
        *(bf16x8*)(wL + col * KP1 + ch * 8) =
            *(const bf16x8*)(w1l + ((q * 64 + col) << 7) + ch * 8);
    }

    const int w = tid >> 6, l = tid & 63;
    const int cl = l & 15, g = l >> 4, g8 = g * 8;
    const int na = min(n0 + w * 16 + cl, NN - 1);

    bf16x8 aH[4];
#pragma unroll
    for (int kk = 0; kk < 4; ++kk)
        aH[kk] = *(const bf16x8*)(xaggb + ((size_t)na * 4 + q) * INC + kk * 32 + g8);

    f32x4 acc[4];
#pragma unroll
    for (int ct = 0; ct < 4; ++ct) acc[ct] = (f32x4){0.f, 0.f, 0.f, 0.f};

    __syncthreads();

#pragma unroll
    for (int kk = 0; kk < 4; ++kk) {
        const int ko = kk * 32 + g8;
#pragma unroll
        for (int ct = 0; ct < 4; ++ct) {
            const bf16x8 bH = *(const bf16x8*)(wH + (ct * 16 + cl) * KP1 + ko);
            const bf16x8 bL = *(const bf16x8*)(wL + (ct * 16 + cl) * KP1 + ko);
            acc[ct] = __builtin_amdgcn_mfma_f32_16x16x32_bf16(aH[kk], bH, acc[ct], 0, 0, 0);
            acc[ct] = __builtin_amdgcn_mfma_f32_16x16x32_bf16(aH[kk], bL, acc[ct], 0, 0, 0);
        }
    }

#pragma unroll
    for (int reg = 0; reg < 4; ++reg) {
        const int nd = n0 + w * 16 + g * 4 + reg;
        if (nd < NN) {
#pragma unroll
            for (int ct = 0; ct < 4; ++ct) {
                const int col = q * 64 + ct * 16 + cl;
                float o = acc[ct][reg] + b1[col];
                o = o > 0.f ? o : (__expf(o) - 1.f);
                h1c[(size_t)nd * C1 + col] = f2bf(o);
            }
        }
    }
}

// ================= GEMM2: bf16-A x split-bf16-W MFMA + att2 epilogue =========
__global__ __launch_bounds__(256) void gemm2_mfma(const unsigned short* __restrict__ h1c,
                                                  const unsigned short* __restrict__ w2h,
                                                  const unsigned short* __restrict__ w2l,
                                                  const float* __restrict__ att_s,
                                                  const float* __restrict__ att_d,
                                                  unsigned short* __restrict__ h2b,
                                                  float* __restrict__ as2,
                                                  float* __restrict__ ad2) {
    __shared__ unsigned short wH[64 * KP2];
    __shared__ unsigned short wL[64 * KP2];
    const int tid = threadIdx.x;
    const int n0 = blockIdx.x * 64;

    for (int idx = tid; idx < 64 * 32; idx += 256) {
        int col = idx >> 5, ch = idx & 31;
        *(bf16x8*)(wH + col * KP2 + ch * 8) =
            *(const bf16x8*)(w2h + ((col) << 8) + ch * 8);
        *(bf16x8*)(wL + col * KP2 + ch * 8) =
            *(const bf16x8*)(w2l + ((col) << 8) + ch * 8);
    }

    const int w = tid >> 6, l = tid & 63;
    const int cl = l & 15, g = l >> 4, g8 = g * 8;
    const int na = min(n0 + w * 16 + cl, NN - 1);

    f32x4 acc[4];
#pragma unroll
    for (int ct = 0; ct < 4; ++ct) acc[ct] = (f32x4){0.f, 0.f, 0.f, 0.f};

    __syncthreads();

#pragma unroll
    for (int kk = 0; kk < 8; ++kk) {
        const bf16x8 aH = *(const bf16x8*)(h1c + (size_t)na * C1 + kk * 32 + g8);
        const int ko = kk * 32 + g8;
#pragma unroll
        for (int ct = 0; ct < 4; ++ct) {
            const bf16x8 bH = *(const bf16x8*)(wH + (ct * 16 + cl) * KP2 + ko);
            const bf16x8 bL = *(const bf16x8*)(wL + (ct * 16 + cl) * KP2 + ko);
            acc[ct] = __builtin_amdgcn_mfma_f32_16x16x32_bf16(aH, bH, acc[ct], 0, 0, 0);
            acc[ct] = __builtin_amdgcn_mfma_f32_16x16x32_bf16(aH, bL, acc[ct], 0, 0, 0);
        }
    }

    float asc[4], adc[4];
#pragma unroll
    for (int ct = 0; ct < 4; ++ct) {
        asc[ct] = att_s[ct * 16 + cl];
        adc[ct] = att_d[ct * 16 + cl];
    }

#pragma unroll
    for (int reg = 0; reg < 4; ++reg) {
        const int nd = n0 + w * 16 + g * 4 + reg;
        float sa = 0.f, sd = 0.f;
#pragma unroll
        for (int ct = 0; ct < 4; ++ct) {
            sa += acc[ct][reg] * asc[ct];
            sd += acc[ct][reg] * adc[ct];
        }
#pragma unroll
        for (int off = 8; off > 0; off >>= 1) {
            sa += __shfl_xor(sa, off);
            sd += __shfl_xor(sd, off);
        }
        if (nd < NN) {
#pragma unroll
            for (int ct = 0; ct < 4; ++ct)
                h2b[(size_t)nd * HID + ct * 16 + cl] = f2bf(acc[ct][reg]);
            if (cl == 0) { as2[nd] = sa; ad2[nd] = sd; }
        }
    }
}

// ================= conv2 aggregate: 2 nodes/wave, precomputed weights =========
__global__ __launch_bounds__(256) void conv2_agg(const int* __restrict__ rowptr,
                                                 const int* __restrict__ csr_src,
                                                 const float* __restrict__ w2e,
                                                 const unsigned short* __restrict__ h2b,
                                                 const float* __restrict__ b2,
                                                 unsigned short* __restrict__ embb) {
    const int tid  = threadIdx.x;
    const int wid  = tid >> 6;
    const int l    = tid & 63;
    const int half = l >> 5;
    const int l32  = l & 31;
    const int node = blockIdx.x * 8 + wid * 2 + half;
    const int beg = rowptr[node], end = rowptr[node + 1];

    float a0 = 0.f, a1 = 0.f, sm = 0.f;
#pragma unroll 2
    for (int i = beg; i < end; ++i) {
        int s = csr_src[i];
        float w = w2e[i];
        unsigned hv = *(const unsigned*)(h2b + (size_t)s * HID + l32 * 2);
        a0 += w * bf2f((unsigned short)(hv & 0xFFFF));
        a1 += w * bf2f((unsigned short)(hv >> 16));
        sm += w;
    }
    const float rden = 1.f / (sm + EPSS);
    float o0 = a0 * rden + b2[l32 * 2];
    float o1 = a1 * rden + b2[l32 * 2 + 1];
    unsigned outw = (unsigned)f2bf(o0) | ((unsigned)f2bf(o1) << 16);
    *(unsigned*)(embb + (size_t)node * HID + l32 * 2) = outw;
}

// ================= edge MLP: swapped operands, bf16-only W ====================
#define NT_MLP (NE / 32)    // 25000
__global__ __launch_bounds__(512) void edge_mlp_mfma(const int* __restrict__ ei,
                                                     const unsigned short* __restrict__ embb,
                                                     const float* __restrict__ stats,
                                                     const unsigned short* __restrict__ wFh,
                                                     const float* __restrict__ mb1,
                                                     const float* __restrict__ mW2,
                                                     const float* __restrict__ mb2,
                                                     float* __restrict__ out) {
    __shared__ unsigned short sH[PREP_N2];   // 20 KB
    __shared__ float biaS[64], w2aS[64], w2bS[64];
    const int tid = threadIdx.x;
    for (int idx = tid; idx < PREP_N2 / 8; idx += 512)
        ((float4*)sH)[idx] = ((const float4*)wFh)[idx];
    if (tid < 64) {
        biaS[tid] = mb1[tid];
        w2aS[tid] = mW2[tid * 2];
        w2bS[tid] = mW2[tid * 2 + 1];
    }

    const int l  = tid & 63;
    const int cl = l & 15;
    const int g  = l >> 4;
    const int g8 = g * 8;
    const float ob0 = mb2[0], ob1 = mb2[1];

    const int t = blockIdx.x * 8 + (tid >> 6);   // 32-edge tile id

    bf16x8 a[2][5];
#pragma unroll
    for (int s = 0; s < 2; ++s) {
        const int ge_a = t * 32 + s * 16 + cl;
        const int rn = ei[ge_a];
        const int cn = ei[NE + ge_a];
        const unsigned short* rp = embb + (size_t)rn * HID;
        const unsigned short* cp = embb + (size_t)cn * HID;
        a[s][0] = *(const bf16x8*)(rp + g8);
        a[s][1] = *(const bf16x8*)(rp + 32 + g8);
        a[s][2] = *(const bf16x8*)(cp + g8);
        a[s][3] = *(const bf16x8*)(cp + 32 + g8);
        bf16x8 z = {0, 0, 0, 0, 0, 0, 0, 0};
        if (g == 0) {
            const float* sp = stats + (size_t)ge_a * 3;
            z[0] = (short)f2bf(sp[0]);
            z[1] = (short)f2bf(sp[1]);
            z[2] = (short)f2bf(sp[2]);
        }
        a[s][4] = z;
    }

    f32x4 acc[2][4];
#pragma unroll
    for (int s = 0; s < 2; ++s)
#pragma unroll
        for (int ct = 0; ct < 4; ++ct)
            acc[s][ct] = (f32x4){0.f, 0.f, 0.f, 0.f};

    __syncthreads();

#pragma unroll
    for (int kk = 0; kk < 5; ++kk) {
#pragma unroll
        for (int ct = 0; ct < 4; ++ct) {
            const int fo = ((kk * 4 + ct) * 64 + l) * 8;
            const bf16x8 wHf = *(const bf16x8*)(sH + fo);
#pragma unroll
            for (int s = 0; s < 2; ++s) {
                acc[s][ct] = __builtin_amdgcn_mfma_f32_16x16x32_bf16(wHf, a[s][kk], acc[s][ct], 0, 0, 0);
            }
        }
    }

#pragma unroll
    for (int s = 0; s < 2; ++s) {
        float p0 = 0.f, p1 = 0.f;
#pragma unroll
        for (int ct = 0; ct < 4; ++ct) {
            const int hb = ct * 16 + g * 4;
            float4 bi = *(const float4*)(biaS + hb);
            float4 wa = *(const float4*)(w2aS + hb);
            float4 wb = *(const float4*)(w2bS + hb);
#pragma unroll
            for (int reg = 0; reg < 4; ++reg) {
                float bv = (reg == 0) ? bi.x : (reg == 1) ? bi.y : (reg == 2) ? bi.z : bi.w;
                float av = (reg == 0) ? wa.x : (reg == 1) ? wa.y : (reg == 2) ? wa.z : wa.w;
                float wv = (reg == 0) ? wb.x : (reg == 1) ? wb.y : (reg == 2) ? wb.z : wb.w;
                float h = fmaxf(acc[s][ct][reg] + bv, 0.f);
                p0 += h * av;
                p1 += h * wv;
            }
        }
        p0 += __shfl_xor(p0, 16); p0 += __shfl_xor(p0, 32);
        p1 += __shfl_xor(p1, 16); p1 += __shfl_xor(p1, 32);
        if (g == 0) {
            const int ge = t * 32 + s * 16 + cl;
            *(float2*)(out + (size_t)ge * 2) = make_float2(p0 + ob0, p1 + ob1);
        }
    }
}

// ================= launcher =================
extern "C" void kernel_launch(void* const* d_in, const int* in_sizes, int n_in,
                              void* d_out, int out_size, void* d_ws, size_t ws_size,
                              hipStream_t stream) {
    const float* x      = (const float*)d_in[0];
    const int*   ei     = (const int*)d_in[1];
    const float* stats  = (const float*)d_in[2];
    const float* W1     = (const float*)d_in[3];
    const float* att_s1 = (const float*)d_in[4];
    const float* att_d1 = (const float*)d_in[5];
    const float* b1     = (const float*)d_in[6];
    const float* W2     = (const float*)d_in[7];
    const float* att_s2 = (const float*)d_in[8];
    const float* att_d2 = (const float*)d_in[9];
    const float* b2     = (const float*)d_in[10];
    const float* mW1    = (const float*)d_in[11];
    const float* mb1    = (const float*)d_in[12];
    const float* mW2    = (const float*)d_in[13];
    const float* mb2    = (const float*)d_in[14];
    float* out = (float*)d_out;
    float* ws  = (float*)d_ws;

    // f32-word-offset layout (no aliasing; all chunks 16B-aligned)
    int*   rowptr  = (int*)ws;                                 // NN+16
    int*   csr_src = rowptr + NN + 16;                         // EP
    int*   csr_dst = csr_src + EP;                             // EP
    float* as1     = (float*)(csr_dst + EP);                   // 4NN
    float* ad1     = as1 + (size_t)4 * NN;                     // 4NN
    unsigned short* xb    = (unsigned short*)(ad1 + (size_t)4 * NN);  // NN*128 bf16
    unsigned short* xaggb = xb + (size_t)128 * NN;             // NN*512 bf16
    unsigned short* h1c   = xaggb + (size_t)512 * NN;          // NN*256 bf16
    unsigned short* h2b   = h1c + (size_t)256 * NN;            // NN*64 bf16
    unsigned short* embb  = h2b + (size_t)64 * NN;             // NN*64 bf16
    float* as2     = (float*)(embb + (size_t)64 * NN);         // NN
    float* ad2     = as2 + NN;                                 // NN
    unsigned short* w1h = (unsigned short*)(ad2 + NN);         // 256*128
    unsigned short* w1l = w1h + C1 * INC;
    unsigned short* w2h = w1l + C1 * INC;                      // 64*256
    unsigned short* w2l = w2h + HID * C1;
    unsigned short* wFh = w2l + HID * C1;                      // 10240
    float* vsd     = (float*)(wFh + PREP_N2);                  // 1024
    float* w1e     = vsd + 1024;                               // 4*EP
    float* w2e     = w1e + (size_t)4 * EP;                     // EP
    int*   counts  = (int*)(w2e + EP + 64);                    // NN
    int*   bsum    = counts + NN + 64;                         // NSB
    int*   cursor  = bsum + NSB + 64;                          // NN

    // ---- CSR build + weight prep + projections ----
    hipMemsetAsync(counts, 0, NN * sizeof(int), stream);
    prep_all<<<(PREP_TOT + 255) / 256, 256, 0, stream>>>(
        mW1, W1, W2, x, att_s1, att_d1,
        w1h, w1l, w2h, w2l, wFh, vsd, xb);
    count_x<<<NXCD * NSUB, 256, 0, stream>>>(ei, counts);
    scan_partial<<<NSB, SCHUNK, 0, stream>>>(counts, bsum);
    scan_top<<<1, 128, 0, stream>>>(bsum, rowptr);
    scan_final<<<NSB, SCHUNK, 0, stream>>>(counts, bsum, rowptr, cursor);
    csr_fill_x<<<NXCD * NSUB, 256, 0, stream>>>(ei, cursor, csr_src);
    fill_dst<<<(NN + 255) / 256, 256, 0, stream>>>(rowptr, csr_dst);

    // ---- conv1: logits -> edge weights -> aggregate x -> GEMM ----
    att1_kernel<<<NN / 16, 256, 0, stream>>>(x, vsd, as1, ad1);
    edge_w1k<<<(EP + 255) / 256, 256, 0, stream>>>(csr_src, csr_dst, as1, ad1, w1e);
    conv1_agg<<<NN / 16, 256, 0, stream>>>(rowptr, csr_src, w1e, xb, xaggb);
    gemm1b<<<dim3((NN + 63) / 64, 4), 256, 0, stream>>>(xaggb, w1h, w1l, b1, h1c);

    // ---- conv2 ----
    gemm2_mfma<<<(NN + 63) / 64, 256, 0, stream>>>(h1c, w2h, w2l, att_s2, att_d2,
                                                   h2b, as2, ad2);
    edge_w2k<<<(EP + 255) / 256, 256, 0, stream>>>(csr_src, csr_dst, as2, ad2, w2e);
    conv2_agg<<<NN / 8, 256, 0, stream>>>(rowptr, csr_src, w2e, h2b, b2, embb);

    // ---- edge MLP: swapped-operand MFMA, bf16-only W, 512 thr ----
    edge_mlp_mfma<<<NT_MLP / 8, 512, 0, stream>>>(ei, embb, stats, wFh,
                                                  mb1, mW2, mb2, out);
}

// Round 25
// 282.964 us; speedup vs baseline: 1.1729x; 1.0212x over previous
//
#include <hip/hip_runtime.h>
#include <math.h>

#define NN 50000
#define NE 800000
#define EP (NE + NN)        // edges including self loops
#define INC 128
#define HID 64
#define HEADS 4
#define C1 (HEADS * HID)    // 256
#define NEG 0.2f
#define EPSS 1e-16f

#define SCHUNK 512
#define NSB ((NN + SCHUNK - 1) / SCHUNK)   // 98

#define KP1 136             // gemm1 W1^T LDS stride
#define KP2 264             // gemm2 W2^T LDS stride
typedef __attribute__((ext_vector_type(8))) short bf16x8;
typedef __attribute__((ext_vector_type(4))) float f32x4;

// ---------- bf16 helpers ----------
__device__ __forceinline__ unsigned short f2bf(float f) {
    unsigned u = __float_as_uint(f);
    unsigned r = (u + 0x7FFFu + ((u >> 16) & 1u)) >> 16;
    return (unsigned short)r;
}
__device__ __forceinline__ float bf2f(unsigned short b) {
    return __uint_as_float(((unsigned)b) << 16);
}

// ================= CSR scans =================
__global__ __launch_bounds__(SCHUNK) void scan_partial(const int* __restrict__ counts,
                                                       int* __restrict__ bsum) {
    __shared__ int lds[SCHUNK];
    int i = blockIdx.x * SCHUNK + threadIdx.x;
    lds[threadIdx.x] = (i < NN) ? counts[i] : 0;
    __syncthreads();
    for (int off = SCHUNK / 2; off > 0; off >>= 1) {
        if (threadIdx.x < off) lds[threadIdx.x] += lds[threadIdx.x + off];
        __syncthreads();
    }
    if (threadIdx.x == 0) bsum[blockIdx.x] = lds[0];
}

__global__ void scan_top(int* __restrict__ bsum, int* __restrict__ rowptr) {
    __shared__ int lds[NSB];
    int t = threadIdx.x;
    if (t < NSB) lds[t] = bsum[t];
    __syncthreads();
    if (t == 0) {
        int acc = 0;
        for (int i = 0; i < NSB; ++i) { int v = lds[i]; lds[i] = acc; acc += v; }
        rowptr[NN] = acc;   // == EP
    }
    __syncthreads();
    if (t < NSB) bsum[t] = lds[t];
}

__global__ __launch_bounds__(SCHUNK) void scan_final(const int* __restrict__ counts,
                                                     const int* __restrict__ bsum,
                                                     int* __restrict__ rowptr,
                                                     int* __restrict__ cursor) {
    __shared__ int lds[SCHUNK];
    int i = blockIdx.x * SCHUNK + threadIdx.x;
    int v = (i < NN) ? counts[i] : 0;
    lds[threadIdx.x] = v;
    __syncthreads();
    for (int off = 1; off < SCHUNK; off <<= 1) {
        int t = (threadIdx.x >= off) ? lds[threadIdx.x - off] : 0;
        __syncthreads();
        lds[threadIdx.x] += t;
        __syncthreads();
    }
    if (i < NN) {
        int excl = lds[threadIdx.x] - v + bsum[blockIdx.x];
        rowptr[i] = excl;
        cursor[i] = excl;
    }
}

// ================= XCD-partitioned histogram + CSR scatter =================
#define NXCD 8
#define NSUB 104
#define DRANGE ((NN + NXCD - 1) / NXCD)   // 6250
__global__ __launch_bounds__(256) void count_x(const int* __restrict__ ei,
                                               int* __restrict__ counts) {
    const int x   = blockIdx.x & (NXCD - 1);
    const int sub = blockIdx.x >> 3;
    const int CH  = (EP + NSUB - 1) / NSUB;
    const int beg = sub * CH;
    const int end = min(beg + CH, EP);
    const int dlo = x * DRANGE;
    const int dhi = dlo + DRANGE;
    for (int e = beg + (int)threadIdx.x; e < end; e += 256) {
        int d = (e < NE) ? ei[NE + e] : (e - NE);
        if (d >= dlo && d < dhi) atomicAdd(&counts[d], 1);
    }
}

__global__ __launch_bounds__(256) void csr_fill_x(const int* __restrict__ ei,
                                                  int* __restrict__ cursor,
                                                  int* __restrict__ csr_src) {
    const int x   = blockIdx.x & (NXCD - 1);
    const int sub = blockIdx.x >> 3;
    const int CH  = (EP + NSUB - 1) / NSUB;
    const int beg = sub * CH;
    const int end = min(beg + CH, EP);
    const int dlo = x * DRANGE;
    const int dhi = dlo + DRANGE;
    for (int e = beg + (int)threadIdx.x; e < end; e += 256) {
        int s, d;
        if (e < NE) { s = ei[e]; d = ei[NE + e]; } else { s = d = e - NE; }
        if (d >= dlo && d < dhi) {
            int pos = atomicAdd(&cursor[d], 1);
            csr_src[pos] = s;
        }
    }
}

// sequential coalesced fill of dst-per-position
__global__ void fill_dst(const int* __restrict__ rowptr, int* __restrict__ csr_dst) {
    int n = blockIdx.x * 256 + threadIdx.x;
    if (n >= NN) return;
    int beg = rowptr[n], end = rowptr[n + 1];
    for (int i = beg; i < end; ++i) csr_dst[i] = n;
}

// ================= merged weight prep + projections =============
// R0: W1^T bf16; R1: W2^T bf16; R2: mW1 fragment-linear bf16
// R3: vsd projections; R4: xb = bf16(x), 8 elems/thread
#define PREP_N0 (C1 * INC)
#define PREP_N1 (HID * C1)
#define PREP_N2 (5 * 4 * 64 * 8)   // 10240
#define PREP_N3 1024
#define PREP_N4 (NN * INC / 8)     // 800000 threads, 8 elems each
#define PREP_TOT (PREP_N0 + PREP_N1 + PREP_N2 + PREP_N3 + PREP_N4)
__global__ void prep_all(const float* __restrict__ mW1, const float* __restrict__ W1,
                         const float* __restrict__ W2,
                         const float* __restrict__ x,
                         const float* __restrict__ att_s1, const float* __restrict__ att_d1,
                         unsigned short* __restrict__ w1h,
                         unsigned short* __restrict__ w2h,
                         unsigned short* __restrict__ wFh,
                         float* __restrict__ vsd, unsigned short* __restrict__ xb) {
    int i = blockIdx.x * 256 + threadIdx.x;
    if (i < PREP_N0) {
        int c = i >> 7, k = i & 127;
        w1h[i] = f2bf(W1[k * C1 + c]);
        return;
    }
    i -= PREP_N0;
    if (i < PREP_N1) {
        int c = i >> 8, k = i & 255;
        w2h[i] = f2bf(W2[k * HID + c]);
        return;
    }
    i -= PREP_N1;
    if (i < PREP_N2) {
        int kk = i >> 11;
        int ct = (i >> 9) & 3;
        int l  = (i >> 3) & 63;
        int j  = i & 7;
        int cl = l & 15, g = l >> 4;
        int k   = kk * 32 + g * 8 + j;
        int col = ct * 16 + cl;
        unsigned short h = 0;
        if (k < 131) h = f2bf(mW1[k * 64 + col]);
        wFh[i] = h;
        return;
    }
    i -= PREP_N2;
    if (i < PREP_N3) {
        int type = i >> 9;
        int rem  = i & 511;
        int h = rem >> 7, k = rem & 127;
        const float* att = type ? att_d1 : att_s1;
        float acc = 0.f;
        for (int c = 0; c < 64; ++c)
            acc += W1[k * C1 + h * 64 + c] * att[h * 64 + c];
        vsd[i] = acc;
        return;
    }
    i -= PREP_N3;
    if (i < PREP_N4) {
        const float* xp = x + (size_t)i * 8;
        float4 v0 = *(const float4*)xp;
        float4 v1 = *(const float4*)(xp + 4);
        bf16x8 ob;
        ob[0] = (short)f2bf(v0.x); ob[1] = (short)f2bf(v0.y);
        ob[2] = (short)f2bf(v0.z); ob[3] = (short)f2bf(v0.w);
        ob[4] = (short)f2bf(v1.x); ob[5] = (short)f2bf(v1.y);
        ob[6] = (short)f2bf(v1.z); ob[7] = (short)f2bf(v1.w);
        *(bf16x8*)(xb + (size_t)i * 8) = ob;
        return;
    }
}

// ================= att1: as1/ad1 = x . (W1 @ att) — 16 lanes/node ============
__global__ __launch_bounds__(256) void att1_kernel(const float* __restrict__ x,
                                                   const float* __restrict__ vsd,
                                                   float* __restrict__ as1,
                                                   float* __restrict__ ad1) {
    __shared__ float vsS[1024];
    const int tid = threadIdx.x;
    for (int idx = tid; idx < 1024; idx += 256) vsS[idx] = vsd[idx];
    __syncthreads();

    const int n = blockIdx.x * 16 + (tid >> 4);
    const int l16 = tid & 15;
    const float* xp = x + (size_t)n * INC + l16 * 8;
    float4 xa = *(const float4*)xp;
    float4 xc = *(const float4*)(xp + 4);

    float o[8];
#pragma unroll
    for (int h = 0; h < 4; ++h) {
        const float* vp = vsS + h * 128 + l16 * 8;
        const float* dp = vsS + 512 + h * 128 + l16 * 8;
        o[h]     = xa.x * vp[0] + xa.y * vp[1] + xa.z * vp[2] + xa.w * vp[3]
                 + xc.x * vp[4] + xc.y * vp[5] + xc.z * vp[6] + xc.w * vp[7];
        o[4 + h] = xa.x * dp[0] + xa.y * dp[1] + xa.z * dp[2] + xa.w * dp[3]
                 + xc.x * dp[4] + xc.y * dp[5] + xc.z * dp[6] + xc.w * dp[7];
    }
#pragma unroll
    for (int off = 1; off < 16; off <<= 1)
#pragma unroll
        for (int v = 0; v < 8; ++v) o[v] += __shfl_xor(o[v], off);
    if (l16 == 0) {
        *(float4*)(as1 + n * 4) = make_float4(o[0], o[1], o[2], o[3]);
        *(float4*)(ad1 + n * 4) = make_float4(o[4], o[5], o[6], o[7]);
    }
}

// ================= edge softmax weights =================
__global__ void edge_w1k(const int* __restrict__ csr_src, const int* __restrict__ csr_dst,
                         const float* __restrict__ as1, const float* __restrict__ ad1,
                         float* __restrict__ w1e) {
    int i = blockIdx.x * 256 + threadIdx.x;
    if (i >= EP) return;
    int s = csr_src[i], d = csr_dst[i];
    float4 a = *(const float4*)(as1 + s * 4);
    float4 b = *(const float4*)(ad1 + d * 4);
    float4 o;
    float t;
    t = a.x + b.x; t = t > 0.f ? t : NEG * t; o.x = __expf(t);
    t = a.y + b.y; t = t > 0.f ? t : NEG * t; o.y = __expf(t);
    t = a.z + b.z; t = t > 0.f ? t : NEG * t; o.z = __expf(t);
    t = a.w + b.w; t = t > 0.f ? t : NEG * t; o.w = __expf(t);
    *(float4*)(w1e + (size_t)i * 4) = o;
}

__global__ void edge_w2k(const int* __restrict__ csr_src, const int* __restrict__ csr_dst,
                         const float* __restrict__ as2, const float* __restrict__ ad2,
                         float* __restrict__ w2e) {
    int i = blockIdx.x * 256 + threadIdx.x;
    if (i >= EP) return;
    float t = as2[csr_src[i]] + ad2[csr_dst[i]];
    t = t > 0.f ? t : NEG * t;
    w2e[i] = __expf(t);
}

// ================= conv1 aggregate of x (bf16): 16 lanes/node ================
__global__ __launch_bounds__(256) void conv1_agg(const int* __restrict__ rowptr,
                                                 const int* __restrict__ csr_src,
                                                 const float* __restrict__ w1e,
                                                 const unsigned short* __restrict__ xb,
                                                 unsigned short* __restrict__ xaggb) {
    const int tid = threadIdx.x;
    const int node = blockIdx.x * 16 + (tid >> 4);   // NN % 16 == 0
    const int l16 = tid & 15;
    const int beg = rowptr[node], end = rowptr[node + 1];

    float acc[4][8];
#pragma unroll
    for (int h = 0; h < 4; ++h)
#pragma unroll
        for (int j = 0; j < 8; ++j) acc[h][j] = 0.f;
    float sm[4] = {0.f, 0.f, 0.f, 0.f};

#pragma unroll 2
    for (int i = beg; i < end; ++i) {
        int s = csr_src[i];
        float4 w = *(const float4*)(w1e + (size_t)i * 4);
        bf16x8 xv = *(const bf16x8*)(xb + (size_t)s * INC + l16 * 8);
        float xf[8];
#pragma unroll
        for (int j = 0; j < 8; ++j) xf[j] = bf2f((unsigned short)xv[j]);
#pragma unroll
        for (int j = 0; j < 8; ++j) {
            acc[0][j] += w.x * xf[j];
            acc[1][j] += w.y * xf[j];
            acc[2][j] += w.z * xf[j];
            acc[3][j] += w.w * xf[j];
        }
        sm[0] += w.x; sm[1] += w.y; sm[2] += w.z; sm[3] += w.w;
    }

#pragma unroll
    for (int h = 0; h < 4; ++h) {
        const float rden = 1.f / (sm[h] + EPSS);
        bf16x8 ob;
#pragma unroll
        for (int j = 0; j < 8; ++j) ob[j] = (short)f2bf(acc[h][j] * rden);
        *(bf16x8*)(xaggb + ((size_t)node * 4 + h) * INC + l16 * 8) = ob;
    }
}

// ================= GEMM1 (post-agg): h1c = ELU(xagg @ W1 + b1), bf16 both ====
__global__ __launch_bounds__(256) void gemm1b(const unsigned short* __restrict__ xaggb,
                                              const unsigned short* __restrict__ w1h,
                                              const float* __restrict__ b1,
                                              unsigned short* __restrict__ h1c) {
    __shared__ unsigned short wH[64 * KP1];
    const int tid = threadIdx.x;
    const int n0 = blockIdx.x * 64;
    const int q  = blockIdx.y;

    for (int idx = tid; idx < 64 * 16; idx += 256) {
        int col = idx >> 4, ch = idx & 15;
        *(bf16x8*)(wH + col * KP1 + ch * 8) =
            *(const bf16x8*)(w1h + ((q * 64 + col) << 7) + ch * 8);
    }

    const int w = tid >> 6, l = tid & 63;
    const int cl = l & 15, g = l >> 4, g8 = g * 8;
    const int na = min(n0 + w * 16 + cl, NN - 1);

    bf16x8 aH[4];
#pragma unroll
    for (int kk = 0; kk < 4; ++kk)
        aH[kk] = *(const bf16x8*)(xaggb + ((size_t)na * 4 + q) * INC + kk * 32 + g8);

    f32x4 acc[4];
#pragma unroll
    for (int ct = 0; ct < 4; ++ct) acc[ct] = (f32x4){0.f, 0.f, 0.f, 0.f};

    __syncthreads();

#pragma unroll
    for (int kk = 0; kk < 4; ++kk) {
        const int ko = kk * 32 + g8;
#pragma unroll
        for (int ct = 0; ct < 4; ++ct) {
            const bf16x8 bH = *(const bf16x8*)(wH + (ct * 16 + cl) * KP1 + ko);
            acc[ct] = __builtin_amdgcn_mfma_f32_16x16x32_bf16(aH[kk], bH, acc[ct], 0, 0, 0);
        }
    }

#pragma unroll
    for (int reg = 0; reg < 4; ++reg) {
        const int nd = n0 + w * 16 + g * 4 + reg;
        if (nd < NN) {
#pragma unroll
            for (int ct = 0; ct < 4; ++ct) {
                const int col = q * 64 + ct * 16 + cl;
                float o = acc[ct][reg] + b1[col];
                o = o > 0.f ? o : (__expf(o) - 1.f);
                h1c[(size_t)nd * C1 + col] = f2bf(o);
            }
        }
    }
}

// ================= GEMM2: bf16 A x bf16 W MFMA + att2 epilogue ===============
__global__ __launch_bounds__(256) void gemm2_mfma(const unsigned short* __restrict__ h1c,
                                                  const unsigned short* __restrict__ w2h,
                                                  const float* __restrict__ att_s,
                                                  const float* __restrict__ att_d,
                                                  unsigned short* __restrict__ h2b,
                                                  float* __restrict__ as2,
                                                  float* __restrict__ ad2) {
    __shared__ unsigned short wH[64 * KP2];
    const int tid = threadIdx.x;
    const int n0 = blockIdx.x * 64;

    for (int idx = tid; idx < 64 * 32; idx += 256) {
        int col = idx >> 5, ch = idx & 31;
        *(bf16x8*)(wH + col * KP2 + ch * 8) =
            *(const bf16x8*)(w2h + ((col) << 8) + ch * 8);
    }

    const int w = tid >> 6, l = tid & 63;
    const int cl = l & 15, g = l >> 4, g8 = g * 8;
    const int na = min(n0 + w * 16 + cl, NN - 1);

    f32x4 acc[4];
#pragma unroll
    for (int ct = 0; ct < 4; ++ct) acc[ct] = (f32x4){0.f, 0.f, 0.f, 0.f};

    __syncthreads();

#pragma unroll
    for (int kk = 0; kk < 8; ++kk) {
        const bf16x8 aH = *(const bf16x8*)(h1c + (size_t)na * C1 + kk * 32 + g8);
        const int ko = kk * 32 + g8;
#pragma unroll
        for (int ct = 0; ct < 4; ++ct) {
            const bf16x8 bH = *(const bf16x8*)(wH + (ct * 16 + cl) * KP2 + ko);
            acc[ct] = __builtin_amdgcn_mfma_f32_16x16x32_bf16(aH, bH, acc[ct], 0, 0, 0);
        }
    }

    float asc[4], adc[4];
#pragma unroll
    for (int ct = 0; ct < 4; ++ct) {
        asc[ct] = att_s[ct * 16 + cl];
        adc[ct] = att_d[ct * 16 + cl];
    }

#pragma unroll
    for (int reg = 0; reg < 4; ++reg) {
        const int nd = n0 + w * 16 + g * 4 + reg;
        float sa = 0.f, sd = 0.f;
#pragma unroll
        for (int ct = 0; ct < 4; ++ct) {
            sa += acc[ct][reg] * asc[ct];
            sd += acc[ct][reg] * adc[ct];
        }
#pragma unroll
        for (int off = 8; off > 0; off >>= 1) {
            sa += __shfl_xor(sa, off);
            sd += __shfl_xor(sd, off);
        }
        if (nd < NN) {
#pragma unroll
            for (int ct = 0; ct < 4; ++ct)
                h2b[(size_t)nd * HID + ct * 16 + cl] = f2bf(acc[ct][reg]);
            if (cl == 0) { as2[nd] = sa; ad2[nd] = sd; }
        }
    }
}

// ================= conv2 aggregate: 2 nodes/wave, precomputed weights =========
__global__ __launch_bounds__(256) void conv2_agg(const int* __restrict__ rowptr,
                                                 const int* __restrict__ csr_src,
                                                 const float* __restrict__ w2e,
                                                 const unsigned short* __restrict__ h2b,
                                                 const float* __restrict__ b2,
                                                 unsigned short* __restrict__ embb) {
    const int tid  = threadIdx.x;
    const int wid  = tid >> 6;
    const int l    = tid & 63;
    const int half = l >> 5;
    const int l32  = l & 31;
    const int node = blockIdx.x * 8 + wid * 2 + half;
    const int beg = rowptr[node], end = rowptr[node + 1];

    float a0 = 0.f, a1 = 0.f, sm = 0.f;
#pragma unroll 2
    for (int i = beg; i < end; ++i) {
        int s = csr_src[i];
        float w = w2e[i];
        unsigned hv = *(const unsigned*)(h2b + (size_t)s * HID + l32 * 2);
        a0 += w * bf2f((unsigned short)(hv & 0xFFFF));
        a1 += w * bf2f((unsigned short)(hv >> 16));
        sm += w;
    }
    const float rden = 1.f / (sm + EPSS);
    float o0 = a0 * rden + b2[l32 * 2];
    float o1 = a1 * rden + b2[l32 * 2 + 1];
    unsigned outw = (unsigned)f2bf(o0) | ((unsigned)f2bf(o1) << 16);
    *(unsigned*)(embb + (size_t)node * HID + l32 * 2) = outw;
}

// ================= edge MLP: swapped operands, bf16-only W ====================
#define NT_MLP (NE / 32)    // 25000
__global__ __launch_bounds__(512) void edge_mlp_mfma(const int* __restrict__ ei,
                                                     const unsigned short* __restrict__ embb,
                                                     const float* __restrict__ stats,
                                                     const unsigned short* __restrict__ wFh,
                                                     const float* __restrict__ mb1,
                                                     const float* __restrict__ mW2,
                                                     const float* __restrict__ mb2,
                                                     float* __restrict__ out) {
    __shared__ unsigned short sH[PREP_N2];   // 20 KB
    __shared__ float biaS[64], w2aS[64], w2bS[64];
    const int tid = threadIdx.x;
    for (int idx = tid; idx < PREP_N2 / 8; idx += 512)
        ((float4*)sH)[idx] = ((const float4*)wFh)[idx];
    if (tid < 64) {
        biaS[tid] = mb1[tid];
        w2aS[tid] = mW2[tid * 2];
        w2bS[tid] = mW2[tid * 2 + 1];
    }

    const int l  = tid & 63;
    const int cl = l & 15;
    const int g  = l >> 4;
    const int g8 = g * 8;
    const float ob0 = mb2[0], ob1 = mb2[1];

    const int t = blockIdx.x * 8 + (tid >> 6);   // 32-edge tile id

    bf16x8 a[2][5];
#pragma unroll
    for (int s = 0; s < 2; ++s) {
        const int ge_a = t * 32 + s * 16 + cl;
        const int rn = ei[ge_a];
        const int cn = ei[NE + ge_a];
        const unsigned short* rp = embb + (size_t)rn * HID;
        const unsigned short* cp = embb + (size_t)cn * HID;
        a[s][0] = *(const bf16x8*)(rp + g8);
        a[s][1] = *(const bf16x8*)(rp + 32 + g8);
        a[s][2] = *(const bf16x8*)(cp + g8);
        a[s][3] = *(const bf16x8*)(cp + 32 + g8);
        bf16x8 z = {0, 0, 0, 0, 0, 0, 0, 0};
        if (g == 0) {
            const float* sp = stats + (size_t)ge_a * 3;
            z[0] = (short)f2bf(sp[0]);
            z[1] = (short)f2bf(sp[1]);
            z[2] = (short)f2bf(sp[2]);
        }
        a[s][4] = z;
    }

    f32x4 acc[2][4];
#pragma unroll
    for (int s = 0; s < 2; ++s)
#pragma unroll
        for (int ct = 0; ct < 4; ++ct)
            acc[s][ct] = (f32x4){0.f, 0.f, 0.f, 0.f};

    __syncthreads();

#pragma unroll
    for (int kk = 0; kk < 5; ++kk) {
#pragma unroll
        for (int ct = 0; ct < 4; ++ct) {
            const int fo = ((kk * 4 + ct) * 64 + l) * 8;
            const bf16x8 wHf = *(const bf16x8*)(sH + fo);
#pragma unroll
            for (int s = 0; s < 2; ++s) {
                acc[s][ct] = __builtin_amdgcn_mfma_f32_16x16x32_bf16(wHf, a[s][kk], acc[s][ct], 0, 0, 0);
            }
        }
    }

#pragma unroll
    for (int s = 0; s < 2; ++s) {
        float p0 = 0.f, p1 = 0.f;
#pragma unroll
        for (int ct = 0; ct < 4; ++ct) {
            const int hb = ct * 16 + g * 4;
            float4 bi = *(const float4*)(biaS + hb);
            float4 wa = *(const float4*)(w2aS + hb);
            float4 wb = *(const float4*)(w2bS + hb);
#pragma unroll
            for (int reg = 0; reg < 4; ++reg) {
                float bv = (reg == 0) ? bi.x : (reg == 1) ? bi.y : (reg == 2) ? bi.z : bi.w;
                float av = (reg == 0) ? wa.x : (reg == 1) ? wa.y : (reg == 2) ? wa.z : wa.w;
                float wv = (reg == 0) ? wb.x : (reg == 1) ? wb.y : (reg == 2) ? wb.z : wb.w;
                float h = fmaxf(acc[s][ct][reg] + bv, 0.f);
                p0 += h * av;
                p1 += h * wv;
            }
        }
        p0 += __shfl_xor(p0, 16); p0 += __shfl_xor(p0, 32);
        p1 += __shfl_xor(p1, 16); p1 += __shfl_xor(p1, 32);
        if (g == 0) {
            const int ge = t * 32 + s * 16 + cl;
            *(float2*)(out + (size_t)ge * 2) = make_float2(p0 + ob0, p1 + ob1);
        }
    }
}

// ================= launcher =================
extern "C" void kernel_launch(void* const* d_in, const int* in_sizes, int n_in,
                              void* d_out, int out_size, void* d_ws, size_t ws_size,
                              hipStream_t stream) {
    const float* x      = (const float*)d_in[0];
    const int*   ei     = (const int*)d_in[1];
    const float* stats  = (const float*)d_in[2];
    const float* W1     = (const float*)d_in[3];
    const float* att_s1 = (const float*)d_in[4];
    const float* att_d1 = (const float*)d_in[5];
    const float* b1     = (const float*)d_in[6];
    const float* W2     = (const float*)d_in[7];
    const float* att_s2 = (const float*)d_in[8];
    const float* att_d2 = (const float*)d_in[9];
    const float* b2     = (const float*)d_in[10];
    const float* mW1    = (const float*)d_in[11];
    const float* mb1    = (const float*)d_in[12];
    const float* mW2    = (const float*)d_in[13];
    const float* mb2    = (const float*)d_in[14];
    float* out = (float*)d_out;
    float* ws  = (float*)d_ws;

    // f32-word-offset layout (no aliasing; all chunks 16B-aligned)
    int*   rowptr  = (int*)ws;                                 // NN+16
    int*   csr_src = rowptr + NN + 16;                         // EP
    int*   csr_dst = csr_src + EP;                             // EP
    float* as1     = (float*)(csr_dst + EP);                   // 4NN
    float* ad1     = as1 + (size_t)4 * NN;                     // 4NN
    unsigned short* xb    = (unsigned short*)(ad1 + (size_t)4 * NN);  // NN*128 bf16
    unsigned short* xaggb = xb + (size_t)128 * NN;             // NN*512 bf16
    unsigned short* h1c   = xaggb + (size_t)512 * NN;          // NN*256 bf16
    unsigned short* h2b   = h1c + (size_t)256 * NN;            // NN*64 bf16
    unsigned short* embb  = h2b + (size_t)64 * NN;             // NN*64 bf16
    float* as2     = (float*)(embb + (size_t)64 * NN);         // NN
    float* ad2     = as2 + NN;                                 // NN
    unsigned short* w1h = (unsigned short*)(ad2 + NN);         // 256*128
    unsigned short* w2h = w1h + C1 * INC;                      // 64*256
    unsigned short* wFh = w2h + HID * C1;                      // 10240
    float* vsd     = (float*)(wFh + PREP_N2);                  // 1024
    float* w1e     = vsd + 1024;                               // 4*EP
    float* w2e     = w1e + (size_t)4 * EP;                     // EP
    int*   counts  = (int*)(w2e + EP + 64);                    // NN
    int*   bsum    = counts + NN + 64;                         // NSB
    int*   cursor  = bsum + NSB + 64;                          // NN

    // ---- CSR build + weight prep + projections ----
    hipMemsetAsync(counts, 0, NN * sizeof(int), stream);
    prep_all<<<(PREP_TOT + 255) / 256, 256, 0, stream>>>(
        mW1, W1, W2, x, att_s1, att_d1,
        w1h, w2h, wFh, vsd, xb);
    count_x<<<NXCD * NSUB, 256, 0, stream>>>(ei, counts);
    scan_partial<<<NSB, SCHUNK, 0, stream>>>(counts, bsum);
    scan_top<<<1, 128, 0, stream>>>(bsum, rowptr);
    scan_final<<<NSB, SCHUNK, 0, stream>>>(counts, bsum, rowptr, cursor);
    csr_fill_x<<<NXCD * NSUB, 256, 0, stream>>>(ei, cursor, csr_src);
    fill_dst<<<(NN + 255) / 256, 256, 0, stream>>>(rowptr, csr_dst);

    // ---- conv1: logits -> edge weights -> aggregate x -> GEMM ----
    att1_kernel<<<NN / 16, 256, 0, stream>>>(x, vsd, as1, ad1);
    edge_w1k<<<(EP + 255) / 256, 256, 0, stream>>>(csr_src, csr_dst, as1, ad1, w1e);
    conv1_agg<<<NN / 16, 256, 0, stream>>>(rowptr, csr_src, w1e, xb, xaggb);
    gemm1b<<<dim3((NN + 63) / 64, 4), 256, 0, stream>>>(xaggb, w1h, b1, h1c);

    // ---- conv2 ----
    gemm2_mfma<<<(NN + 63) / 64, 256, 0, stream>>>(h1c, w2h, att_s2, att_d2,
                                                   h2b, as2, ad2);
    edge_w2k<<<(EP + 255) / 256, 256, 0, stream>>>(csr_src, csr_dst, as2, ad2, w2e);
    conv2_agg<<<NN / 8, 256, 0, stream>>>(rowptr, csr_src, w2e, h2b, b2, embb);

    // ---- edge MLP: swapped-operand MFMA, bf16-only W, 512 thr ----
    edge_mlp_mfma<<<NT_MLP / 8, 512, 0, stream>>>(ei, embb, stats, wFh,
                                                  mb1, mW2, mb2, out);
}

// Round 26
// 271.855 us; speedup vs baseline: 1.2209x; 1.0409x over previous
//
#include <hip/hip_runtime.h>
#include <math.h>

#define NN 50000
#define NE 800000
#define EP (NE + NN)        // edges including self loops
#define INC 128
#define HID 64
#define HEADS 4
#define C1 (HEADS * HID)    // 256
#define NEG 0.2f
#define EPSS 1e-16f

#define SCHUNK 512
#define NSB ((NN + SCHUNK - 1) / SCHUNK)   // 98

#define KP1 136             // gemm1 W1^T LDS stride
#define KP2 264             // gemm2 W2^T LDS stride
typedef __attribute__((ext_vector_type(8))) short bf16x8;
typedef __attribute__((ext_vector_type(4))) float f32x4;

// ---------- bf16 helpers ----------
__device__ __forceinline__ unsigned short f2bf(float f) {
    unsigned u = __float_as_uint(f);
    unsigned r = (u + 0x7FFFu + ((u >> 16) & 1u)) >> 16;
    return (unsigned short)r;
}
__device__ __forceinline__ float bf2f(unsigned short b) {
    return __uint_as_float(((unsigned)b) << 16);
}

// ================= CSR scans =================
__global__ __launch_bounds__(SCHUNK) void scan_partial(const int* __restrict__ counts,
                                                       int* __restrict__ bsum) {
    __shared__ int lds[SCHUNK];
    int i = blockIdx.x * SCHUNK + threadIdx.x;
    lds[threadIdx.x] = (i < NN) ? counts[i] : 0;
    __syncthreads();
    for (int off = SCHUNK / 2; off > 0; off >>= 1) {
        if (threadIdx.x < off) lds[threadIdx.x] += lds[threadIdx.x + off];
        __syncthreads();
    }
    if (threadIdx.x == 0) bsum[blockIdx.x] = lds[0];
}

__global__ void scan_top(int* __restrict__ bsum, int* __restrict__ rowptr) {
    __shared__ int lds[NSB];
    int t = threadIdx.x;
    if (t < NSB) lds[t] = bsum[t];
    __syncthreads();
    if (t == 0) {
        int acc = 0;
        for (int i = 0; i < NSB; ++i) { int v = lds[i]; lds[i] = acc; acc += v; }
        rowptr[NN] = acc;   // == EP
    }
    __syncthreads();
    if (t < NSB) bsum[t] = lds[t];
}

__global__ __launch_bounds__(SCHUNK) void scan_final(const int* __restrict__ counts,
                                                     const int* __restrict__ bsum,
                                                     int* __restrict__ rowptr,
                                                     int* __restrict__ cursor) {
    __shared__ int lds[SCHUNK];
    int i = blockIdx.x * SCHUNK + threadIdx.x;
    int v = (i < NN) ? counts[i] : 0;
    lds[threadIdx.x] = v;
    __syncthreads();
    for (int off = 1; off < SCHUNK; off <<= 1) {
        int t = (threadIdx.x >= off) ? lds[threadIdx.x - off] : 0;
        __syncthreads();
        lds[threadIdx.x] += t;
        __syncthreads();
    }
    if (i < NN) {
        int excl = lds[threadIdx.x] - v + bsum[blockIdx.x];
        rowptr[i] = excl;
        cursor[i] = excl;
    }
}

// ================= XCD-partitioned histogram + CSR scatter =================
#define NXCD 8
#define NSUB 104
#define DRANGE ((NN + NXCD - 1) / NXCD)   // 6250
__global__ __launch_bounds__(256) void count_x(const int* __restrict__ ei,
                                               int* __restrict__ counts) {
    const int x   = blockIdx.x & (NXCD - 1);
    const int sub = blockIdx.x >> 3;
    const int CH  = (EP + NSUB - 1) / NSUB;
    const int beg = sub * CH;
    const int end = min(beg + CH, EP);
    const int dlo = x * DRANGE;
    const int dhi = dlo + DRANGE;
    for (int e = beg + (int)threadIdx.x; e < end; e += 256) {
        int d = (e < NE) ? ei[NE + e] : (e - NE);
        if (d >= dlo && d < dhi) atomicAdd(&counts[d], 1);
    }
}

__global__ __launch_bounds__(256) void csr_fill_x(const int* __restrict__ ei,
                                                  int* __restrict__ cursor,
                                                  int* __restrict__ csr_src) {
    const int x   = blockIdx.x & (NXCD - 1);
    const int sub = blockIdx.x >> 3;
    const int CH  = (EP + NSUB - 1) / NSUB;
    const int beg = sub * CH;
    const int end = min(beg + CH, EP);
    const int dlo = x * DRANGE;
    const int dhi = dlo + DRANGE;
    for (int e = beg + (int)threadIdx.x; e < end; e += 256) {
        int s, d;
        if (e < NE) { s = ei[e]; d = ei[NE + e]; } else { s = d = e - NE; }
        if (d >= dlo && d < dhi) {
            int pos = atomicAdd(&cursor[d], 1);
            csr_src[pos] = s;
        }
    }
}

// sequential coalesced fill of dst-per-position
__global__ void fill_dst(const int* __restrict__ rowptr, int* __restrict__ csr_dst) {
    int n = blockIdx.x * 256 + threadIdx.x;
    if (n >= NN) return;
    int beg = rowptr[n], end = rowptr[n + 1];
    for (int i = beg; i < end; ++i) csr_dst[i] = n;
}

// ================= merged weight prep + projections =============
#define PREP_N0 (C1 * INC)
#define PREP_N1 (HID * C1)
#define PREP_N2 (5 * 4 * 64 * 8)   // 10240
#define PREP_N3 1024
#define PREP_N4 (NN * INC / 8)     // 800000 threads, 8 elems each
#define PREP_TOT (PREP_N0 + PREP_N1 + PREP_N2 + PREP_N3 + PREP_N4)
__global__ void prep_all(const float* __restrict__ mW1, const float* __restrict__ W1,
                         const float* __restrict__ W2,
                         const float* __restrict__ x,
                         const float* __restrict__ att_s1, const float* __restrict__ att_d1,
                         unsigned short* __restrict__ w1h,
                         unsigned short* __restrict__ w2h,
                         unsigned short* __restrict__ wFh,
                         float* __restrict__ vsd, unsigned short* __restrict__ xb) {
    int i = blockIdx.x * 256 + threadIdx.x;
    if (i < PREP_N0) {
        int c = i >> 7, k = i & 127;
        w1h[i] = f2bf(W1[k * C1 + c]);
        return;
    }
    i -= PREP_N0;
    if (i < PREP_N1) {
        int c = i >> 8, k = i & 255;
        w2h[i] = f2bf(W2[k * HID + c]);
        return;
    }
    i -= PREP_N1;
    if (i < PREP_N2) {
        int kk = i >> 11;
        int ct = (i >> 9) & 3;
        int l  = (i >> 3) & 63;
        int j  = i & 7;
        int cl = l & 15, g = l >> 4;
        int k   = kk * 32 + g * 8 + j;
        int col = ct * 16 + cl;
        unsigned short h = 0;
        if (k < 131) h = f2bf(mW1[k * 64 + col]);
        wFh[i] = h;
        return;
    }
    i -= PREP_N2;
    if (i < PREP_N3) {
        int type = i >> 9;
        int rem  = i & 511;
        int h = rem >> 7, k = rem & 127;
        const float* att = type ? att_d1 : att_s1;
        float acc = 0.f;
        for (int c = 0; c < 64; ++c)
            acc += W1[k * C1 + h * 64 + c] * att[h * 64 + c];
        vsd[i] = acc;
        return;
    }
    i -= PREP_N3;
    if (i < PREP_N4) {
        const float* xp = x + (size_t)i * 8;
        float4 v0 = *(const float4*)xp;
        float4 v1 = *(const float4*)(xp + 4);
        bf16x8 ob;
        ob[0] = (short)f2bf(v0.x); ob[1] = (short)f2bf(v0.y);
        ob[2] = (short)f2bf(v0.z); ob[3] = (short)f2bf(v0.w);
        ob[4] = (short)f2bf(v1.x); ob[5] = (short)f2bf(v1.y);
        ob[6] = (short)f2bf(v1.z); ob[7] = (short)f2bf(v1.w);
        *(bf16x8*)(xb + (size_t)i * 8) = ob;
        return;
    }
}

// ================= att1: as1/ad1 = x . (W1 @ att) — 16 lanes/node ============
__global__ __launch_bounds__(256) void att1_kernel(const float* __restrict__ x,
                                                   const float* __restrict__ vsd,
                                                   float* __restrict__ as1,
                                                   float* __restrict__ ad1) {
    __shared__ float vsS[1024];
    const int tid = threadIdx.x;
    for (int idx = tid; idx < 1024; idx += 256) vsS[idx] = vsd[idx];
    __syncthreads();

    const int n = blockIdx.x * 16 + (tid >> 4);
    const int l16 = tid & 15;
    const float* xp = x + (size_t)n * INC + l16 * 8;
    float4 xa = *(const float4*)xp;
    float4 xc = *(const float4*)(xp + 4);

    float o[8];
#pragma unroll
    for (int h = 0; h < 4; ++h) {
        const float* vp = vsS + h * 128 + l16 * 8;
        const float* dp = vsS + 512 + h * 128 + l16 * 8;
        o[h]     = xa.x * vp[0] + xa.y * vp[1] + xa.z * vp[2] + xa.w * vp[3]
                 + xc.x * vp[4] + xc.y * vp[5] + xc.z * vp[6] + xc.w * vp[7];
        o[4 + h] = xa.x * dp[0] + xa.y * dp[1] + xa.z * dp[2] + xa.w * dp[3]
                 + xc.x * dp[4] + xc.y * dp[5] + xc.z * dp[6] + xc.w * dp[7];
    }
#pragma unroll
    for (int off = 1; off < 16; off <<= 1)
#pragma unroll
        for (int v = 0; v < 8; ++v) o[v] += __shfl_xor(o[v], off);
    if (l16 == 0) {
        *(float4*)(as1 + n * 4) = make_float4(o[0], o[1], o[2], o[3]);
        *(float4*)(ad1 + n * 4) = make_float4(o[4], o[5], o[6], o[7]);
    }
}

// ================= edge softmax weights =================
__global__ void edge_w1k(const int* __restrict__ csr_src, const int* __restrict__ csr_dst,
                         const float* __restrict__ as1, const float* __restrict__ ad1,
                         float* __restrict__ w1e) {
    int i = blockIdx.x * 256 + threadIdx.x;
    if (i >= EP) return;
    int s = csr_src[i], d = csr_dst[i];
    float4 a = *(const float4*)(as1 + s * 4);
    float4 b = *(const float4*)(ad1 + d * 4);
    float4 o;
    float t;
    t = a.x + b.x; t = t > 0.f ? t : NEG * t; o.x = __expf(t);
    t = a.y + b.y; t = t > 0.f ? t : NEG * t; o.y = __expf(t);
    t = a.z + b.z; t = t > 0.f ? t : NEG * t; o.z = __expf(t);
    t = a.w + b.w; t = t > 0.f ? t : NEG * t; o.w = __expf(t);
    *(float4*)(w1e + (size_t)i * 4) = o;
}

__global__ void edge_w2k(const int* __restrict__ csr_src, const int* __restrict__ csr_dst,
                         const float* __restrict__ as2, const float* __restrict__ ad2,
                         float* __restrict__ w2e) {
    int i = blockIdx.x * 256 + threadIdx.x;
    if (i >= EP) return;
    float t = as2[csr_src[i]] + ad2[csr_dst[i]];
    t = t > 0.f ? t : NEG * t;
    w2e[i] = __expf(t);
}

// ================= conv1 aggregate of x (bf16): 16 lanes/node, ILP-4 =========
__global__ __launch_bounds__(256) void conv1_agg(const int* __restrict__ rowptr,
                                                 const int* __restrict__ csr_src,
                                                 const float* __restrict__ w1e,
                                                 const unsigned short* __restrict__ xb,
                                                 unsigned short* __restrict__ xaggb) {
    const int tid = threadIdx.x;
    const int node = blockIdx.x * 16 + (tid >> 4);   // NN % 16 == 0
    const int l16 = tid & 15;
    const int beg = rowptr[node], end = rowptr[node + 1];

    float acc[4][8];
#pragma unroll
    for (int h = 0; h < 4; ++h)
#pragma unroll
        for (int j = 0; j < 8; ++j) acc[h][j] = 0.f;
    float sm[4] = {0.f, 0.f, 0.f, 0.f};

    int i = beg;
    for (; i + 4 <= end; i += 4) {
        // issue all 4 index loads, then 4 w loads, then 4 gathers (ILP-4)
        int s0 = csr_src[i];
        int s1 = csr_src[i + 1];
        int s2 = csr_src[i + 2];
        int s3 = csr_src[i + 3];
        float4 w0 = *(const float4*)(w1e + (size_t)i * 4);
        float4 w1 = *(const float4*)(w1e + (size_t)(i + 1) * 4);
        float4 w2 = *(const float4*)(w1e + (size_t)(i + 2) * 4);
        float4 w3 = *(const float4*)(w1e + (size_t)(i + 3) * 4);
        bf16x8 v0 = *(const bf16x8*)(xb + (size_t)s0 * INC + l16 * 8);
        bf16x8 v1 = *(const bf16x8*)(xb + (size_t)s1 * INC + l16 * 8);
        bf16x8 v2 = *(const bf16x8*)(xb + (size_t)s2 * INC + l16 * 8);
        bf16x8 v3 = *(const bf16x8*)(xb + (size_t)s3 * INC + l16 * 8);
#pragma unroll
        for (int j = 0; j < 8; ++j) {
            float f0 = bf2f((unsigned short)v0[j]);
            float f1 = bf2f((unsigned short)v1[j]);
            float f2 = bf2f((unsigned short)v2[j]);
            float f3 = bf2f((unsigned short)v3[j]);
            acc[0][j] += w0.x * f0 + w1.x * f1 + w2.x * f2 + w3.x * f3;
            acc[1][j] += w0.y * f0 + w1.y * f1 + w2.y * f2 + w3.y * f3;
            acc[2][j] += w0.z * f0 + w1.z * f1 + w2.z * f2 + w3.z * f3;
            acc[3][j] += w0.w * f0 + w1.w * f1 + w2.w * f2 + w3.w * f3;
        }
        sm[0] += w0.x + w1.x + w2.x + w3.x;
        sm[1] += w0.y + w1.y + w2.y + w3.y;
        sm[2] += w0.z + w1.z + w2.z + w3.z;
        sm[3] += w0.w + w1.w + w2.w + w3.w;
    }
    for (; i < end; ++i) {
        int s = csr_src[i];
        float4 w = *(const float4*)(w1e + (size_t)i * 4);
        bf16x8 xv = *(const bf16x8*)(xb + (size_t)s * INC + l16 * 8);
#pragma unroll
        for (int j = 0; j < 8; ++j) {
            float xf = bf2f((unsigned short)xv[j]);
            acc[0][j] += w.x * xf;
            acc[1][j] += w.y * xf;
            acc[2][j] += w.z * xf;
            acc[3][j] += w.w * xf;
        }
        sm[0] += w.x; sm[1] += w.y; sm[2] += w.z; sm[3] += w.w;
    }

#pragma unroll
    for (int h = 0; h < 4; ++h) {
        const float rden = 1.f / (sm[h] + EPSS);
        bf16x8 ob;
#pragma unroll
        for (int j = 0; j < 8; ++j) ob[j] = (short)f2bf(acc[h][j] * rden);
        *(bf16x8*)(xaggb + ((size_t)node * 4 + h) * INC + l16 * 8) = ob;
    }
}

// ================= GEMM1 (post-agg): h1c = ELU(xagg @ W1 + b1), bf16 both ====
__global__ __launch_bounds__(256) void gemm1b(const unsigned short* __restrict__ xaggb,
                                              const unsigned short* __restrict__ w1h,
                                              const float* __restrict__ b1,
                                              unsigned short* __restrict__ h1c) {
    __shared__ unsigned short wH[64 * KP1];
    const int tid = threadIdx.x;
    const int n0 = blockIdx.x * 64;
    const int q  = blockIdx.y;

    for (int idx = tid; idx < 64 * 16; idx += 256) {
        int col = idx >> 4, ch = idx & 15;
        *(bf16x8*)(wH + col * KP1 + ch * 8) =
            *(const bf16x8*)(w1h + ((q * 64 + col) << 7) + ch * 8);
    }

    const int w = tid >> 6, l = tid & 63;
    const int cl = l & 15, g = l >> 4, g8 = g * 8;
    const int na = min(n0 + w * 16 + cl, NN - 1);

    bf16x8 aH[4];
#pragma unroll
    for (int kk = 0; kk < 4; ++kk)
        aH[kk] = *(const bf16x8*)(xaggb + ((size_t)na * 4 + q) * INC + kk * 32 + g8);

    f32x4 acc[4];
#pragma unroll
    for (int ct = 0; ct < 4; ++ct) acc[ct] = (f32x4){0.f, 0.f, 0.f, 0.f};

    __syncthreads();

#pragma unroll
    for (int kk = 0; kk < 4; ++kk) {
        const int ko = kk * 32 + g8;
#pragma unroll
        for (int ct = 0; ct < 4; ++ct) {
            const bf16x8 bH = *(const bf16x8*)(wH + (ct * 16 + cl) * KP1 + ko);
            acc[ct] = __builtin_amdgcn_mfma_f32_16x16x32_bf16(aH[kk], bH, acc[ct], 0, 0, 0);
        }
    }

#pragma unroll
    for (int reg = 0; reg < 4; ++reg) {
        const int nd = n0 + w * 16 + g * 4 + reg;
        if (nd < NN) {
#pragma unroll
            for (int ct = 0; ct < 4; ++ct) {
                const int col = q * 64 + ct * 16 + cl;
                float o = acc[ct][reg] + b1[col];
                o = o > 0.f ? o : (__expf(o) - 1.f);
                h1c[(size_t)nd * C1 + col] = f2bf(o);
            }
        }
    }
}

// ================= GEMM2: bf16 A x bf16 W MFMA + att2 epilogue ===============
__global__ __launch_bounds__(256) void gemm2_mfma(const unsigned short* __restrict__ h1c,
                                                  const unsigned short* __restrict__ w2h,
                                                  const float* __restrict__ att_s,
                                                  const float* __restrict__ att_d,
                                                  unsigned short* __restrict__ h2b,
                                                  float* __restrict__ as2,
                                                  float* __restrict__ ad2) {
    __shared__ unsigned short wH[64 * KP2];
    const int tid = threadIdx.x;
    const int n0 = blockIdx.x * 64;

    for (int idx = tid; idx < 64 * 32; idx += 256) {
        int col = idx >> 5, ch = idx & 31;
        *(bf16x8*)(wH + col * KP2 + ch * 8) =
            *(const bf16x8*)(w2h + ((col) << 8) + ch * 8);
    }

    const int w = tid >> 6, l = tid & 63;
    const int cl = l & 15, g = l >> 4, g8 = g * 8;
    const int na = min(n0 + w * 16 + cl, NN - 1);

    f32x4 acc[4];
#pragma unroll
    for (int ct = 0; ct < 4; ++ct) acc[ct] = (f32x4){0.f, 0.f, 0.f, 0.f};

    __syncthreads();

#pragma unroll
    for (int kk = 0; kk < 8; ++kk) {
        const bf16x8 aH = *(const bf16x8*)(h1c + (size_t)na * C1 + kk * 32 + g8);
        const int ko = kk * 32 + g8;
#pragma unroll
        for (int ct = 0; ct < 4; ++ct) {
            const bf16x8 bH = *(const bf16x8*)(wH + (ct * 16 + cl) * KP2 + ko);
            acc[ct] = __builtin_amdgcn_mfma_f32_16x16x32_bf16(aH, bH, acc[ct], 0, 0, 0);
        }
    }

    float asc[4], adc[4];
#pragma unroll
    for (int ct = 0; ct < 4; ++ct) {
        asc[ct] = att_s[ct * 16 + cl];
        adc[ct] = att_d[ct * 16 + cl];
    }

#pragma unroll
    for (int reg = 0; reg < 4; ++reg) {
        const int nd = n0 + w * 16 + g * 4 + reg;
        float sa = 0.f, sd = 0.f;
#pragma unroll
        for (int ct = 0; ct < 4; ++ct) {
            sa += acc[ct][reg] * asc[ct];
            sd += acc[ct][reg] * adc[ct];
        }
#pragma unroll
        for (int off = 8; off > 0; off >>= 1) {
            sa += __shfl_xor(sa, off);
            sd += __shfl_xor(sd, off);
        }
        if (nd < NN) {
#pragma unroll
            for (int ct = 0; ct < 4; ++ct)
                h2b[(size_t)nd * HID + ct * 16 + cl] = f2bf(acc[ct][reg]);
            if (cl == 0) { as2[nd] = sa; ad2[nd] = sd; }
        }
    }
}

// ================= conv2 aggregate: 2 nodes/wave, ILP-4 =======================
__global__ __launch_bounds__(256) void conv2_agg(const int* __restrict__ rowptr,
                                                 const int* __restrict__ csr_src,
                                                 const float* __restrict__ w2e,
                                                 const unsigned short* __restrict__ h2b,
                                                 const float* __restrict__ b2,
                                                 unsigned short* __restrict__ embb) {
    const int tid  = threadIdx.x;
    const int wid  = tid >> 6;
    const int l    = tid & 63;
    const int half = l >> 5;
    const int l32  = l & 31;
    const int node = blockIdx.x * 8 + wid * 2 + half;
    const int beg = rowptr[node], end = rowptr[node + 1];

    float a0 = 0.f, a1 = 0.f, sm = 0.f;
    int i = beg;
    for (; i + 4 <= end; i += 4) {
        int s0 = csr_src[i];
        int s1 = csr_src[i + 1];
        int s2 = csr_src[i + 2];
        int s3 = csr_src[i + 3];
        float w0 = w2e[i], w1 = w2e[i + 1], w2 = w2e[i + 2], w3 = w2e[i + 3];
        unsigned v0 = *(const unsigned*)(h2b + (size_t)s0 * HID + l32 * 2);
        unsigned v1 = *(const unsigned*)(h2b + (size_t)s1 * HID + l32 * 2);
        unsigned v2 = *(const unsigned*)(h2b + (size_t)s2 * HID + l32 * 2);
        unsigned v3 = *(const unsigned*)(h2b + (size_t)s3 * HID + l32 * 2);
        a0 += w0 * bf2f((unsigned short)(v0 & 0xFFFF)) + w1 * bf2f((unsigned short)(v1 & 0xFFFF))
            + w2 * bf2f((unsigned short)(v2 & 0xFFFF)) + w3 * bf2f((unsigned short)(v3 & 0xFFFF));
        a1 += w0 * bf2f((unsigned short)(v0 >> 16)) + w1 * bf2f((unsigned short)(v1 >> 16))
            + w2 * bf2f((unsigned short)(v2 >> 16)) + w3 * bf2f((unsigned short)(v3 >> 16));
        sm += w0 + w1 + w2 + w3;
    }
    for (; i < end; ++i) {
        int s = csr_src[i];
        float w = w2e[i];
        unsigned hv = *(const unsigned*)(h2b + (size_t)s * HID + l32 * 2);
        a0 += w * bf2f((unsigned short)(hv & 0xFFFF));
        a1 += w * bf2f((unsigned short)(hv >> 16));
        sm += w;
    }
    const float rden = 1.f / (sm + EPSS);
    float o0 = a0 * rden + b2[l32 * 2];
    float o1 = a1 * rden + b2[l32 * 2 + 1];
    unsigned outw = (unsigned)f2bf(o0) | ((unsigned)f2bf(o1) << 16);
    *(unsigned*)(embb + (size_t)node * HID + l32 * 2) = outw;
}

// ================= edge MLP: swapped operands, bf16-only W ====================
#define NT_MLP (NE / 32)    // 25000
__global__ __launch_bounds__(512) void edge_mlp_mfma(const int* __restrict__ ei,
                                                     const unsigned short* __restrict__ embb,
                                                     const float* __restrict__ stats,
                                                     const unsigned short* __restrict__ wFh,
                                                     const float* __restrict__ mb1,
                                                     const float* __restrict__ mW2,
                                                     const float* __restrict__ mb2,
                                                     float* __restrict__ out) {
    __shared__ unsigned short sH[PREP_N2];   // 20 KB
    __shared__ float biaS[64], w2aS[64], w2bS[64];
    const int tid = threadIdx.x;
    for (int idx = tid; idx < PREP_N2 / 8; idx += 512)
        ((float4*)sH)[idx] = ((const float4*)wFh)[idx];
    if (tid < 64) {
        biaS[tid] = mb1[tid];
        w2aS[tid] = mW2[tid * 2];
        w2bS[tid] = mW2[tid * 2 + 1];
    }

    const int l  = tid & 63;
    const int cl = l & 15;
    const int g  = l >> 4;
    const int g8 = g * 8;
    const float ob0 = mb2[0], ob1 = mb2[1];

    const int t = blockIdx.x * 8 + (tid >> 6);   // 32-edge tile id

    bf16x8 a[2][5];
#pragma unroll
    for (int s = 0; s < 2; ++s) {
        const int ge_a = t * 32 + s * 16 + cl;
        const int rn = ei[ge_a];
        const int cn = ei[NE + ge_a];
        const unsigned short* rp = embb + (size_t)rn * HID;
        const unsigned short* cp = embb + (size_t)cn * HID;
        a[s][0] = *(const bf16x8*)(rp + g8);
        a[s][1] = *(const bf16x8*)(rp + 32 + g8);
        a[s][2] = *(const bf16x8*)(cp + g8);
        a[s][3] = *(const bf16x8*)(cp + 32 + g8);
        bf16x8 z = {0, 0, 0, 0, 0, 0, 0, 0};
        if (g == 0) {
            const float* sp = stats + (size_t)ge_a * 3;
            z[0] = (short)f2bf(sp[0]);
            z[1] = (short)f2bf(sp[1]);
            z[2] = (short)f2bf(sp[2]);
        }
        a[s][4] = z;
    }

    f32x4 acc[2][4];
#pragma unroll
    for (int s = 0; s < 2; ++s)
#pragma unroll
        for (int ct = 0; ct < 4; ++ct)
            acc[s][ct] = (f32x4){0.f, 0.f, 0.f, 0.f};

    __syncthreads();

#pragma unroll
    for (int kk = 0; kk < 5; ++kk) {
#pragma unroll
        for (int ct = 0; ct < 4; ++ct) {
            const int fo = ((kk * 4 + ct) * 64 + l) * 8;
            const bf16x8 wHf = *(const bf16x8*)(sH + fo);
#pragma unroll
            for (int s = 0; s < 2; ++s) {
                acc[s][ct] = __builtin_amdgcn_mfma_f32_16x16x32_bf16(wHf, a[s][kk], acc[s][ct], 0, 0, 0);
            }
        }
    }

#pragma unroll
    for (int s = 0; s < 2; ++s) {
        float p0 = 0.f, p1 = 0.f;
#pragma unroll
        for (int ct = 0; ct < 4; ++ct) {
            const int hb = ct * 16 + g * 4;
            float4 bi = *(const float4*)(biaS + hb);
            float4 wa = *(const float4*)(w2aS + hb);
            float4 wb = *(const float4*)(w2bS + hb);
#pragma unroll
            for (int reg = 0; reg < 4; ++reg) {
                float bv = (reg == 0) ? bi.x : (reg == 1) ? bi.y : (reg == 2) ? bi.z : bi.w;
                float av = (reg == 0) ? wa.x : (reg == 1) ? wa.y : (reg == 2) ? wa.z : wa.w;
                float wv = (reg == 0) ? wb.x : (reg == 1) ? wb.y : (reg == 2) ? wb.z : wb.w;
                float h = fmaxf(acc[s][ct][reg] + bv, 0.f);
                p0 += h * av;
                p1 += h * wv;
            }
        }
        p0 += __shfl_xor(p0, 16); p0 += __shfl_xor(p0, 32);
        p1 += __shfl_xor(p1, 16); p1 += __shfl_xor(p1, 32);
        if (g == 0) {
            const int ge = t * 32 + s * 16 + cl;
            *(float2*)(out + (size_t)ge * 2) = make_float2(p0 + ob0, p1 + ob1);
        }
    }
}

// ================= launcher =================
extern "C" void kernel_launch(void* const* d_in, const int* in_sizes, int n_in,
                              void* d_out, int out_size, void* d_ws, size_t ws_size,
                              hipStream_t stream) {
    const float* x      = (const float*)d_in[0];
    const int*   ei     = (const int*)d_in[1];
    const float* stats  = (const float*)d_in[2];
    const float* W1     = (const float*)d_in[3];
    const float* att_s1 = (const float*)d_in[4];
    const float* att_d1 = (const float*)d_in[5];
    const float* b1     = (const float*)d_in[6];
    const float* W2     = (const float*)d_in[7];
    const float* att_s2 = (const float*)d_in[8];
    const float* att_d2 = (const float*)d_in[9];
    const float* b2     = (const float*)d_in[10];
    const float* mW1    = (const float*)d_in[11];
    const float* mb1    = (const float*)d_in[12];
    const float* mW2    = (const float*)d_in[13];
    const float* mb2    = (const float*)d_in[14];
    float* out = (float*)d_out;
    float* ws  = (float*)d_ws;

    // f32-word-offset layout (no aliasing; all chunks 16B-aligned)
    int*   rowptr  = (int*)ws;                                 // NN+16
    int*   csr_src = rowptr + NN + 16;                         // EP
    int*   csr_dst = csr_src + EP;                             // EP
    float* as1     = (float*)(csr_dst + EP);                   // 4NN
    float* ad1     = as1 + (size_t)4 * NN;                     // 4NN
    unsigned short* xb    = (unsigned short*)(ad1 + (size_t)4 * NN);  // NN*128 bf16
    unsigned short* xaggb = xb + (size_t)128 * NN;             // NN*512 bf16
    unsigned short* h1c   = xaggb + (size_t)512 * NN;          // NN*256 bf16
    unsigned short* h2b   = h1c + (size_t)256 * NN;            // NN*64 bf16
    unsigned short* embb  = h2b + (size_t)64 * NN;             // NN*64 bf16
    float* as2     = (float*)(embb + (size_t)64 * NN);         // NN
    float* ad2     = as2 + NN;                                 // NN
    unsigned short* w1h = (unsigned short*)(ad2 + NN);         // 256*128
    unsigned short* w2h = w1h + C1 * INC;                      // 64*256
    unsigned short* wFh = w2h + HID * C1;                      // 10240
    float* vsd     = (float*)(wFh + PREP_N2);                  // 1024
    float* w1e     = vsd + 1024;                               // 4*EP
    float* w2e     = w1e + (size_t)4 * EP;                     // EP
    int*   counts  = (int*)(w2e + EP + 64);                    // NN
    int*   bsum    = counts + NN + 64;                         // NSB
    int*   cursor  = bsum + NSB + 64;                          // NN

    // ---- CSR build + weight prep + projections ----
    hipMemsetAsync(counts, 0, NN * sizeof(int), stream);
    prep_all<<<(PREP_TOT + 255) / 256, 256, 0, stream>>>(
        mW1, W1, W2, x, att_s1, att_d1,
        w1h, w2h, wFh, vsd, xb);
    count_x<<<NXCD * NSUB, 256, 0, stream>>>(ei, counts);
    scan_partial<<<NSB, SCHUNK, 0, stream>>>(counts, bsum);
    scan_top<<<1, 128, 0, stream>>>(bsum, rowptr);
    scan_final<<<NSB, SCHUNK, 0, stream>>>(counts, bsum, rowptr, cursor);
    csr_fill_x<<<NXCD * NSUB, 256, 0, stream>>>(ei, cursor, csr_src);
    fill_dst<<<(NN + 255) / 256, 256, 0, stream>>>(rowptr, csr_dst);

    // ---- conv1: logits -> edge weights -> aggregate x -> GEMM ----
    att1_kernel<<<NN / 16, 256, 0, stream>>>(x, vsd, as1, ad1);
    edge_w1k<<<(EP + 255) / 256, 256, 0, stream>>>(csr_src, csr_dst, as1, ad1, w1e);
    conv1_agg<<<NN / 16, 256, 0, stream>>>(rowptr, csr_src, w1e, xb, xaggb);
    gemm1b<<<dim3((NN + 63) / 64, 4), 256, 0, stream>>>(xaggb, w1h, b1, h1c);

    // ---- conv2 ----
    gemm2_mfma<<<(NN + 63) / 64, 256, 0, stream>>>(h1c, w2h, att_s2, att_d2,
                                                   h2b, as2, ad2);
    edge_w2k<<<(EP + 255) / 256, 256, 0, stream>>>(csr_src, csr_dst, as2, ad2, w2e);
    conv2_agg<<<NN / 8, 256, 0, stream>>>(rowptr, csr_src, w2e, h2b, b2, embb);

    // ---- edge MLP: swapped-operand MFMA, bf16-only W, 512 thr ----
    edge_mlp_mfma<<<NT_MLP / 8, 512, 0, stream>>>(ei, embb, stats, wFh,
                                                  mb1, mW2, mb2, out);
}